// Round 1
// baseline (120234.680 us; speedup 1.0000x reference)
//
#include <hip/hip_runtime.h>
#include <math.h>

#define NM   128
#define LDA  129          // +1 pad: conflict-free column access (129 % 32 == 1)
#define NT   512          // 8 waves
#define MAX_SWEEPS 14

// One workgroup per matrix. A and V live in LDS (f32). Parallel cyclic Jacobi
// with round-robin (tournament) pair schedule: 127 rounds x 64 disjoint pairs.
__global__ __launch_bounds__(NT, 1)
void logeig_jacobi(const float* __restrict__ in, float* __restrict__ out)
{
    __shared__ float A[NM][LDA];
    __shared__ float V[NM][LDA];
    __shared__ float rc[64], rs[64];
    __shared__ float logd[NM];
    __shared__ float roff[NT/64], rdia[NT/64];
    __shared__ int   s_done;

    const int t = threadIdx.x;
    const long long b = blockIdx.x;
    const float* __restrict__ Ain  = in  + (b << 14);
    float* __restrict__       Aout = out + (b << 14);

    // ---- load A, init V = I ----
    for (int k = 0; k < (NM*NM)/NT; ++k) {
        int idx = t + k*NT;
        int i = idx >> 7, j = idx & 127;
        A[i][j] = Ain[idx];
        V[i][j] = (i == j) ? 1.0f : 0.0f;
    }
    __syncthreads();

    for (int sweep = 0; sweep < MAX_SWEEPS; ++sweep) {
        for (int r = 0; r < NM-1; ++r) {
            // ---- compute 64 disjoint rotations ----
            if (t < 64) {
                int m = t, p, q;
                if (m == 0) { p = NM-1; q = r; }
                else {
                    p = r + m;            if (p >= NM-1) p -= (NM-1);
                    q = r - m + (NM-1);   if (q >= NM-1) q -= (NM-1);
                }
                float app = A[p][p], aqq = A[q][q], apq = A[p][q];
                float c = 1.0f, s = 0.0f;
                if (fabsf(apq) > 1e-12f*(fabsf(app)+fabsf(aqq)) + 1e-32f) {
                    float tau = (aqq - app) * 0.5f / apq;
                    float tt  = 1.0f / (fabsf(tau) + sqrtf(fmaf(tau,tau,1.0f)));
                    tt = (tau < 0.0f) ? -tt : tt;
                    c = rsqrtf(fmaf(tt,tt,1.0f));
                    s = tt * c;
                }
                rc[m] = c; rs[m] = s;
            }
            __syncthreads();

            // ---- phase 1: column rotations on A (A <- A*J) and V (V <- V*J) ----
            // 16384 tasks: i = low 7 bits (lane-consecutive -> conflict-free)
            for (int k = 0; k < (2*64*NM)/NT; ++k) {
                int task = t + k*NT;
                int i   = task & 127;
                int m   = (task >> 7) & 63;
                int isV = task >> 13;
                int p, q;
                if (m == 0) { p = NM-1; q = r; }
                else {
                    p = r + m;            if (p >= NM-1) p -= (NM-1);
                    q = r - m + (NM-1);   if (q >= NM-1) q -= (NM-1);
                }
                float c = rc[m], s = rs[m];
                if (isV == 0) {
                    float x = A[i][p], y = A[i][q];
                    A[i][p] = c*x - s*y;
                    A[i][q] = s*x + c*y;
                } else {
                    float x = V[i][p], y = V[i][q];
                    V[i][p] = c*x - s*y;
                    V[i][q] = s*x + c*y;
                }
            }
            __syncthreads();

            // ---- phase 2: row rotations on A (A <- J^T * A) ----
            for (int k = 0; k < (64*NM)/NT; ++k) {
                int task = t + k*NT;
                int j = task & 127;
                int m = task >> 7;
                int p, q;
                if (m == 0) { p = NM-1; q = r; }
                else {
                    p = r + m;            if (p >= NM-1) p -= (NM-1);
                    q = r - m + (NM-1);   if (q >= NM-1) q -= (NM-1);
                }
                float c = rc[m], s = rs[m];
                float x = A[p][j], y = A[q][j];
                A[p][j] = c*x - s*y;
                A[q][j] = s*x + c*y;
            }
            __syncthreads();
        }

        // ---- deterministic convergence check (tree reduction, fixed order) ----
        float off2 = 0.0f, dia2 = 0.0f;
        for (int k = 0; k < (NM*NM)/NT; ++k) {
            int idx = t + k*NT;
            int i = idx >> 7, j = idx & 127;
            float v = A[i][j];
            if (i == j) dia2 += v*v; else off2 += v*v;
        }
        #pragma unroll
        for (int o = 32; o > 0; o >>= 1) {
            off2 += __shfl_down(off2, o, 64);
            dia2 += __shfl_down(dia2, o, 64);
        }
        if ((t & 63) == 0) { roff[t >> 6] = off2; rdia[t >> 6] = dia2; }
        __syncthreads();
        if (t == 0) {
            float o2 = 0.0f, d2 = 0.0f;
            for (int w = 0; w < NT/64; ++w) { o2 += roff[w]; d2 += rdia[w]; }
            s_done = (o2 <= 1e-13f * d2) ? 1 : 0;
        }
        __syncthreads();
        if (s_done) break;
    }

    // ---- eigenvalues -> log ----
    if (t < NM) logd[t] = logf(fmaxf(A[t][t], 1e-12f));
    __syncthreads();

    // ---- W = V * diag(logd), overwrite A ----
    for (int kk = 0; kk < (NM*NM)/NT; ++kk) {
        int idx = t + kk*NT;
        int i = idx >> 7, k = idx & 127;
        A[i][k] = V[i][k] * logd[k];
    }
    __syncthreads();

    // ---- O = W * V^T, register-blocked: thread -> (row i, 32-col strip jb) ----
    {
        int i  = t >> 2;
        int jb = t & 3;
        float acc[32];
        #pragma unroll
        for (int jj = 0; jj < 32; ++jj) acc[jj] = 0.0f;
        for (int kk = 0; kk < NM; ++kk) {
            int k = (kk + jb) & 127;          // jb-stagger: breaks bank aliasing
            float w = A[i][k];
            #pragma unroll
            for (int jj = 0; jj < 32; ++jj)
                acc[jj] = fmaf(w, V[jb*32 + jj][k], acc[jj]);
        }
        #pragma unroll
        for (int jj = 0; jj < 32; ++jj)
            Aout[i*NM + jb*32 + jj] = acc[jj];
    }
}

extern "C" void kernel_launch(void* const* d_in, const int* in_sizes, int n_in,
                              void* d_out, int out_size, void* d_ws, size_t ws_size,
                              hipStream_t stream) {
    const float* in = (const float*)d_in[0];
    float* out = (float*)d_out;
    int batch = in_sizes[0] / (NM*NM);   // 4096
    hipLaunchKernelGGL(logeig_jacobi, dim3(batch), dim3(NT), 0, stream, in, out);
}

// Round 4
// 21300.557 us; speedup vs baseline: 5.6447x; 5.6447x over previous
//
#include <hip/hip_runtime.h>
#include <math.h>

#define NM   128
#define PAD  132   // row stride in floats
#define NTG  512

// ============================================================================
// log(A) = ln(s) I + 8 * cheb_log( NS_sqrt^3( A/s ) ),  s = Gershgorin bound.
// GEMMs read both operands as rows ((B*C)_ij = sum_k B[k][i]*C[k][j]), which
// is only valid for symmetric operands. The antisymmetric error mode of this
// scheme is EXPONENTIALLY UNSTABLE (multiplier ~2-3.4/iter), so every kernel
// re-symmetrizes its LDS operands after load — resets asym to rounding level.
// NS scaling provably capped at c<=1.5: spectrum stays in (0,1.5] forever.
// ============================================================================

__global__ __launch_bounds__(256,1)
void scale_kernel(const float* __restrict__ A, float* __restrict__ outY,
                  float* __restrict__ outM, float* __restrict__ lns)
{
    __shared__ __align__(16) float L[NM][PAD];
    __shared__ float rs[NM];
    __shared__ float s_inv;
    const int t = threadIdx.x;
    const long long b = blockIdx.x;
    const long long off = b << 14;
    for (int v = 0; v < 16; ++v) {
        int f = t + v*256;
        int row = f >> 5, c4 = (f & 31) << 2;
        *(float4*)&L[row][c4] = ((const float4*)(A + off))[f];
    }
    __syncthreads();
    if (t < NM) {
        float s = 0.f;
        for (int j = 0; j < NM; ++j) s += fabsf(L[t][j]);
        rs[t] = s;
    }
    __syncthreads();
    if (t < 64) {
        float m = fmaxf(rs[t], rs[t+64]);
        #pragma unroll
        for (int o = 32; o > 0; o >>= 1) m = fmaxf(m, __shfl_down(m, o, 64));
        if (t == 0) { s_inv = 1.0f/m; lns[b] = logf(m); }
    }
    __syncthreads();
    const float inv = s_inv;
    for (int v = 0; v < 16; ++v) {
        int f = t + v*256;
        int row = f >> 5, c4 = (f & 31) << 2;
        float4 x = *(const float4*)&L[row][c4];
        x.x *= inv; x.y *= inv; x.z *= inv; x.w *= inv;
        ((float4*)(outY + off))[f] = x;
        ((float4*)(outM + off))[f] = x;
    }
}

// One scaled Newton-Schulz sqrt iteration (invariant Y^2 = (A/s)*M):
//   Y' = dd*(3Y - Y*M)/2            (dd = sqrt(cc))
//   M' = cc*(9M - 6M^2 + M^3)/4     (skipped when doM==0)
__global__ __launch_bounds__(NTG,1)
void ns_kernel(const float* __restrict__ Mp, const float* __restrict__ Yp,
               float* __restrict__ outM, float* __restrict__ outY,
               float cc, float dd, int doM)
{
    __shared__ __align__(16) float LM[NM][PAD];
    __shared__ __align__(16) float LB[NM][PAD];
    const int t = threadIdx.x;
    const long long off = (long long)blockIdx.x << 14;
    for (int v = 0; v < 8; ++v) {
        int f = t + v*NTG;
        int row = f >> 5, c4 = (f & 31) << 2;
        *(float4*)&LM[row][c4] = ((const float4*)(Mp + off))[f];
        *(float4*)&LB[row][c4] = ((const float4*)(Yp + off))[f];
    }
    __syncthreads();
    // ---- re-symmetrize (kills the unstable antisymmetric mode each iter) ----
    for (int idx = t; idx < NM*NM; idx += NTG) {
        int i = idx >> 7, j = idx & 127;
        if (i < j) {
            float a = 0.5f*(LM[i][j] + LM[j][i]);
            LM[i][j] = a; LM[j][i] = a;
            float y = 0.5f*(LB[i][j] + LB[j][i]);
            LB[i][j] = y; LB[j][i] = y;
        }
    }
    __syncthreads();

    const int r0 = (t >> 4) << 2;      // rows r0..r0+3
    const int ca = (t & 15) << 2;      // cols ca..ca+3 and cb..cb+3
    const int cb = ca + 64;
    float acc[4][8];

    // ---- phase 1: acc = (Y^T M) tile = (Y M) for symmetric Y
    #pragma unroll
    for (int i = 0; i < 4; ++i)
        #pragma unroll
        for (int j = 0; j < 8; ++j) acc[i][j] = 0.f;
    #pragma unroll 8
    for (int k = 0; k < NM; ++k) {
        float av[4], bv[8];
        *(float4*)&av[0] = *(const float4*)&LB[k][r0];
        *(float4*)&bv[0] = *(const float4*)&LM[k][ca];
        *(float4*)&bv[4] = *(const float4*)&LM[k][cb];
        #pragma unroll
        for (int i = 0; i < 4; ++i)
            #pragma unroll
            for (int j = 0; j < 8; ++j) acc[i][j] = fmaf(av[i], bv[j], acc[i][j]);
    }
    const float a15 = 1.5f*dd, a05 = 0.5f*dd;
    #pragma unroll
    for (int i = 0; i < 4; ++i) {
        float4 o;
        o.x = a15*LB[r0+i][ca+0] - a05*acc[i][0];
        o.y = a15*LB[r0+i][ca+1] - a05*acc[i][1];
        o.z = a15*LB[r0+i][ca+2] - a05*acc[i][2];
        o.w = a15*LB[r0+i][ca+3] - a05*acc[i][3];
        *(float4*)&outY[off + (long long)(r0+i)*NM + ca] = o;
        o.x = a15*LB[r0+i][cb+0] - a05*acc[i][4];
        o.y = a15*LB[r0+i][cb+1] - a05*acc[i][5];
        o.z = a15*LB[r0+i][cb+2] - a05*acc[i][6];
        o.w = a15*LB[r0+i][cb+3] - a05*acc[i][7];
        *(float4*)&outY[off + (long long)(r0+i)*NM + cb] = o;
    }

    if (doM) {
        __syncthreads();   // all phase-1 LB reads done before overwriting LB
        // ---- phase 2: LB <- M^T M = M^2 (exactly symmetric by construction)
        #pragma unroll
        for (int i = 0; i < 4; ++i)
            #pragma unroll
            for (int j = 0; j < 8; ++j) acc[i][j] = 0.f;
        #pragma unroll 8
        for (int k = 0; k < NM; ++k) {
            float av[4], bv[8];
            *(float4*)&av[0] = *(const float4*)&LM[k][r0];
            *(float4*)&bv[0] = *(const float4*)&LM[k][ca];
            *(float4*)&bv[4] = *(const float4*)&LM[k][cb];
            #pragma unroll
            for (int i = 0; i < 4; ++i)
                #pragma unroll
                for (int j = 0; j < 8; ++j) acc[i][j] = fmaf(av[i], bv[j], acc[i][j]);
        }
        #pragma unroll
        for (int i = 0; i < 4; ++i) {
            *(float4*)&LB[r0+i][ca] = make_float4(acc[i][0],acc[i][1],acc[i][2],acc[i][3]);
            *(float4*)&LB[r0+i][cb] = make_float4(acc[i][4],acc[i][5],acc[i][6],acc[i][7]);
        }
        __syncthreads();
        // ---- phase 3: acc = M * M^2; combine M' = cc*(9M - 6M^2 + M^3)/4
        #pragma unroll
        for (int i = 0; i < 4; ++i)
            #pragma unroll
            for (int j = 0; j < 8; ++j) acc[i][j] = 0.f;
        #pragma unroll 8
        for (int k = 0; k < NM; ++k) {
            float av[4], bv[8];
            *(float4*)&av[0] = *(const float4*)&LM[k][r0];
            *(float4*)&bv[0] = *(const float4*)&LB[k][ca];
            *(float4*)&bv[4] = *(const float4*)&LB[k][cb];
            #pragma unroll
            for (int i = 0; i < 4; ++i)
                #pragma unroll
                for (int j = 0; j < 8; ++j) acc[i][j] = fmaf(av[i], bv[j], acc[i][j]);
        }
        const float q = 0.25f*cc;
        #pragma unroll
        for (int i = 0; i < 4; ++i) {
            float4 o;
            o.x = q*(9.f*LM[r0+i][ca+0] - 6.f*LB[r0+i][ca+0] + acc[i][0]);
            o.y = q*(9.f*LM[r0+i][ca+1] - 6.f*LB[r0+i][ca+1] + acc[i][1]);
            o.z = q*(9.f*LM[r0+i][ca+2] - 6.f*LB[r0+i][ca+2] + acc[i][2]);
            o.w = q*(9.f*LM[r0+i][ca+3] - 6.f*LB[r0+i][ca+3] + acc[i][3]);
            *(float4*)&outM[off + (long long)(r0+i)*NM + ca] = o;
            o.x = q*(9.f*LM[r0+i][cb+0] - 6.f*LB[r0+i][cb+0] + acc[i][4]);
            o.y = q*(9.f*LM[r0+i][cb+1] - 6.f*LB[r0+i][cb+1] + acc[i][5]);
            o.z = q*(9.f*LM[r0+i][cb+2] - 6.f*LB[r0+i][cb+2] + acc[i][6]);
            o.w = q*(9.f*LM[r0+i][cb+3] - 6.f*LB[r0+i][cb+3] + acc[i][7]);
            *(float4*)&outM[off + (long long)(r0+i)*NM + cb] = o;
        }
    }
}

// P = a*X + bd*I   (elementwise Horner init: top two coefficients)
__global__ __launch_bounds__(256,1)
void horner_init(const float* __restrict__ X, float* __restrict__ P, float a, float bd)
{
    const int t = threadIdx.x;
    const long long b = blockIdx.x;
    const long long off = b << 14;
    for (int v = 0; v < 16; ++v) {
        int f = t + v*256;
        float4 x = ((const float4*)(X + off))[f];
        int idx0 = f << 2;
        int row = idx0 >> 7, col = idx0 & 127;
        float4 o;
        o.x = a*x.x + ((col+0)==row ? bd : 0.f);
        o.y = a*x.y + ((col+1)==row ? bd : 0.f);
        o.z = a*x.z + ((col+2)==row ? bd : 0.f);
        o.w = a*x.w + ((col+3)==row ? bd : 0.f);
        ((float4*)(P + off))[f] = o;
    }
}

// Out = s1*(X*P) - s2*P + (s3 + lns[b]?)*I
__global__ __launch_bounds__(NTG,1)
void poly_kernel(const float* __restrict__ X, const float* __restrict__ P,
                 float* __restrict__ Out, float s1, float s2, float s3,
                 const float* __restrict__ lns)
{
    __shared__ __align__(16) float LX[NM][PAD];
    __shared__ __align__(16) float LP[NM][PAD];
    const int t = threadIdx.x;
    const long long b = blockIdx.x;
    const long long off = b << 14;
    for (int v = 0; v < 8; ++v) {
        int f = t + v*NTG;
        int row = f >> 5, c4 = (f & 31) << 2;
        *(float4*)&LX[row][c4] = ((const float4*)(X + off))[f];
        *(float4*)&LP[row][c4] = ((const float4*)(P + off))[f];
    }
    __syncthreads();
    for (int idx = t; idx < NM*NM; idx += NTG) {
        int i = idx >> 7, j = idx & 127;
        if (i < j) {
            float a = 0.5f*(LX[i][j] + LX[j][i]);
            LX[i][j] = a; LX[j][i] = a;
            float p2 = 0.5f*(LP[i][j] + LP[j][i]);
            LP[i][j] = p2; LP[j][i] = p2;
        }
    }
    __syncthreads();
    const int r0 = (t >> 4) << 2;
    const int ca = (t & 15) << 2;
    const int cb = ca + 64;
    float acc[4][8];
    #pragma unroll
    for (int i = 0; i < 4; ++i)
        #pragma unroll
        for (int j = 0; j < 8; ++j) acc[i][j] = 0.f;
    #pragma unroll 8
    for (int k = 0; k < NM; ++k) {
        float av[4], bv[8];
        *(float4*)&av[0] = *(const float4*)&LX[k][r0];
        *(float4*)&bv[0] = *(const float4*)&LP[k][ca];
        *(float4*)&bv[4] = *(const float4*)&LP[k][cb];
        #pragma unroll
        for (int i = 0; i < 4; ++i)
            #pragma unroll
            for (int j = 0; j < 8; ++j) acc[i][j] = fmaf(av[i], bv[j], acc[i][j]);
    }
    const float dadd = s3 + (lns ? lns[b] : 0.f);
    #pragma unroll
    for (int i = 0; i < 4; ++i) {
        float4 o;
        o.x = s1*acc[i][0] - s2*LP[r0+i][ca+0] + ((r0+i)==(ca+0) ? dadd : 0.f);
        o.y = s1*acc[i][1] - s2*LP[r0+i][ca+1] + ((r0+i)==(ca+1) ? dadd : 0.f);
        o.z = s1*acc[i][2] - s2*LP[r0+i][ca+2] + ((r0+i)==(ca+2) ? dadd : 0.f);
        o.w = s1*acc[i][3] - s2*LP[r0+i][ca+3] + ((r0+i)==(ca+3) ? dadd : 0.f);
        *(float4*)&Out[off + (long long)(r0+i)*NM + ca] = o;
        o.x = s1*acc[i][4] - s2*LP[r0+i][cb+0] + ((r0+i)==(cb+0) ? dadd : 0.f);
        o.y = s1*acc[i][5] - s2*LP[r0+i][cb+1] + ((r0+i)==(cb+1) ? dadd : 0.f);
        o.z = s1*acc[i][6] - s2*LP[r0+i][cb+2] + ((r0+i)==(cb+2) ? dadd : 0.f);
        o.w = s1*acc[i][7] - s2*LP[r0+i][cb+3] + ((r0+i)==(cb+3) ? dadd : 0.f);
        *(float4*)&Out[off + (long long)(r0+i)*NM + cb] = o;
    }
}

// ============================================================================
// Fallback (ws too small): round-1 parallel Jacobi
// ============================================================================
#define LDA  129
#define NT   512
#define MAX_SWEEPS 14

__global__ __launch_bounds__(NT, 1)
void logeig_jacobi(const float* __restrict__ in, float* __restrict__ out)
{
    __shared__ float A[NM][LDA];
    __shared__ float V[NM][LDA];
    __shared__ float rc[64], rs[64];
    __shared__ float logd[NM];
    __shared__ float roff[NT/64], rdia[NT/64];
    __shared__ int   s_done;

    const int t = threadIdx.x;
    const long long b = blockIdx.x;
    const float* __restrict__ Ain  = in  + (b << 14);
    float* __restrict__       Aout = out + (b << 14);

    for (int k = 0; k < (NM*NM)/NT; ++k) {
        int idx = t + k*NT;
        int i = idx >> 7, j = idx & 127;
        A[i][j] = Ain[idx];
        V[i][j] = (i == j) ? 1.0f : 0.0f;
    }
    __syncthreads();

    for (int sweep = 0; sweep < MAX_SWEEPS; ++sweep) {
        for (int r = 0; r < NM-1; ++r) {
            if (t < 64) {
                int m = t, p, q;
                if (m == 0) { p = NM-1; q = r; }
                else {
                    p = r + m;            if (p >= NM-1) p -= (NM-1);
                    q = r - m + (NM-1);   if (q >= NM-1) q -= (NM-1);
                }
                float app = A[p][p], aqq = A[q][q], apq = A[p][q];
                float c = 1.0f, s = 0.0f;
                if (fabsf(apq) > 1e-12f*(fabsf(app)+fabsf(aqq)) + 1e-32f) {
                    float tau = (aqq - app) * 0.5f / apq;
                    float tt  = 1.0f / (fabsf(tau) + sqrtf(fmaf(tau,tau,1.0f)));
                    tt = (tau < 0.0f) ? -tt : tt;
                    c = rsqrtf(fmaf(tt,tt,1.0f));
                    s = tt * c;
                }
                rc[m] = c; rs[m] = s;
            }
            __syncthreads();
            for (int k = 0; k < (2*64*NM)/NT; ++k) {
                int task = t + k*NT;
                int i   = task & 127;
                int m   = (task >> 7) & 63;
                int isV = task >> 13;
                int p, q;
                if (m == 0) { p = NM-1; q = r; }
                else {
                    p = r + m;            if (p >= NM-1) p -= (NM-1);
                    q = r - m + (NM-1);   if (q >= NM-1) q -= (NM-1);
                }
                float c = rc[m], s = rs[m];
                if (isV == 0) {
                    float x = A[i][p], y = A[i][q];
                    A[i][p] = c*x - s*y;
                    A[i][q] = s*x + c*y;
                } else {
                    float x = V[i][p], y = V[i][q];
                    V[i][p] = c*x - s*y;
                    V[i][q] = s*x + c*y;
                }
            }
            __syncthreads();
            for (int k = 0; k < (64*NM)/NT; ++k) {
                int task = t + k*NT;
                int j = task & 127;
                int m = task >> 7;
                int p, q;
                if (m == 0) { p = NM-1; q = r; }
                else {
                    p = r + m;            if (p >= NM-1) p -= (NM-1);
                    q = r - m + (NM-1);   if (q >= NM-1) q -= (NM-1);
                }
                float c = rc[m], s = rs[m];
                float x = A[p][j], y = A[q][j];
                A[p][j] = c*x - s*y;
                A[q][j] = s*x + c*y;
            }
            __syncthreads();
        }
        float off2 = 0.0f, dia2 = 0.0f;
        for (int k = 0; k < (NM*NM)/NT; ++k) {
            int idx = t + k*NT;
            int i = idx >> 7, j = idx & 127;
            float v = A[i][j];
            if (i == j) dia2 += v*v; else off2 += v*v;
        }
        #pragma unroll
        for (int o = 32; o > 0; o >>= 1) {
            off2 += __shfl_down(off2, o, 64);
            dia2 += __shfl_down(dia2, o, 64);
        }
        if ((t & 63) == 0) { roff[t >> 6] = off2; rdia[t >> 6] = dia2; }
        __syncthreads();
        if (t == 0) {
            float o2 = 0.0f, d2 = 0.0f;
            for (int w = 0; w < NT/64; ++w) { o2 += roff[w]; d2 += rdia[w]; }
            s_done = (o2 <= 1e-13f * d2) ? 1 : 0;
        }
        __syncthreads();
        if (s_done) break;
    }

    if (t < NM) logd[t] = logf(fmaxf(A[t][t], 1e-12f));
    __syncthreads();
    for (int kk = 0; kk < (NM*NM)/NT; ++kk) {
        int idx = t + kk*NT;
        int i = idx >> 7, k = idx & 127;
        A[i][k] = V[i][k] * logd[k];
    }
    __syncthreads();
    {
        int i  = t >> 2;
        int jb = t & 3;
        float acc[32];
        #pragma unroll
        for (int jj = 0; jj < 32; ++jj) acc[jj] = 0.0f;
        for (int kk = 0; kk < NM; ++kk) {
            int k = (kk + jb) & 127;
            float w = A[i][k];
            #pragma unroll
            for (int jj = 0; jj < 32; ++jj)
                acc[jj] = fmaf(w, V[jb*32 + jj][k], acc[jj]);
        }
        #pragma unroll
        for (int jj = 0; jj < 32; ++jj)
            Aout[i*NM + jb*32 + jj] = acc[jj];
    }
}

// ============================================================================
// Host
// ============================================================================
static void cheb_log_power(double lo, double up, int deg, double* p)
{
    const int NC = deg + 1;
    const int MN = 64;
    double mid = 0.5*(lo+up), hw = 0.5*(up-lo);
    double cc[32];
    for (int j = 0; j < NC; ++j) {
        double s = 0.0;
        for (int m = 0; m < MN; ++m) {
            double th = M_PI*(m+0.5)/MN;
            s += log(mid + hw*cos(th)) * cos(j*th);
        }
        cc[j] = 2.0*s/MN;
    }
    double Tp[32] = {0}, Tc[32] = {0}, Tn[32];
    for (int j = 0; j < NC; ++j) p[j] = 0.0;
    Tp[0] = 1.0;  p[0] += 0.5*cc[0];
    Tc[1] = 1.0;  p[1] += cc[1];
    for (int k = 2; k <= deg; ++k) {
        for (int j = 0; j < NC; ++j) Tn[j] = -Tp[j];
        for (int j = 1; j < NC; ++j) Tn[j] += 2.0*Tc[j-1];
        for (int j = 0; j < NC; ++j) { p[j] += cc[k]*Tn[j]; Tp[j] = Tc[j]; Tc[j] = Tn[j]; }
    }
}

extern "C" void kernel_launch(void* const* d_in, const int* in_sizes, int n_in,
                              void* d_out, int out_size, void* d_ws, size_t ws_size,
                              hipStream_t stream) {
    const float* in = (const float*)d_in[0];
    float* out = (float*)d_out;
    const int batch = in_sizes[0] >> 14;                 // 4096
    const size_t matBytes = (size_t)batch * NM * NM * 4; // 256 MB
    const size_t need = matBytes + (size_t)batch * 4;

    if (ws_size < need) {   // fallback
        logeig_jacobi<<<batch, NT, 0, stream>>>(in, out);
        return;
    }

    float* Mbuf = (float*)d_ws;
    float* lns  = (float*)((char*)d_ws + matBytes);

    scale_kernel<<<batch, 256, 0, stream>>>(in, out, Mbuf, lns);

    // Provably-safe schedule: every c <= 1.5 -> spectrum confined to (0,1.5].
    // Interval-tracked from worst-case [5e-5, 1]:
    //   L1 (12): 1.5 x9, 1.116, 1, 1   -> [1-6e-6, 1]
    //   L2 (8):  1.5 x5, 1.116, 1, 1
    //   L3 (6):  1.5 x3, 1.116, 1, 1
    const float cs[26] = {
        1.5f,1.5f,1.5f,1.5f,1.5f,1.5f,1.5f,1.5f,1.5f, 1.116f, 1.0f, 1.0f,
        1.5f,1.5f,1.5f,1.5f,1.5f, 1.116f, 1.0f, 1.0f,
        1.5f,1.5f,1.5f, 1.116f, 1.0f, 1.0f
    };
    const int levLen[3] = {12, 8, 6};
    int idx = 0;
    for (int L = 0; L < 3; ++L) {
        for (int j = 0; j < levLen[L]; ++j, ++idx) {
            float c = cs[idx];
            const float* mp = (j == 0) ? out : Mbuf;   // level start: M0 = Y0 = X
            int doM = (j == levLen[L]-1) ? 0 : 1;
            ns_kernel<<<batch, NTG, 0, stream>>>(mp, out, Mbuf, out,
                                                 c, sqrtf(c), doM);
        }
    }

    // Chebyshev-minimax log, deg 10 on [0.25, 1.002]; tail ~1.6e-6 (x8 -> 1.3e-5)
    const double lo = 0.25, up = 1.002;
    const double mid = 0.5*(lo+up), hw = 0.5*(up-lo);
    double p[11];
    cheb_log_power(lo, up, 10, p);

    horner_init<<<batch, 256, 0, stream>>>(out, Mbuf,
        (float)(p[10]/hw), (float)(p[9] - p[10]*mid/hw));
    for (int j = 8; j >= 1; --j)
        poly_kernel<<<batch, NTG, 0, stream>>>(out, Mbuf, Mbuf,
            (float)(1.0/hw), (float)(mid/hw), (float)p[j], (const float*)nullptr);
    // final: out = 8*(X*P - mid/hw*P + p0 I) + ln(s) I
    poly_kernel<<<batch, NTG, 0, stream>>>(out, Mbuf, out,
        (float)(8.0/hw), (float)(8.0*mid/hw), (float)(8.0*p[0]), lns);
}

// Round 8
// 11907.371 us; speedup vs baseline: 10.0975x; 1.7889x over previous
//
#include <hip/hip_runtime.h>
#include <hip/hip_bf16.h>
#include <math.h>

#define NM   128
#define PAD  132   // f32 LDS pitch for f32 kernels
#define NTG  512
#define PB   136   // pitch for MFMA LDS tiles (u16 units for bf16, f32 units for T)

typedef __attribute__((ext_vector_type(8))) short bf16x8;
typedef __attribute__((ext_vector_type(4))) float f32x4;

// ============================================================================
// log(A) = ln(s) I + 8 * cheb_log( NS_sqrt^3( A/s ) ).
// s = Gershgorin(A) tightened by sqrt(Gershgorin((A/s0)^2)).
// L1 iters 0-3: f32 VALU kernels (precision-critical).
// Later: bf16 2-way-split 3-product MFMA, lower-triangle tiles + mirror-write
// + symdiag on the FULL epilogue output (round-6 lesson: exact symmetry).
// ROUND-7 ROOT CAUSE: epi_M read the 9M passthrough from GLOBAL Mp, which at
// L2/L3 level starts aliases outY(=out) already overwritten by phase 1 ->
// M' built from Y' instead of M -> deterministic O(1) corruption. Fix: read
// M from the LDS split staged at kernel entry (exact to 2^-18, symmetric).
// ============================================================================

// ---------------------------------------------------------------- f32 kernels
__global__ __launch_bounds__(256,1)
void scale_kernel(const float* __restrict__ A, float* __restrict__ outY,
                  float* __restrict__ outM, float* __restrict__ lns)
{
    __shared__ __align__(16) float L[NM][PAD];
    __shared__ float rs[NM];
    __shared__ float s_inv;
    const int t = threadIdx.x;
    const long long b = blockIdx.x;
    const long long off = b << 14;
    for (int v = 0; v < 16; ++v) {
        int f = t + v*256;
        int row = f >> 5, c4 = (f & 31) << 2;
        *(float4*)&L[row][c4] = ((const float4*)(A + off))[f];
    }
    __syncthreads();
    if (t < NM) {
        float s = 0.f;
        for (int j = 0; j < NM; ++j) s += fabsf(L[t][j]);
        rs[t] = s;
    }
    __syncthreads();
    if (t < 64) {
        float m = fmaxf(rs[t], rs[t+64]);
        #pragma unroll
        for (int o = 32; o > 0; o >>= 1) m = fmaxf(m, __shfl_down(m, o, 64));
        if (t == 0) { s_inv = 1.0f/m; lns[b] = logf(m); }
    }
    __syncthreads();
    const float inv = s_inv;
    for (int v = 0; v < 16; ++v) {
        int f = t + v*256;
        int row = f >> 5, c4 = (f & 31) << 2;
        float4 x = *(const float4*)&L[row][c4];
        x.x *= inv; x.y *= inv; x.z *= inv; x.w *= inv;
        ((float4*)(outY + off))[f] = x;
        ((float4*)(outM + off))[f] = x;
    }
}

// reads Sq = X0^2; g = gersh(Sq) >= lmax(X0)^2; X = X0/sqrt(g) -> out & Mbuf
__global__ __launch_bounds__(256,1)
void rescale_kernel(const float* __restrict__ Sq, float* __restrict__ X,
                    float* __restrict__ M, float* __restrict__ lns)
{
    __shared__ __align__(16) float L[NM][PAD];
    __shared__ float rs[NM];
    __shared__ float s_g;
    const int t = threadIdx.x;
    const long long b = blockIdx.x;
    const long long off = b << 14;
    for (int v = 0; v < 16; ++v) {
        int f = t + v*256;
        int row = f >> 5, c4 = (f & 31) << 2;
        *(float4*)&L[row][c4] = ((const float4*)(Sq + off))[f];
    }
    __syncthreads();
    if (t < NM) {
        float s = 0.f;
        for (int j = 0; j < NM; ++j) s += fabsf(L[t][j]);
        rs[t] = s;
    }
    __syncthreads();
    if (t < 64) {
        float m = fmaxf(rs[t], rs[t+64]);
        #pragma unroll
        for (int o = 32; o > 0; o >>= 1) m = fmaxf(m, __shfl_down(m, o, 64));
        if (t == 0) { s_g = 1.0f/sqrtf(m); lns[b] = lns[b] + 0.5f*logf(m); }
    }
    __syncthreads();
    const float g = s_g;
    for (int v = 0; v < 16; ++v) {
        int f = t + v*256;
        float4 x = ((const float4*)(X + off))[f];
        x.x *= g; x.y *= g; x.z *= g; x.w *= g;
        ((float4*)(X + off))[f] = x;
        ((float4*)(M + off))[f] = x;
    }
}

__global__ __launch_bounds__(NTG,1)
void ns_kernel(const float* __restrict__ Mp, const float* __restrict__ Yp,
               float* __restrict__ outM, float* __restrict__ outY,
               float cc, float dd, int doM)
{
    __shared__ __align__(16) float LM[NM][PAD];
    __shared__ __align__(16) float LB[NM][PAD];
    const int t = threadIdx.x;
    const long long off = (long long)blockIdx.x << 14;
    for (int v = 0; v < 8; ++v) {
        int f = t + v*NTG;
        int row = f >> 5, c4 = (f & 31) << 2;
        *(float4*)&LM[row][c4] = ((const float4*)(Mp + off))[f];
        *(float4*)&LB[row][c4] = ((const float4*)(Yp + off))[f];
    }
    __syncthreads();
    for (int idx = t; idx < NM*NM; idx += NTG) {
        int i = idx >> 7, j = idx & 127;
        if (i < j) {
            float a = 0.5f*(LM[i][j] + LM[j][i]);
            LM[i][j] = a; LM[j][i] = a;
            float y = 0.5f*(LB[i][j] + LB[j][i]);
            LB[i][j] = y; LB[j][i] = y;
        }
    }
    __syncthreads();

    const int r0 = (t >> 4) << 2;
    const int ca = (t & 15) << 2;
    const int cb = ca + 64;
    float acc[4][8];

    #pragma unroll
    for (int i = 0; i < 4; ++i)
        #pragma unroll
        for (int j = 0; j < 8; ++j) acc[i][j] = 0.f;
    #pragma unroll 8
    for (int k = 0; k < NM; ++k) {
        float av[4], bv[8];
        *(float4*)&av[0] = *(const float4*)&LB[k][r0];
        *(float4*)&bv[0] = *(const float4*)&LM[k][ca];
        *(float4*)&bv[4] = *(const float4*)&LM[k][cb];
        #pragma unroll
        for (int i = 0; i < 4; ++i)
            #pragma unroll
            for (int j = 0; j < 8; ++j) acc[i][j] = fmaf(av[i], bv[j], acc[i][j]);
    }
    const float a15 = 1.5f*dd, a05 = 0.5f*dd;
    #pragma unroll
    for (int i = 0; i < 4; ++i) {
        float4 o;
        o.x = a15*LB[r0+i][ca+0] - a05*acc[i][0];
        o.y = a15*LB[r0+i][ca+1] - a05*acc[i][1];
        o.z = a15*LB[r0+i][ca+2] - a05*acc[i][2];
        o.w = a15*LB[r0+i][ca+3] - a05*acc[i][3];
        *(float4*)&outY[off + (long long)(r0+i)*NM + ca] = o;
        o.x = a15*LB[r0+i][cb+0] - a05*acc[i][4];
        o.y = a15*LB[r0+i][cb+1] - a05*acc[i][5];
        o.z = a15*LB[r0+i][cb+2] - a05*acc[i][6];
        o.w = a15*LB[r0+i][cb+3] - a05*acc[i][7];
        *(float4*)&outY[off + (long long)(r0+i)*NM + cb] = o;
    }

    if (doM) {
        __syncthreads();
        #pragma unroll
        for (int i = 0; i < 4; ++i)
            #pragma unroll
            for (int j = 0; j < 8; ++j) acc[i][j] = 0.f;
        #pragma unroll 8
        for (int k = 0; k < NM; ++k) {
            float av[4], bv[8];
            *(float4*)&av[0] = *(const float4*)&LM[k][r0];
            *(float4*)&bv[0] = *(const float4*)&LM[k][ca];
            *(float4*)&bv[4] = *(const float4*)&LM[k][cb];
            #pragma unroll
            for (int i = 0; i < 4; ++i)
                #pragma unroll
                for (int j = 0; j < 8; ++j) acc[i][j] = fmaf(av[i], bv[j], acc[i][j]);
        }
        #pragma unroll
        for (int i = 0; i < 4; ++i) {
            *(float4*)&LB[r0+i][ca] = make_float4(acc[i][0],acc[i][1],acc[i][2],acc[i][3]);
            *(float4*)&LB[r0+i][cb] = make_float4(acc[i][4],acc[i][5],acc[i][6],acc[i][7]);
        }
        __syncthreads();
        #pragma unroll
        for (int i = 0; i < 4; ++i)
            #pragma unroll
            for (int j = 0; j < 8; ++j) acc[i][j] = 0.f;
        #pragma unroll 8
        for (int k = 0; k < NM; ++k) {
            float av[4], bv[8];
            *(float4*)&av[0] = *(const float4*)&LM[k][r0];
            *(float4*)&bv[0] = *(const float4*)&LB[k][ca];
            *(float4*)&bv[4] = *(const float4*)&LB[k][cb];
            #pragma unroll
            for (int i = 0; i < 4; ++i)
                #pragma unroll
                for (int j = 0; j < 8; ++j) acc[i][j] = fmaf(av[i], bv[j], acc[i][j]);
        }
        const float q = 0.25f*cc;
        #pragma unroll
        for (int i = 0; i < 4; ++i) {
            float4 o;
            o.x = q*(9.f*LM[r0+i][ca+0] - 6.f*LB[r0+i][ca+0] + acc[i][0]);
            o.y = q*(9.f*LM[r0+i][ca+1] - 6.f*LB[r0+i][ca+1] + acc[i][1]);
            o.z = q*(9.f*LM[r0+i][ca+2] - 6.f*LB[r0+i][ca+2] + acc[i][2]);
            o.w = q*(9.f*LM[r0+i][ca+3] - 6.f*LB[r0+i][ca+3] + acc[i][3]);
            *(float4*)&outM[off + (long long)(r0+i)*NM + ca] = o;
            o.x = q*(9.f*LM[r0+i][cb+0] - 6.f*LB[r0+i][cb+0] + acc[i][4]);
            o.y = q*(9.f*LM[r0+i][cb+1] - 6.f*LB[r0+i][cb+1] + acc[i][5]);
            o.z = q*(9.f*LM[r0+i][cb+2] - 6.f*LB[r0+i][cb+2] + acc[i][6]);
            o.w = q*(9.f*LM[r0+i][cb+3] - 6.f*LB[r0+i][cb+3] + acc[i][7]);
            *(float4*)&outM[off + (long long)(r0+i)*NM + cb] = o;
        }
    }
}

__global__ __launch_bounds__(256,1)
void horner_init(const float* __restrict__ X, float* __restrict__ P, float a, float bd)
{
    const int t = threadIdx.x;
    const long long b = blockIdx.x;
    const long long off = b << 14;
    for (int v = 0; v < 16; ++v) {
        int f = t + v*256;
        float4 x = ((const float4*)(X + off))[f];
        int idx0 = f << 2;
        int row = idx0 >> 7, col = idx0 & 127;
        float4 o;
        o.x = a*x.x + ((col+0)==row ? bd : 0.f);
        o.y = a*x.y + ((col+1)==row ? bd : 0.f);
        o.z = a*x.z + ((col+2)==row ? bd : 0.f);
        o.w = a*x.w + ((col+3)==row ? bd : 0.f);
        ((float4*)(P + off))[f] = o;
    }
}

// f32 full GEMM (used once for X0^2); Out = s1*(X*P) - s2*P + (s3+lns?)*I
__global__ __launch_bounds__(NTG,1)
void poly_kernel(const float* __restrict__ X, const float* __restrict__ P,
                 float* __restrict__ Out, float s1, float s2, float s3,
                 const float* __restrict__ lns)
{
    __shared__ __align__(16) float LX[NM][PAD];
    __shared__ __align__(16) float LP[NM][PAD];
    const int t = threadIdx.x;
    const long long b = blockIdx.x;
    const long long off = b << 14;
    for (int v = 0; v < 8; ++v) {
        int f = t + v*NTG;
        int row = f >> 5, c4 = (f & 31) << 2;
        *(float4*)&LX[row][c4] = ((const float4*)(X + off))[f];
        *(float4*)&LP[row][c4] = ((const float4*)(P + off))[f];
    }
    __syncthreads();
    for (int idx = t; idx < NM*NM; idx += NTG) {
        int i = idx >> 7, j = idx & 127;
        if (i < j) {
            float a = 0.5f*(LX[i][j] + LX[j][i]);
            LX[i][j] = a; LX[j][i] = a;
            float p2 = 0.5f*(LP[i][j] + LP[j][i]);
            LP[i][j] = p2; LP[j][i] = p2;
        }
    }
    __syncthreads();
    const int r0 = (t >> 4) << 2;
    const int ca = (t & 15) << 2;
    const int cb = ca + 64;
    float acc[4][8];
    #pragma unroll
    for (int i = 0; i < 4; ++i)
        #pragma unroll
        for (int j = 0; j < 8; ++j) acc[i][j] = 0.f;
    #pragma unroll 8
    for (int k = 0; k < NM; ++k) {
        float av[4], bv[8];
        *(float4*)&av[0] = *(const float4*)&LX[k][r0];
        *(float4*)&bv[0] = *(const float4*)&LP[k][ca];
        *(float4*)&bv[4] = *(const float4*)&LP[k][cb];
        #pragma unroll
        for (int i = 0; i < 4; ++i)
            #pragma unroll
            for (int j = 0; j < 8; ++j) acc[i][j] = fmaf(av[i], bv[j], acc[i][j]);
    }
    const float dadd = s3 + (lns ? lns[b] : 0.f);
    #pragma unroll
    for (int i = 0; i < 4; ++i) {
        float4 o;
        o.x = s1*acc[i][0] - s2*LP[r0+i][ca+0] + ((r0+i)==(ca+0) ? dadd : 0.f);
        o.y = s1*acc[i][1] - s2*LP[r0+i][ca+1] + ((r0+i)==(ca+1) ? dadd : 0.f);
        o.z = s1*acc[i][2] - s2*LP[r0+i][ca+2] + ((r0+i)==(ca+2) ? dadd : 0.f);
        o.w = s1*acc[i][3] - s2*LP[r0+i][ca+3] + ((r0+i)==(ca+3) ? dadd : 0.f);
        *(float4*)&Out[off + (long long)(r0+i)*NM + ca] = o;
        o.x = s1*acc[i][4] - s2*LP[r0+i][cb+0] + ((r0+i)==(cb+0) ? dadd : 0.f);
        o.y = s1*acc[i][5] - s2*LP[r0+i][cb+1] + ((r0+i)==(cb+1) ? dadd : 0.f);
        o.z = s1*acc[i][6] - s2*LP[r0+i][cb+2] + ((r0+i)==(cb+2) ? dadd : 0.f);
        o.w = s1*acc[i][7] - s2*LP[r0+i][cb+3] + ((r0+i)==(cb+3) ? dadd : 0.f);
        *(float4*)&Out[off + (long long)(r0+i)*NM + cb] = o;
    }
}

// ---------------------------------------------------------------- MFMA path
__device__ __forceinline__ f32x4 mfma16(bf16x8 a, bf16x8 b, f32x4 c) {
    return __builtin_amdgcn_mfma_f32_16x16x32_bf16(a, b, c, 0, 0, 0);
}

__device__ __forceinline__ void splitbf(float x, unsigned short &h, unsigned short &l) {
    __hip_bfloat16 bh = __float2bfloat16(x);
    float r = x - __bfloat162float(bh);
    __hip_bfloat16 bl = __float2bfloat16(r);
    h = *(unsigned short*)&bh;
    l = *(unsigned short*)&bl;
}

// reconstruct f32 M value from the staged LDS split (exact to 2^-18 rel)
__device__ __forceinline__ float ldsM(const unsigned short* __restrict__ Mh,
                                      const unsigned short* __restrict__ Ml,
                                      int row, int col) {
    unsigned int uh = ((unsigned int)Mh[row*PB + col]) << 16;
    unsigned int ul = ((unsigned int)Ml[row*PB + col]) << 16;
    return __uint_as_float(uh) + __uint_as_float(ul);
}

// A/B fragment: row/col = rb*16 + (lane&15); k = kc*32 + (lane>>4)*8 + j.
__device__ __forceinline__ bf16x8 ldfrag(const unsigned short* __restrict__ a,
                                         int rb, int lane, int kc) {
    int row = rb*16 + (lane & 15);
    int col = kc*32 + ((lane >> 4) & 3)*8;
    return *(const bf16x8*)(a + row*PB + col);
}

__device__ __forceinline__ void ldfragT(const float* __restrict__ T, int rb, int lane,
                                        int kc, bf16x8 &h, bf16x8 &l) {
    int row = rb*16 + (lane & 15);
    int col = kc*32 + ((lane >> 4) & 3)*8;
    const float* p = T + row*PB + col;
    float4 x0 = *(const float4*)p;
    float4 x1 = *(const float4*)(p + 4);
    unsigned short hh, ll;
    splitbf(x0.x,hh,ll); h[0]=(short)hh; l[0]=(short)ll;
    splitbf(x0.y,hh,ll); h[1]=(short)hh; l[1]=(short)ll;
    splitbf(x0.z,hh,ll); h[2]=(short)hh; l[2]=(short)ll;
    splitbf(x0.w,hh,ll); h[3]=(short)hh; l[3]=(short)ll;
    splitbf(x1.x,hh,ll); h[4]=(short)hh; l[4]=(short)ll;
    splitbf(x1.y,hh,ll); h[5]=(short)hh; l[5]=(short)ll;
    splitbf(x1.z,hh,ll); h[6]=(short)hh; l[6]=(short)ll;
    splitbf(x1.w,hh,ll); h[7]=(short)hh; l[7]=(short)ll;
}

// Exact symmetrization of a DIAGONAL 16x16 tile held across the wave.
// C/D layout: element (i,j): lane = j + 16*(i>>2), reg = i&3.
__device__ __forceinline__ f32x4 symdiag(f32x4 a, int lane) {
    const int g = (lane >> 4) & 3, j = lane & 15;
    const int rp = j & 3;
    f32x4 out;
    #pragma unroll
    for (int r = 0; r < 4; ++r) {
        int lp = 4*g + r + ((j >> 2) << 4);
        float t0 = __shfl(a[0], lp, 64);
        float t1 = __shfl(a[1], lp, 64);
        float t2 = __shfl(a[2], lp, 64);
        float t3 = __shfl(a[3], lp, 64);
        float tv = (rp == 0) ? t0 : (rp == 1) ? t1 : (rp == 2) ? t2 : t3;
        out[r] = 0.5f*(a[r] + tv);
    }
    return out;
}

// C/D layout (m89 HW-verified): col = lane&15, row = (lane>>4)*4 + reg.
// epi_axpy's Src read is same-thread in-place (read-before-write): safe.
__device__ __forceinline__ void epi_axpy(float* __restrict__ out, const float* __restrict__ Src,
                                         long long off, int Tr, int Tc, int lane,
                                         f32x4 a, float a15, float a05) {
    int col = Tc*16 + (lane & 15);
    int rb  = Tr*16 + ((lane >> 4) & 3)*4;
    f32x4 o;
    #pragma unroll
    for (int r = 0; r < 4; ++r) {
        float y = Src[off + (long long)(rb+r)*NM + col];
        o[r] = a15*y - a05*a[r];
    }
    if (Tr == Tc) o = symdiag(o, lane);
    #pragma unroll
    for (int r = 0; r < 4; ++r)
        out[off + (long long)(rb+r)*NM + col] = o[r];
    if (Tr != Tc)
        *(f32x4*)&out[off + (long long)col*NM + rb] = o;
}

__device__ __forceinline__ void epi_T(float* __restrict__ T, int Tr, int Tc, int lane, f32x4 a) {
    int col = Tc*16 + (lane & 15);
    int rb  = Tr*16 + ((lane >> 4) & 3)*4;
    T[(rb+0)*PB + col] = a[0];
    T[(rb+1)*PB + col] = a[1];
    T[(rb+2)*PB + col] = a[2];
    T[(rb+3)*PB + col] = a[3];
    if (Tr != Tc) *(f32x4*)&T[col*PB + rb] = a;
}

// ROUND-7 FIX: M passthrough from LDS split (never from global Mp, which can
// alias outY at level starts).
__device__ __forceinline__ void epi_M(float* __restrict__ outM,
                                      const unsigned short* __restrict__ Mh,
                                      const unsigned short* __restrict__ Ml,
                                      const float* __restrict__ T, long long off,
                                      int Tr, int Tc, int lane, f32x4 a, float q) {
    int col = Tc*16 + (lane & 15);
    int rb  = Tr*16 + ((lane >> 4) & 3)*4;
    f32x4 o;
    #pragma unroll
    for (int r = 0; r < 4; ++r) {
        float mm = ldsM(Mh, Ml, rb+r, col);
        float tt = T[(rb+r)*PB + col];
        o[r] = q*(9.f*mm - 6.f*tt + a[r]);
    }
    if (Tr == Tc) o = symdiag(o, lane);
    #pragma unroll
    for (int r = 0; r < 4; ++r)
        outM[off + (long long)(rb+r)*NM + col] = o[r];
    if (Tr != Tc)
        *(f32x4*)&outM[off + (long long)col*NM + rb] = o;
}

__device__ __forceinline__ void epi_poly(float* __restrict__ Out, const float* __restrict__ Pp,
                                         long long off, int Tr, int Tc, int lane,
                                         f32x4 a, float s1, float s2, float dadd) {
    int col = Tc*16 + (lane & 15);
    int rb  = Tr*16 + ((lane >> 4) & 3)*4;
    f32x4 o;
    #pragma unroll
    for (int r = 0; r < 4; ++r) {
        float p = Pp[off + (long long)(rb+r)*NM + col];
        o[r] = s1*a[r] - s2*p + ((rb+r) == col ? dadd : 0.f);
    }
    if (Tr == Tc) o = symdiag(o, lane);
    #pragma unroll
    for (int r = 0; r < 4; ++r)
        Out[off + (long long)(rb+r)*NM + col] = o[r];
    if (Tr != Tc)
        *(f32x4*)&Out[off + (long long)col*NM + rb] = o;
}

// Wave W owns row-blocks R0=W (cols 0..W) and R1=7-W (cols 0..7-W): 9 tiles.
template<int W>
__device__ __forceinline__ void ns_body(
    const unsigned short* Mh, const unsigned short* Ml,
    const unsigned short* Yh, const unsigned short* Yl, float* T,
    const float* Yp, float* outM, float* outY,
    long long off, int lane, float cc, float dd, int doM)
{
    constexpr int R0 = W, R1 = 7 - W;
    const f32x4 z = {0.f, 0.f, 0.f, 0.f};
    f32x4 acc0[R0+1], acc1[R1+1];

    // ---- phase 1: Y*M ----
    #pragma unroll
    for (int c = 0; c <= R0; ++c) acc0[c] = z;
    #pragma unroll
    for (int c = 0; c <= R1; ++c) acc1[c] = z;
    #pragma unroll
    for (int kc = 0; kc < 4; ++kc) {
        bf16x8 a0h = ldfrag(Yh, R0, lane, kc), a0l = ldfrag(Yl, R0, lane, kc);
        bf16x8 a1h = ldfrag(Yh, R1, lane, kc), a1l = ldfrag(Yl, R1, lane, kc);
        #pragma unroll
        for (int c = 0; c <= R1; ++c) {
            bf16x8 bh = ldfrag(Mh, c, lane, kc), bl = ldfrag(Ml, c, lane, kc);
            if (c <= R0) {
                acc0[c] = mfma16(a0h, bh, acc0[c]);
                acc0[c] = mfma16(a0h, bl, acc0[c]);
                acc0[c] = mfma16(a0l, bh, acc0[c]);
            }
            acc1[c] = mfma16(a1h, bh, acc1[c]);
            acc1[c] = mfma16(a1h, bl, acc1[c]);
            acc1[c] = mfma16(a1l, bh, acc1[c]);
        }
    }
    const float a15 = 1.5f*dd, a05 = 0.5f*dd;
    #pragma unroll
    for (int c = 0; c <= R0; ++c) epi_axpy(outY, Yp, off, R0, c, lane, acc0[c], a15, a05);
    #pragma unroll
    for (int c = 0; c <= R1; ++c) epi_axpy(outY, Yp, off, R1, c, lane, acc1[c], a15, a05);

    if (!doM) return;
    __syncthreads();   // all waves done reading Y-frags; T overlays Yh/Yl

    // ---- phase 2: T = M*M^T (Gram: exactly symmetric) ----
    #pragma unroll
    for (int c = 0; c <= R0; ++c) acc0[c] = z;
    #pragma unroll
    for (int c = 0; c <= R1; ++c) acc1[c] = z;
    #pragma unroll
    for (int kc = 0; kc < 4; ++kc) {
        bf16x8 a0h = ldfrag(Mh, R0, lane, kc), a0l = ldfrag(Ml, R0, lane, kc);
        bf16x8 a1h = ldfrag(Mh, R1, lane, kc), a1l = ldfrag(Ml, R1, lane, kc);
        #pragma unroll
        for (int c = 0; c <= R1; ++c) {
            bf16x8 bh = ldfrag(Mh, c, lane, kc), bl = ldfrag(Ml, c, lane, kc);
            if (c <= R0) {
                acc0[c] = mfma16(a0h, bh, acc0[c]);
                acc0[c] = mfma16(a0h, bl, acc0[c]);
                acc0[c] = mfma16(a0l, bh, acc0[c]);
            }
            acc1[c] = mfma16(a1h, bh, acc1[c]);
            acc1[c] = mfma16(a1h, bl, acc1[c]);
            acc1[c] = mfma16(a1l, bh, acc1[c]);
        }
    }
    #pragma unroll
    for (int c = 0; c <= R0; ++c) epi_T(T, R0, c, lane, acc0[c]);
    #pragma unroll
    for (int c = 0; c <= R1; ++c) epi_T(T, R1, c, lane, acc1[c]);
    __syncthreads();

    // ---- phase 3: M*T ----
    #pragma unroll
    for (int c = 0; c <= R0; ++c) acc0[c] = z;
    #pragma unroll
    for (int c = 0; c <= R1; ++c) acc1[c] = z;
    #pragma unroll
    for (int kc = 0; kc < 4; ++kc) {
        bf16x8 a0h = ldfrag(Mh, R0, lane, kc), a0l = ldfrag(Ml, R0, lane, kc);
        bf16x8 a1h = ldfrag(Mh, R1, lane, kc), a1l = ldfrag(Ml, R1, lane, kc);
        #pragma unroll
        for (int c = 0; c <= R1; ++c) {
            bf16x8 bh, bl;
            ldfragT(T, c, lane, kc, bh, bl);
            if (c <= R0) {
                acc0[c] = mfma16(a0h, bh, acc0[c]);
                acc0[c] = mfma16(a0h, bl, acc0[c]);
                acc0[c] = mfma16(a0l, bh, acc0[c]);
            }
            acc1[c] = mfma16(a1h, bh, acc1[c]);
            acc1[c] = mfma16(a1h, bl, acc1[c]);
            acc1[c] = mfma16(a1l, bh, acc1[c]);
        }
    }
    const float q = 0.25f*cc;
    #pragma unroll
    for (int c = 0; c <= R0; ++c) epi_M(outM, Mh, Ml, T, off, R0, c, lane, acc0[c], q);
    #pragma unroll
    for (int c = 0; c <= R1; ++c) epi_M(outM, Mh, Ml, T, off, R1, c, lane, acc1[c], q);
}

__global__ __launch_bounds__(256,1)
void ns_mfma(const float* __restrict__ Mp, const float* __restrict__ Yp,
             float* __restrict__ outM, float* __restrict__ outY,
             float cc, float dd, int doM)
{
    __shared__ __align__(16) unsigned short pool[4*NM*PB];
    unsigned short* Mh = pool;
    unsigned short* Ml = pool + NM*PB;
    unsigned short* Yh = pool + 2*NM*PB;
    unsigned short* Yl = pool + 3*NM*PB;
    float* T = (float*)(pool + 2*NM*PB);

    const int t = threadIdx.x;
    const long long off = (long long)blockIdx.x << 14;
    for (int v = 0; v < 16; ++v) {
        int f = t + v*256;
        int row = f >> 5, c4 = (f & 31) << 2;
        float4 x = ((const float4*)(Mp + off))[f];
        ushort4 h, l;
        splitbf(x.x, h.x, l.x); splitbf(x.y, h.y, l.y);
        splitbf(x.z, h.z, l.z); splitbf(x.w, h.w, l.w);
        *(ushort4*)&Mh[row*PB + c4] = h;
        *(ushort4*)&Ml[row*PB + c4] = l;
        x = ((const float4*)(Yp + off))[f];
        splitbf(x.x, h.x, l.x); splitbf(x.y, h.y, l.y);
        splitbf(x.z, h.z, l.z); splitbf(x.w, h.w, l.w);
        *(ushort4*)&Yh[row*PB + c4] = h;
        *(ushort4*)&Yl[row*PB + c4] = l;
    }
    __syncthreads();

    const int lane = t & 63;
    const int w = t >> 6;
    switch (w) {
        case 0:  ns_body<0>(Mh,Ml,Yh,Yl,T,Yp,outM,outY,off,lane,cc,dd,doM); break;
        case 1:  ns_body<1>(Mh,Ml,Yh,Yl,T,Yp,outM,outY,off,lane,cc,dd,doM); break;
        case 2:  ns_body<2>(Mh,Ml,Yh,Yl,T,Yp,outM,outY,off,lane,cc,dd,doM); break;
        default: ns_body<3>(Mh,Ml,Yh,Yl,T,Yp,outM,outY,off,lane,cc,dd,doM); break;
    }
}

template<int W>
__device__ __forceinline__ void poly_body(
    const unsigned short* Xh, const unsigned short* Xl,
    const unsigned short* Ph, const unsigned short* Pl,
    const float* Pp, float* Out, long long off, int lane,
    float s1, float s2, float dadd)
{
    constexpr int R0 = W, R1 = 7 - W;
    const f32x4 z = {0.f, 0.f, 0.f, 0.f};
    f32x4 acc0[R0+1], acc1[R1+1];
    #pragma unroll
    for (int c = 0; c <= R0; ++c) acc0[c] = z;
    #pragma unroll
    for (int c = 0; c <= R1; ++c) acc1[c] = z;
    #pragma unroll
    for (int kc = 0; kc < 4; ++kc) {
        bf16x8 a0h = ldfrag(Xh, R0, lane, kc), a0l = ldfrag(Xl, R0, lane, kc);
        bf16x8 a1h = ldfrag(Xh, R1, lane, kc), a1l = ldfrag(Xl, R1, lane, kc);
        #pragma unroll
        for (int c = 0; c <= R1; ++c) {
            bf16x8 bh = ldfrag(Ph, c, lane, kc), bl = ldfrag(Pl, c, lane, kc);
            if (c <= R0) {
                acc0[c] = mfma16(a0h, bh, acc0[c]);
                acc0[c] = mfma16(a0h, bl, acc0[c]);
                acc0[c] = mfma16(a0l, bh, acc0[c]);
            }
            acc1[c] = mfma16(a1h, bh, acc1[c]);
            acc1[c] = mfma16(a1h, bl, acc1[c]);
            acc1[c] = mfma16(a1l, bh, acc1[c]);
        }
    }
    #pragma unroll
    for (int c = 0; c <= R0; ++c) epi_poly(Out, Pp, off, R0, c, lane, acc0[c], s1, s2, dadd);
    #pragma unroll
    for (int c = 0; c <= R1; ++c) epi_poly(Out, Pp, off, R1, c, lane, acc1[c], s1, s2, dadd);
}

__global__ __launch_bounds__(256,1)
void poly_mfma(const float* __restrict__ Xp, const float* __restrict__ Pp,
               float* __restrict__ Out, float s1, float s2, float s3,
               const float* __restrict__ lns)
{
    __shared__ __align__(16) unsigned short pool[4*NM*PB];
    unsigned short* Xh = pool;
    unsigned short* Xl = pool + NM*PB;
    unsigned short* Ph = pool + 2*NM*PB;
    unsigned short* Pl = pool + 3*NM*PB;

    const int t = threadIdx.x;
    const long long b = blockIdx.x;
    const long long off = b << 14;
    for (int v = 0; v < 16; ++v) {
        int f = t + v*256;
        int row = f >> 5, c4 = (f & 31) << 2;
        float4 x = ((const float4*)(Xp + off))[f];
        ushort4 h, l;
        splitbf(x.x, h.x, l.x); splitbf(x.y, h.y, l.y);
        splitbf(x.z, h.z, l.z); splitbf(x.w, h.w, l.w);
        *(ushort4*)&Xh[row*PB + c4] = h;
        *(ushort4*)&Xl[row*PB + c4] = l;
        x = ((const float4*)(Pp + off))[f];
        splitbf(x.x, h.x, l.x); splitbf(x.y, h.y, l.y);
        splitbf(x.z, h.z, l.z); splitbf(x.w, h.w, l.w);
        *(ushort4*)&Ph[row*PB + c4] = h;
        *(ushort4*)&Pl[row*PB + c4] = l;
    }
    __syncthreads();

    const float dadd = s3 + (lns ? lns[b] : 0.f);
    const int lane = t & 63;
    const int w = t >> 6;
    switch (w) {
        case 0:  poly_body<0>(Xh,Xl,Ph,Pl,Pp,Out,off,lane,s1,s2,dadd); break;
        case 1:  poly_body<1>(Xh,Xl,Ph,Pl,Pp,Out,off,lane,s1,s2,dadd); break;
        case 2:  poly_body<2>(Xh,Xl,Ph,Pl,Pp,Out,off,lane,s1,s2,dadd); break;
        default: poly_body<3>(Xh,Xl,Ph,Pl,Pp,Out,off,lane,s1,s2,dadd); break;
    }
}

// ============================================================================
// Fallback (ws too small): round-1 parallel Jacobi
// ============================================================================
#define LDA  129
#define NT   512
#define MAX_SWEEPS 14

__global__ __launch_bounds__(NT, 1)
void logeig_jacobi(const float* __restrict__ in, float* __restrict__ out)
{
    __shared__ float A[NM][LDA];
    __shared__ float V[NM][LDA];
    __shared__ float rc[64], rs[64];
    __shared__ float logd[NM];
    __shared__ float roff[NT/64], rdia[NT/64];
    __shared__ int   s_done;

    const int t = threadIdx.x;
    const long long b = blockIdx.x;
    const float* __restrict__ Ain  = in  + (b << 14);
    float* __restrict__       Aout = out + (b << 14);

    for (int k = 0; k < (NM*NM)/NT; ++k) {
        int idx = t + k*NT;
        int i = idx >> 7, j = idx & 127;
        A[i][j] = Ain[idx];
        V[i][j] = (i == j) ? 1.0f : 0.0f;
    }
    __syncthreads();

    for (int sweep = 0; sweep < MAX_SWEEPS; ++sweep) {
        for (int r = 0; r < NM-1; ++r) {
            if (t < 64) {
                int m = t, p, q;
                if (m == 0) { p = NM-1; q = r; }
                else {
                    p = r + m;            if (p >= NM-1) p -= (NM-1);
                    q = r - m + (NM-1);   if (q >= NM-1) q -= (NM-1);
                }
                float app = A[p][p], aqq = A[q][q], apq = A[p][q];
                float c = 1.0f, s = 0.0f;
                if (fabsf(apq) > 1e-12f*(fabsf(app)+fabsf(aqq)) + 1e-32f) {
                    float tau = (aqq - app) * 0.5f / apq;
                    float tt  = 1.0f / (fabsf(tau) + sqrtf(fmaf(tau,tau,1.0f)));
                    tt = (tau < 0.0f) ? -tt : tt;
                    c = rsqrtf(fmaf(tt,tt,1.0f));
                    s = tt * c;
                }
                rc[m] = c; rs[m] = s;
            }
            __syncthreads();
            for (int k = 0; k < (2*64*NM)/NT; ++k) {
                int task = t + k*NT;
                int i   = task & 127;
                int m   = (task >> 7) & 63;
                int isV = task >> 13;
                int p, q;
                if (m == 0) { p = NM-1; q = r; }
                else {
                    p = r + m;            if (p >= NM-1) p -= (NM-1);
                    q = r - m + (NM-1);   if (q >= NM-1) q -= (NM-1);
                }
                float c = rc[m], s = rs[m];
                if (isV == 0) {
                    float x = A[i][p], y = A[i][q];
                    A[i][p] = c*x - s*y;
                    A[i][q] = s*x + c*y;
                } else {
                    float x = V[i][p], y = V[i][q];
                    V[i][p] = c*x - s*y;
                    V[i][q] = s*x + c*y;
                }
            }
            __syncthreads();
            for (int k = 0; k < (64*NM)/NT; ++k) {
                int task = t + k*NT;
                int j = task & 127;
                int m = task >> 7;
                int p, q;
                if (m == 0) { p = NM-1; q = r; }
                else {
                    p = r + m;            if (p >= NM-1) p -= (NM-1);
                    q = r - m + (NM-1);   if (q >= NM-1) q -= (NM-1);
                }
                float c = rc[m], s = rs[m];
                float x = A[p][j], y = A[q][j];
                A[p][j] = c*x - s*y;
                A[q][j] = s*x + c*y;
            }
            __syncthreads();
        }
        float off2 = 0.0f, dia2 = 0.0f;
        for (int k = 0; k < (NM*NM)/NT; ++k) {
            int idx = t + k*NT;
            int i = idx >> 7, j = idx & 127;
            float v = A[i][j];
            if (i == j) dia2 += v*v; else off2 += v*v;
        }
        #pragma unroll
        for (int o = 32; o > 0; o >>= 1) {
            off2 += __shfl_down(off2, o, 64);
            dia2 += __shfl_down(dia2, o, 64);
        }
        if ((t & 63) == 0) { roff[t >> 6] = off2; rdia[t >> 6] = dia2; }
        __syncthreads();
        if (t == 0) {
            float o2 = 0.0f, d2 = 0.0f;
            for (int w = 0; w < NT/64; ++w) { o2 += roff[w]; d2 += rdia[w]; }
            s_done = (o2 <= 1e-13f * d2) ? 1 : 0;
        }
        __syncthreads();
        if (s_done) break;
    }

    if (t < NM) logd[t] = logf(fmaxf(A[t][t], 1e-12f));
    __syncthreads();
    for (int kk = 0; kk < (NM*NM)/NT; ++kk) {
        int idx = t + kk*NT;
        int i = idx >> 7, k = idx & 127;
        A[i][k] = V[i][k] * logd[k];
    }
    __syncthreads();
    {
        int i  = t >> 2;
        int jb = t & 3;
        float acc[32];
        #pragma unroll
        for (int jj = 0; jj < 32; ++jj) acc[jj] = 0.0f;
        for (int kk = 0; kk < NM; ++kk) {
            int k = (kk + jb) & 127;
            float w = A[i][k];
            #pragma unroll
            for (int jj = 0; jj < 32; ++jj)
                acc[jj] = fmaf(w, V[jb*32 + jj][k], acc[jj]);
        }
        #pragma unroll
        for (int jj = 0; jj < 32; ++jj)
            Aout[i*NM + jb*32 + jj] = acc[jj];
    }
}

// ============================================================================
// Host
// ============================================================================
static void cheb_log_power(double lo, double up, int deg, double* p)
{
    const int NC = deg + 1;
    const int MN = 64;
    double mid = 0.5*(lo+up), hw = 0.5*(up-lo);
    double cc[32];
    for (int j = 0; j < NC; ++j) {
        double s = 0.0;
        for (int m = 0; m < MN; ++m) {
            double th = M_PI*(m+0.5)/MN;
            s += log(mid + hw*cos(th)) * cos(j*th);
        }
        cc[j] = 2.0*s/MN;
    }
    double Tp[32] = {0}, Tc[32] = {0}, Tn[32];
    for (int j = 0; j < NC; ++j) p[j] = 0.0;
    Tp[0] = 1.0;  p[0] += 0.5*cc[0];
    Tc[1] = 1.0;  p[1] += cc[1];
    for (int k = 2; k <= deg; ++k) {
        for (int j = 0; j < NC; ++j) Tn[j] = -Tp[j];
        for (int j = 1; j < NC; ++j) Tn[j] += 2.0*Tc[j-1];
        for (int j = 0; j < NC; ++j) { p[j] += cc[k]*Tn[j]; Tp[j] = Tc[j]; Tc[j] = Tn[j]; }
    }
}

extern "C" void kernel_launch(void* const* d_in, const int* in_sizes, int n_in,
                              void* d_out, int out_size, void* d_ws, size_t ws_size,
                              hipStream_t stream) {
    const float* in = (const float*)d_in[0];
    float* out = (float*)d_out;
    const int batch = in_sizes[0] >> 14;                 // 4096
    const size_t matBytes = (size_t)batch * NM * NM * 4; // 256 MB
    const size_t need = matBytes + (size_t)batch * 4;

    if (ws_size < need) {   // fallback
        logeig_jacobi<<<batch, NT, 0, stream>>>(in, out);
        return;
    }

    float* Mbuf = (float*)d_ws;
    float* lns  = (float*)((char*)d_ws + matBytes);

    // --- scaling: s0 = gersh(A); tighten via sqrt(gersh((A/s0)^2)) ---
    scale_kernel<<<batch, 256, 0, stream>>>(in, out, Mbuf, lns);      // out = X0
    poly_kernel<<<batch, NTG, 0, stream>>>(out, out, Mbuf, 1.f, 0.f, 0.f,
                                           (const float*)nullptr);    // Mbuf = X0^2
    rescale_kernel<<<batch, 256, 0, stream>>>(Mbuf, out, Mbuf, lns);  // out=Mbuf=X

    // --- L1 (12 iters, certified c<=1.5 from lmin=5e-5): iters 0-3 f32 ---
    for (int j = 0; j < 4; ++j)
        ns_kernel<<<batch, NTG, 0, stream>>>(Mbuf, out, Mbuf, out,
                                             1.5f, sqrtf(1.5f), 1);
    {   // L1 iters 4..11 in MFMA (mu_min grown enough for 3-product bf16)
        const float cs[8] = {1.5f,1.5f,1.5f,1.5f,1.5f,1.116f,1.0f,1.0f};
        for (int j = 0; j < 8; ++j)
            ns_mfma<<<batch, 256, 0, stream>>>(Mbuf, out, Mbuf, out,
                                               cs[j], sqrtf(cs[j]), (j==7)?0:1);
    }
    // --- L2 (8), L3 (6) fully MFMA ---
    {
        const float cs[8] = {1.5f,1.5f,1.5f,1.5f,1.5f,1.116f,1.0f,1.0f};
        for (int j = 0; j < 8; ++j)
            ns_mfma<<<batch, 256, 0, stream>>>((j==0)?out:Mbuf, out, Mbuf, out,
                                               cs[j], sqrtf(cs[j]), (j==7)?0:1);
    }
    {
        const float cs[6] = {1.5f,1.5f,1.5f,1.116f,1.0f,1.0f};
        for (int j = 0; j < 6; ++j)
            ns_mfma<<<batch, 256, 0, stream>>>((j==0)?out:Mbuf, out, Mbuf, out,
                                               cs[j], sqrtf(cs[j]), (j==5)?0:1);
    }

    // --- Chebyshev-minimax log, deg 10 on [0.25, 1.002] ---
    const double lo = 0.25, up = 1.002;
    const double mid = 0.5*(lo+up), hw = 0.5*(up-lo);
    double p[11];
    cheb_log_power(lo, up, 10, p);

    horner_init<<<batch, 256, 0, stream>>>(out, Mbuf,
        (float)(p[10]/hw), (float)(p[9] - p[10]*mid/hw));
    for (int j = 8; j >= 1; --j)
        poly_mfma<<<batch, 256, 0, stream>>>(out, Mbuf, Mbuf,
            (float)(1.0/hw), (float)(mid/hw), (float)p[j], (const float*)nullptr);
    poly_mfma<<<batch, 256, 0, stream>>>(out, Mbuf, out,
        (float)(8.0/hw), (float)(8.0*mid/hw), (float)(8.0*p[0]), lns);
}

// Round 9
// 9566.869 us; speedup vs baseline: 12.5678x; 1.2446x over previous
//
#include <hip/hip_runtime.h>
#include <hip/hip_bf16.h>
#include <math.h>

#define NM   128
#define PAD  132   // f32 LDS pitch for f32 kernels
#define NTG  512
#define PB   136   // pitch for MFMA LDS tiles (u16 units for bf16, f32 units for T)

typedef __attribute__((ext_vector_type(8))) short bf16x8;
typedef __attribute__((ext_vector_type(4))) float f32x4;

// ============================================================================
// log(A) = ln(s) I + 8 * cheb_log( NS_sqrt^3( A/s ) ).
// Round-9: LDS-persistent fusion. All MFMA NS iterations of a level run in ONE
// kernel (M,Y live as bf16 hi/lo splits in LDS; only Y_final goes to HBM).
// Whole Chebyshev chain fused likewise (X,P resident). Arithmetic identical to
// the round-8 PASS (absmax 0.0156): 3-product bf16-split MFMA, lower-triangle
// tiles + mirror-write, symdiag on full epilogue outputs, M passthrough from
// LDS splits (round-7 alias fix). Only change: Y/P passthroughs also from
// splits (+2^-16 rel) instead of global f32.
// ============================================================================

// ---------------------------------------------------------------- f32 kernels
__global__ __launch_bounds__(256,1)
void scale_kernel(const float* __restrict__ A, float* __restrict__ outY,
                  float* __restrict__ outM, float* __restrict__ lns)
{
    __shared__ __align__(16) float L[NM][PAD];
    __shared__ float rs[NM];
    __shared__ float s_inv;
    const int t = threadIdx.x;
    const long long b = blockIdx.x;
    const long long off = b << 14;
    for (int v = 0; v < 16; ++v) {
        int f = t + v*256;
        int row = f >> 5, c4 = (f & 31) << 2;
        *(float4*)&L[row][c4] = ((const float4*)(A + off))[f];
    }
    __syncthreads();
    if (t < NM) {
        float s = 0.f;
        for (int j = 0; j < NM; ++j) s += fabsf(L[t][j]);
        rs[t] = s;
    }
    __syncthreads();
    if (t < 64) {
        float m = fmaxf(rs[t], rs[t+64]);
        #pragma unroll
        for (int o = 32; o > 0; o >>= 1) m = fmaxf(m, __shfl_down(m, o, 64));
        if (t == 0) { s_inv = 1.0f/m; lns[b] = logf(m); }
    }
    __syncthreads();
    const float inv = s_inv;
    for (int v = 0; v < 16; ++v) {
        int f = t + v*256;
        int row = f >> 5, c4 = (f & 31) << 2;
        float4 x = *(const float4*)&L[row][c4];
        x.x *= inv; x.y *= inv; x.z *= inv; x.w *= inv;
        ((float4*)(outY + off))[f] = x;
        ((float4*)(outM + off))[f] = x;
    }
}

__global__ __launch_bounds__(256,1)
void rescale_kernel(const float* __restrict__ Sq, float* __restrict__ X,
                    float* __restrict__ M, float* __restrict__ lns)
{
    __shared__ __align__(16) float L[NM][PAD];
    __shared__ float rs[NM];
    __shared__ float s_g;
    const int t = threadIdx.x;
    const long long b = blockIdx.x;
    const long long off = b << 14;
    for (int v = 0; v < 16; ++v) {
        int f = t + v*256;
        int row = f >> 5, c4 = (f & 31) << 2;
        *(float4*)&L[row][c4] = ((const float4*)(Sq + off))[f];
    }
    __syncthreads();
    if (t < NM) {
        float s = 0.f;
        for (int j = 0; j < NM; ++j) s += fabsf(L[t][j]);
        rs[t] = s;
    }
    __syncthreads();
    if (t < 64) {
        float m = fmaxf(rs[t], rs[t+64]);
        #pragma unroll
        for (int o = 32; o > 0; o >>= 1) m = fmaxf(m, __shfl_down(m, o, 64));
        if (t == 0) { s_g = 1.0f/sqrtf(m); lns[b] = lns[b] + 0.5f*logf(m); }
    }
    __syncthreads();
    const float g = s_g;
    for (int v = 0; v < 16; ++v) {
        int f = t + v*256;
        float4 x = ((const float4*)(X + off))[f];
        x.x *= g; x.y *= g; x.z *= g; x.w *= g;
        ((float4*)(X + off))[f] = x;
        ((float4*)(M + off))[f] = x;
    }
}

__global__ __launch_bounds__(NTG,1)
void ns_kernel(const float* __restrict__ Mp, const float* __restrict__ Yp,
               float* __restrict__ outM, float* __restrict__ outY,
               float cc, float dd, int doM)
{
    __shared__ __align__(16) float LM[NM][PAD];
    __shared__ __align__(16) float LB[NM][PAD];
    const int t = threadIdx.x;
    const long long off = (long long)blockIdx.x << 14;
    for (int v = 0; v < 8; ++v) {
        int f = t + v*NTG;
        int row = f >> 5, c4 = (f & 31) << 2;
        *(float4*)&LM[row][c4] = ((const float4*)(Mp + off))[f];
        *(float4*)&LB[row][c4] = ((const float4*)(Yp + off))[f];
    }
    __syncthreads();
    for (int idx = t; idx < NM*NM; idx += NTG) {
        int i = idx >> 7, j = idx & 127;
        if (i < j) {
            float a = 0.5f*(LM[i][j] + LM[j][i]);
            LM[i][j] = a; LM[j][i] = a;
            float y = 0.5f*(LB[i][j] + LB[j][i]);
            LB[i][j] = y; LB[j][i] = y;
        }
    }
    __syncthreads();

    const int r0 = (t >> 4) << 2;
    const int ca = (t & 15) << 2;
    const int cb = ca + 64;
    float acc[4][8];

    #pragma unroll
    for (int i = 0; i < 4; ++i)
        #pragma unroll
        for (int j = 0; j < 8; ++j) acc[i][j] = 0.f;
    #pragma unroll 8
    for (int k = 0; k < NM; ++k) {
        float av[4], bv[8];
        *(float4*)&av[0] = *(const float4*)&LB[k][r0];
        *(float4*)&bv[0] = *(const float4*)&LM[k][ca];
        *(float4*)&bv[4] = *(const float4*)&LM[k][cb];
        #pragma unroll
        for (int i = 0; i < 4; ++i)
            #pragma unroll
            for (int j = 0; j < 8; ++j) acc[i][j] = fmaf(av[i], bv[j], acc[i][j]);
    }
    const float a15 = 1.5f*dd, a05 = 0.5f*dd;
    #pragma unroll
    for (int i = 0; i < 4; ++i) {
        float4 o;
        o.x = a15*LB[r0+i][ca+0] - a05*acc[i][0];
        o.y = a15*LB[r0+i][ca+1] - a05*acc[i][1];
        o.z = a15*LB[r0+i][ca+2] - a05*acc[i][2];
        o.w = a15*LB[r0+i][ca+3] - a05*acc[i][3];
        *(float4*)&outY[off + (long long)(r0+i)*NM + ca] = o;
        o.x = a15*LB[r0+i][cb+0] - a05*acc[i][4];
        o.y = a15*LB[r0+i][cb+1] - a05*acc[i][5];
        o.z = a15*LB[r0+i][cb+2] - a05*acc[i][6];
        o.w = a15*LB[r0+i][cb+3] - a05*acc[i][7];
        *(float4*)&outY[off + (long long)(r0+i)*NM + cb] = o;
    }

    if (doM) {
        __syncthreads();
        #pragma unroll
        for (int i = 0; i < 4; ++i)
            #pragma unroll
            for (int j = 0; j < 8; ++j) acc[i][j] = 0.f;
        #pragma unroll 8
        for (int k = 0; k < NM; ++k) {
            float av[4], bv[8];
            *(float4*)&av[0] = *(const float4*)&LM[k][r0];
            *(float4*)&bv[0] = *(const float4*)&LM[k][ca];
            *(float4*)&bv[4] = *(const float4*)&LM[k][cb];
            #pragma unroll
            for (int i = 0; i < 4; ++i)
                #pragma unroll
                for (int j = 0; j < 8; ++j) acc[i][j] = fmaf(av[i], bv[j], acc[i][j]);
        }
        #pragma unroll
        for (int i = 0; i < 4; ++i) {
            *(float4*)&LB[r0+i][ca] = make_float4(acc[i][0],acc[i][1],acc[i][2],acc[i][3]);
            *(float4*)&LB[r0+i][cb] = make_float4(acc[i][4],acc[i][5],acc[i][6],acc[i][7]);
        }
        __syncthreads();
        #pragma unroll
        for (int i = 0; i < 4; ++i)
            #pragma unroll
            for (int j = 0; j < 8; ++j) acc[i][j] = 0.f;
        #pragma unroll 8
        for (int k = 0; k < NM; ++k) {
            float av[4], bv[8];
            *(float4*)&av[0] = *(const float4*)&LM[k][r0];
            *(float4*)&bv[0] = *(const float4*)&LB[k][ca];
            *(float4*)&bv[4] = *(const float4*)&LB[k][cb];
            #pragma unroll
            for (int i = 0; i < 4; ++i)
                #pragma unroll
                for (int j = 0; j < 8; ++j) acc[i][j] = fmaf(av[i], bv[j], acc[i][j]);
        }
        const float q = 0.25f*cc;
        #pragma unroll
        for (int i = 0; i < 4; ++i) {
            float4 o;
            o.x = q*(9.f*LM[r0+i][ca+0] - 6.f*LB[r0+i][ca+0] + acc[i][0]);
            o.y = q*(9.f*LM[r0+i][ca+1] - 6.f*LB[r0+i][ca+1] + acc[i][1]);
            o.z = q*(9.f*LM[r0+i][ca+2] - 6.f*LB[r0+i][ca+2] + acc[i][2]);
            o.w = q*(9.f*LM[r0+i][ca+3] - 6.f*LB[r0+i][ca+3] + acc[i][3]);
            *(float4*)&outM[off + (long long)(r0+i)*NM + ca] = o;
            o.x = q*(9.f*LM[r0+i][cb+0] - 6.f*LB[r0+i][cb+0] + acc[i][4]);
            o.y = q*(9.f*LM[r0+i][cb+1] - 6.f*LB[r0+i][cb+1] + acc[i][5]);
            o.z = q*(9.f*LM[r0+i][cb+2] - 6.f*LB[r0+i][cb+2] + acc[i][6]);
            o.w = q*(9.f*LM[r0+i][cb+3] - 6.f*LB[r0+i][cb+3] + acc[i][7]);
            *(float4*)&outM[off + (long long)(r0+i)*NM + cb] = o;
        }
    }
}

// f32 full GEMM (used once for X0^2)
__global__ __launch_bounds__(NTG,1)
void poly_kernel(const float* __restrict__ X, const float* __restrict__ P,
                 float* __restrict__ Out, float s1, float s2, float s3,
                 const float* __restrict__ lns)
{
    __shared__ __align__(16) float LX[NM][PAD];
    __shared__ __align__(16) float LP[NM][PAD];
    const int t = threadIdx.x;
    const long long b = blockIdx.x;
    const long long off = b << 14;
    for (int v = 0; v < 8; ++v) {
        int f = t + v*NTG;
        int row = f >> 5, c4 = (f & 31) << 2;
        *(float4*)&LX[row][c4] = ((const float4*)(X + off))[f];
        *(float4*)&LP[row][c4] = ((const float4*)(P + off))[f];
    }
    __syncthreads();
    for (int idx = t; idx < NM*NM; idx += NTG) {
        int i = idx >> 7, j = idx & 127;
        if (i < j) {
            float a = 0.5f*(LX[i][j] + LX[j][i]);
            LX[i][j] = a; LX[j][i] = a;
            float p2 = 0.5f*(LP[i][j] + LP[j][i]);
            LP[i][j] = p2; LP[j][i] = p2;
        }
    }
    __syncthreads();
    const int r0 = (t >> 4) << 2;
    const int ca = (t & 15) << 2;
    const int cb = ca + 64;
    float acc[4][8];
    #pragma unroll
    for (int i = 0; i < 4; ++i)
        #pragma unroll
        for (int j = 0; j < 8; ++j) acc[i][j] = 0.f;
    #pragma unroll 8
    for (int k = 0; k < NM; ++k) {
        float av[4], bv[8];
        *(float4*)&av[0] = *(const float4*)&LX[k][r0];
        *(float4*)&bv[0] = *(const float4*)&LP[k][ca];
        *(float4*)&bv[4] = *(const float4*)&LP[k][cb];
        #pragma unroll
        for (int i = 0; i < 4; ++i)
            #pragma unroll
            for (int j = 0; j < 8; ++j) acc[i][j] = fmaf(av[i], bv[j], acc[i][j]);
    }
    const float dadd = s3 + (lns ? lns[b] : 0.f);
    #pragma unroll
    for (int i = 0; i < 4; ++i) {
        float4 o;
        o.x = s1*acc[i][0] - s2*LP[r0+i][ca+0] + ((r0+i)==(ca+0) ? dadd : 0.f);
        o.y = s1*acc[i][1] - s2*LP[r0+i][ca+1] + ((r0+i)==(ca+1) ? dadd : 0.f);
        o.z = s1*acc[i][2] - s2*LP[r0+i][ca+2] + ((r0+i)==(ca+2) ? dadd : 0.f);
        o.w = s1*acc[i][3] - s2*LP[r0+i][ca+3] + ((r0+i)==(ca+3) ? dadd : 0.f);
        *(float4*)&Out[off + (long long)(r0+i)*NM + ca] = o;
        o.x = s1*acc[i][4] - s2*LP[r0+i][cb+0] + ((r0+i)==(cb+0) ? dadd : 0.f);
        o.y = s1*acc[i][5] - s2*LP[r0+i][cb+1] + ((r0+i)==(cb+1) ? dadd : 0.f);
        o.z = s1*acc[i][6] - s2*LP[r0+i][cb+2] + ((r0+i)==(cb+2) ? dadd : 0.f);
        o.w = s1*acc[i][7] - s2*LP[r0+i][cb+3] + ((r0+i)==(cb+3) ? dadd : 0.f);
        *(float4*)&Out[off + (long long)(r0+i)*NM + cb] = o;
    }
}

// ---------------------------------------------------------------- MFMA common
__device__ __forceinline__ f32x4 mfma16(bf16x8 a, bf16x8 b, f32x4 c) {
    return __builtin_amdgcn_mfma_f32_16x16x32_bf16(a, b, c, 0, 0, 0);
}

__device__ __forceinline__ void splitbf(float x, unsigned short &h, unsigned short &l) {
    __hip_bfloat16 bh = __float2bfloat16(x);
    float r = x - __bfloat162float(bh);
    __hip_bfloat16 bl = __float2bfloat16(r);
    h = *(unsigned short*)&bh;
    l = *(unsigned short*)&bl;
}

__device__ __forceinline__ float ldsM(const unsigned short* __restrict__ H,
                                      const unsigned short* __restrict__ L,
                                      int row, int col) {
    unsigned int uh = ((unsigned int)H[row*PB + col]) << 16;
    unsigned int ul = ((unsigned int)L[row*PB + col]) << 16;
    return __uint_as_float(uh) + __uint_as_float(ul);
}

__device__ __forceinline__ bf16x8 ldfrag(const unsigned short* __restrict__ a,
                                         int rb, int lane, int kc) {
    int row = rb*16 + (lane & 15);
    int col = kc*32 + ((lane >> 4) & 3)*8;
    return *(const bf16x8*)(a + row*PB + col);
}

__device__ __forceinline__ void ldfragT(const float* __restrict__ T, int rb, int lane,
                                        int kc, bf16x8 &h, bf16x8 &l) {
    int row = rb*16 + (lane & 15);
    int col = kc*32 + ((lane >> 4) & 3)*8;
    const float* p = T + row*PB + col;
    float4 x0 = *(const float4*)p;
    float4 x1 = *(const float4*)(p + 4);
    unsigned short hh, ll;
    splitbf(x0.x,hh,ll); h[0]=(short)hh; l[0]=(short)ll;
    splitbf(x0.y,hh,ll); h[1]=(short)hh; l[1]=(short)ll;
    splitbf(x0.z,hh,ll); h[2]=(short)hh; l[2]=(short)ll;
    splitbf(x0.w,hh,ll); h[3]=(short)hh; l[3]=(short)ll;
    splitbf(x1.x,hh,ll); h[4]=(short)hh; l[4]=(short)ll;
    splitbf(x1.y,hh,ll); h[5]=(short)hh; l[5]=(short)ll;
    splitbf(x1.z,hh,ll); h[6]=(short)hh; l[6]=(short)ll;
    splitbf(x1.w,hh,ll); h[7]=(short)hh; l[7]=(short)ll;
}

// Exact symmetrization of a DIAGONAL 16x16 tile (C/D layout: col=lane&15,
// row=(lane>>4)*4+reg; transpose of (row rb+r, col) at lane'=4g+r+16(j>>2)).
__device__ __forceinline__ f32x4 symdiag(f32x4 a, int lane) {
    const int g = (lane >> 4) & 3, j = lane & 15;
    const int rp = j & 3;
    f32x4 out;
    #pragma unroll
    for (int r = 0; r < 4; ++r) {
        int lp = 4*g + r + ((j >> 2) << 4);
        float t0 = __shfl(a[0], lp, 64);
        float t1 = __shfl(a[1], lp, 64);
        float t2 = __shfl(a[2], lp, 64);
        float t3 = __shfl(a[3], lp, 64);
        float tv = (rp == 0) ? t0 : (rp == 1) ? t1 : (rp == 2) ? t2 : t3;
        out[r] = 0.5f*(a[r] + tv);
    }
    return out;
}

__device__ __forceinline__ void epi_T(float* __restrict__ T, int Tr, int Tc, int lane, f32x4 a) {
    int col = Tc*16 + (lane & 15);
    int rb  = Tr*16 + ((lane >> 4) & 3)*4;
    T[(rb+0)*PB + col] = a[0];
    T[(rb+1)*PB + col] = a[1];
    T[(rb+2)*PB + col] = a[2];
    T[(rb+3)*PB + col] = a[3];
    if (Tr != Tc) *(f32x4*)&T[col*PB + rb] = a;
}

// write symmetric tile (already symdiag'ed) back to LDS as hi/lo splits
__device__ __forceinline__ void st_split(unsigned short* __restrict__ H,
                                         unsigned short* __restrict__ L,
                                         int Tr, int Tc, int lane, f32x4 o) {
    int col = Tc*16 + (lane & 15);
    int rb  = Tr*16 + ((lane >> 4) & 3)*4;
    #pragma unroll
    for (int r = 0; r < 4; ++r) {
        unsigned short h, l;
        splitbf(o[r], h, l);
        H[(rb+r)*PB + col] = h;
        L[(rb+r)*PB + col] = l;
        if (Tr != Tc) { H[col*PB + rb + r] = h; L[col*PB + rb + r] = l; }
    }
}

__device__ __forceinline__ void stg_sym(float* __restrict__ out, long long off,
                                        int Tr, int Tc, int lane, f32x4 o) {
    int col = Tc*16 + (lane & 15);
    int rb  = Tr*16 + ((lane >> 4) & 3)*4;
    #pragma unroll
    for (int r = 0; r < 4; ++r)
        out[off + (long long)(rb+r)*NM + col] = o[r];
    if (Tr != Tc)
        *(f32x4*)&out[off + (long long)col*NM + rb] = o;
}

__device__ __forceinline__ f32x4 yepi(const unsigned short* __restrict__ Yh,
                                      const unsigned short* __restrict__ Yl,
                                      int Tr, int Tc, int lane, f32x4 a,
                                      float a15, float a05) {
    int col = Tc*16 + (lane & 15);
    int rb  = Tr*16 + ((lane >> 4) & 3)*4;
    f32x4 o;
    #pragma unroll
    for (int r = 0; r < 4; ++r)
        o[r] = a15*ldsM(Yh, Yl, rb+r, col) - a05*a[r];
    if (Tr == Tc) o = symdiag(o, lane);
    return o;
}

__device__ __forceinline__ f32x4 mepi(const unsigned short* __restrict__ Mh,
                                      const unsigned short* __restrict__ Ml,
                                      const float* __restrict__ T,
                                      int Tr, int Tc, int lane, f32x4 a, float q) {
    int col = Tc*16 + (lane & 15);
    int rb  = Tr*16 + ((lane >> 4) & 3)*4;
    f32x4 o;
    #pragma unroll
    for (int r = 0; r < 4; ++r)
        o[r] = q*(9.f*ldsM(Mh, Ml, rb+r, col) - 6.f*T[(rb+r)*PB + col] + a[r]);
    if (Tr == Tc) o = symdiag(o, lane);
    return o;
}

__device__ __forceinline__ f32x4 pepi(const unsigned short* __restrict__ Ph,
                                      const unsigned short* __restrict__ Pl,
                                      int Tr, int Tc, int lane, f32x4 a,
                                      float s1, float s2, float dadd) {
    int col = Tc*16 + (lane & 15);
    int rb  = Tr*16 + ((lane >> 4) & 3)*4;
    f32x4 o;
    #pragma unroll
    for (int r = 0; r < 4; ++r)
        o[r] = s1*a[r] - s2*ldsM(Ph, Pl, rb+r, col) + ((rb+r) == col ? dadd : 0.f);
    if (Tr == Tc) o = symdiag(o, lane);
    return o;
}

// triangular block GEMM: wave owns row-blocks R0 (cols 0..R0), R1 (cols 0..R1)
template<int R0, int R1>
__device__ __forceinline__ void tri_gemm(const unsigned short* __restrict__ Ah,
                                         const unsigned short* __restrict__ Al,
                                         const unsigned short* __restrict__ Bh,
                                         const unsigned short* __restrict__ Bl,
                                         int lane, f32x4* acc0, f32x4* acc1) {
    #pragma unroll
    for (int kc = 0; kc < 4; ++kc) {
        bf16x8 a0h = ldfrag(Ah, R0, lane, kc), a0l = ldfrag(Al, R0, lane, kc);
        bf16x8 a1h = ldfrag(Ah, R1, lane, kc), a1l = ldfrag(Al, R1, lane, kc);
        #pragma unroll
        for (int c = 0; c <= R1; ++c) {
            bf16x8 bh = ldfrag(Bh, c, lane, kc), bl = ldfrag(Bl, c, lane, kc);
            if (c <= R0) {
                acc0[c] = mfma16(a0h, bh, acc0[c]);
                acc0[c] = mfma16(a0h, bl, acc0[c]);
                acc0[c] = mfma16(a0l, bh, acc0[c]);
            }
            acc1[c] = mfma16(a1h, bh, acc1[c]);
            acc1[c] = mfma16(a1h, bl, acc1[c]);
            acc1[c] = mfma16(a1l, bh, acc1[c]);
        }
    }
}

template<int R0, int R1>
__device__ __forceinline__ void tri_gemm_T(const unsigned short* __restrict__ Ah,
                                           const unsigned short* __restrict__ Al,
                                           const float* __restrict__ T,
                                           int lane, f32x4* acc0, f32x4* acc1) {
    #pragma unroll
    for (int kc = 0; kc < 4; ++kc) {
        bf16x8 a0h = ldfrag(Ah, R0, lane, kc), a0l = ldfrag(Al, R0, lane, kc);
        bf16x8 a1h = ldfrag(Ah, R1, lane, kc), a1l = ldfrag(Al, R1, lane, kc);
        #pragma unroll
        for (int c = 0; c <= R1; ++c) {
            bf16x8 bh, bl;
            ldfragT(T, c, lane, kc, bh, bl);
            if (c <= R0) {
                acc0[c] = mfma16(a0h, bh, acc0[c]);
                acc0[c] = mfma16(a0h, bl, acc0[c]);
                acc0[c] = mfma16(a0l, bh, acc0[c]);
            }
            acc1[c] = mfma16(a1h, bh, acc1[c]);
            acc1[c] = mfma16(a1h, bl, acc1[c]);
            acc1[c] = mfma16(a1l, bh, acc1[c]);
        }
    }
}

// ---------------------------------------------------------------- fused NS
template<int W>
__device__ __forceinline__ void ns_fused_body(
    unsigned short* Mh, unsigned short* Ml,
    unsigned short* Yh, unsigned short* Yl, float* T,
    float* outY, long long off, int lane, int niter)
{
    constexpr int R0 = W, R1 = 7 - W;
    const f32x4 z = {0.f, 0.f, 0.f, 0.f};
    f32x4 acc0[R0+1], acc1[R1+1];
    f32x4 y0[R0+1], y1[R1+1];

    for (int j = 0; j < niter; ++j) {
        const int last = (j == niter-1);
        // schedule: 1.5 x(niter-3), 1.116, 1, 1  (certified c<=1.5 cap)
        const float cc = (j < niter-3) ? 1.5f : ((j == niter-3) ? 1.116f : 1.0f);
        const float dd = sqrtf(cc);
        const float a15 = 1.5f*dd, a05 = 0.5f*dd;

        // ---- phase 1: Y' = a15*Y - a05*(Y*M) -> regs ----
        #pragma unroll
        for (int c = 0; c <= R0; ++c) acc0[c] = z;
        #pragma unroll
        for (int c = 0; c <= R1; ++c) acc1[c] = z;
        tri_gemm<R0,R1>(Yh, Yl, Mh, Ml, lane, acc0, acc1);
        #pragma unroll
        for (int c = 0; c <= R0; ++c) y0[c] = yepi(Yh, Yl, R0, c, lane, acc0[c], a15, a05);
        #pragma unroll
        for (int c = 0; c <= R1; ++c) y1[c] = yepi(Yh, Yl, R1, c, lane, acc1[c], a15, a05);

        if (last) {
            #pragma unroll
            for (int c = 0; c <= R0; ++c) stg_sym(outY, off, R0, c, lane, y0[c]);
            #pragma unroll
            for (int c = 0; c <= R1; ++c) stg_sym(outY, off, R1, c, lane, y1[c]);
            return;
        }
        __syncthreads();   // Yh/Yl reads done; T may overlay

        // ---- phase 2: T = M*M (Gram, exactly symmetric) ----
        #pragma unroll
        for (int c = 0; c <= R0; ++c) acc0[c] = z;
        #pragma unroll
        for (int c = 0; c <= R1; ++c) acc1[c] = z;
        tri_gemm<R0,R1>(Mh, Ml, Mh, Ml, lane, acc0, acc1);
        #pragma unroll
        for (int c = 0; c <= R0; ++c) epi_T(T, R0, c, lane, acc0[c]);
        #pragma unroll
        for (int c = 0; c <= R1; ++c) epi_T(T, R1, c, lane, acc1[c]);
        __syncthreads();

        // ---- phase 3: M' = q*(9M - 6T + M*T) -> regs ----
        #pragma unroll
        for (int c = 0; c <= R0; ++c) acc0[c] = z;
        #pragma unroll
        for (int c = 0; c <= R1; ++c) acc1[c] = z;
        tri_gemm_T<R0,R1>(Mh, Ml, T, lane, acc0, acc1);
        const float q = 0.25f*cc;
        #pragma unroll
        for (int c = 0; c <= R0; ++c) acc0[c] = mepi(Mh, Ml, T, R0, c, lane, acc0[c], q);
        #pragma unroll
        for (int c = 0; c <= R1; ++c) acc1[c] = mepi(Mh, Ml, T, R1, c, lane, acc1[c], q);
        __syncthreads();   // all reads of Mh/Ml and T done

        // ---- writeback M', Y' splits (Y region = dead T) ----
        #pragma unroll
        for (int c = 0; c <= R0; ++c) st_split(Mh, Ml, R0, c, lane, acc0[c]);
        #pragma unroll
        for (int c = 0; c <= R1; ++c) st_split(Mh, Ml, R1, c, lane, acc1[c]);
        #pragma unroll
        for (int c = 0; c <= R0; ++c) st_split(Yh, Yl, R0, c, lane, y0[c]);
        #pragma unroll
        for (int c = 0; c <= R1; ++c) st_split(Yh, Yl, R1, c, lane, y1[c]);
        __syncthreads();
    }
}

__global__ __launch_bounds__(256,1)
void ns_fused(const float* __restrict__ Mp, const float* __restrict__ Yp,
              float* __restrict__ outY, int niter)
{
    __shared__ __align__(16) unsigned short pool[4*NM*PB];
    unsigned short* Mh = pool;
    unsigned short* Ml = pool + NM*PB;
    unsigned short* Yh = pool + 2*NM*PB;
    unsigned short* Yl = pool + 3*NM*PB;
    float* T = (float*)(pool + 2*NM*PB);

    const int t = threadIdx.x;
    const long long off = (long long)blockIdx.x << 14;
    for (int v = 0; v < 16; ++v) {
        int f = t + v*256;
        int row = f >> 5, c4 = (f & 31) << 2;
        float4 x = ((const float4*)(Mp + off))[f];
        ushort4 h, l;
        splitbf(x.x, h.x, l.x); splitbf(x.y, h.y, l.y);
        splitbf(x.z, h.z, l.z); splitbf(x.w, h.w, l.w);
        *(ushort4*)&Mh[row*PB + c4] = h;
        *(ushort4*)&Ml[row*PB + c4] = l;
        x = ((const float4*)(Yp + off))[f];
        splitbf(x.x, h.x, l.x); splitbf(x.y, h.y, l.y);
        splitbf(x.z, h.z, l.z); splitbf(x.w, h.w, l.w);
        *(ushort4*)&Yh[row*PB + c4] = h;
        *(ushort4*)&Yl[row*PB + c4] = l;
    }
    __syncthreads();

    const int lane = t & 63;
    const int w = t >> 6;
    switch (w) {
        case 0:  ns_fused_body<0>(Mh,Ml,Yh,Yl,T,outY,off,lane,niter); break;
        case 1:  ns_fused_body<1>(Mh,Ml,Yh,Yl,T,outY,off,lane,niter); break;
        case 2:  ns_fused_body<2>(Mh,Ml,Yh,Yl,T,outY,off,lane,niter); break;
        default: ns_fused_body<3>(Mh,Ml,Yh,Yl,T,outY,off,lane,niter); break;
    }
}

// ---------------------------------------------------------------- fused poly
struct PolyCoefs {
    float a, bd;                          // P0 = a*X + bd*I
    float s1, s2;                         // inner: P = s1*(X*P) - s2*P + c*I
    float c0,c1,c2,c3,c4,c5,c6,c7;        // 8 inner coefficients
    float f1, f2, f3;                     // final: out = f1*(X*P) - f2*P + (f3+lns)*I
};

template<int W>
__device__ __forceinline__ void poly_fused_body(
    const unsigned short* Xh, const unsigned short* Xl,
    unsigned short* Ph, unsigned short* Pl,
    float* Out, long long off, int lane, PolyCoefs pc, float lnsb)
{
    constexpr int R0 = W, R1 = 7 - W;
    const f32x4 z = {0.f, 0.f, 0.f, 0.f};
    f32x4 acc0[R0+1], acc1[R1+1];

    for (int step = 0; step < 8; ++step) {
        #pragma unroll
        for (int c = 0; c <= R0; ++c) acc0[c] = z;
        #pragma unroll
        for (int c = 0; c <= R1; ++c) acc1[c] = z;
        tri_gemm<R0,R1>(Xh, Xl, Ph, Pl, lane, acc0, acc1);
        float s3v;
        switch (step) {
            case 0: s3v = pc.c0; break;  case 1: s3v = pc.c1; break;
            case 2: s3v = pc.c2; break;  case 3: s3v = pc.c3; break;
            case 4: s3v = pc.c4; break;  case 5: s3v = pc.c5; break;
            case 6: s3v = pc.c6; break;  default: s3v = pc.c7; break;
        }
        #pragma unroll
        for (int c = 0; c <= R0; ++c) acc0[c] = pepi(Ph, Pl, R0, c, lane, acc0[c], pc.s1, pc.s2, s3v);
        #pragma unroll
        for (int c = 0; c <= R1; ++c) acc1[c] = pepi(Ph, Pl, R1, c, lane, acc1[c], pc.s1, pc.s2, s3v);
        __syncthreads();   // all Ph/Pl reads done
        #pragma unroll
        for (int c = 0; c <= R0; ++c) st_split(Ph, Pl, R0, c, lane, acc0[c]);
        #pragma unroll
        for (int c = 0; c <= R1; ++c) st_split(Ph, Pl, R1, c, lane, acc1[c]);
        __syncthreads();
    }
    // final combine -> global
    #pragma unroll
    for (int c = 0; c <= R0; ++c) acc0[c] = z;
    #pragma unroll
    for (int c = 0; c <= R1; ++c) acc1[c] = z;
    tri_gemm<R0,R1>(Xh, Xl, Ph, Pl, lane, acc0, acc1);
    const float dadd = pc.f3 + lnsb;
    #pragma unroll
    for (int c = 0; c <= R0; ++c) {
        f32x4 o = pepi(Ph, Pl, R0, c, lane, acc0[c], pc.f1, pc.f2, dadd);
        stg_sym(Out, off, R0, c, lane, o);
    }
    #pragma unroll
    for (int c = 0; c <= R1; ++c) {
        f32x4 o = pepi(Ph, Pl, R1, c, lane, acc1[c], pc.f1, pc.f2, dadd);
        stg_sym(Out, off, R1, c, lane, o);
    }
}

__global__ __launch_bounds__(256,1)
void poly_fused(const float* __restrict__ Xp, float* __restrict__ Out,
                const float* __restrict__ lns, PolyCoefs pc)
{
    __shared__ __align__(16) unsigned short pool[4*NM*PB];
    unsigned short* Xh = pool;
    unsigned short* Xl = pool + NM*PB;
    unsigned short* Ph = pool + 2*NM*PB;
    unsigned short* Pl = pool + 3*NM*PB;

    const int t = threadIdx.x;
    const long long b = blockIdx.x;
    const long long off = b << 14;
    for (int v = 0; v < 16; ++v) {
        int f = t + v*256;
        int row = f >> 5, c4 = (f & 31) << 2;
        float4 x = ((const float4*)(Xp + off))[f];
        float4 p;
        p.x = pc.a*x.x + ((c4+0)==row ? pc.bd : 0.f);
        p.y = pc.a*x.y + ((c4+1)==row ? pc.bd : 0.f);
        p.z = pc.a*x.z + ((c4+2)==row ? pc.bd : 0.f);
        p.w = pc.a*x.w + ((c4+3)==row ? pc.bd : 0.f);
        ushort4 h, l;
        splitbf(x.x, h.x, l.x); splitbf(x.y, h.y, l.y);
        splitbf(x.z, h.z, l.z); splitbf(x.w, h.w, l.w);
        *(ushort4*)&Xh[row*PB + c4] = h;
        *(ushort4*)&Xl[row*PB + c4] = l;
        splitbf(p.x, h.x, l.x); splitbf(p.y, h.y, l.y);
        splitbf(p.z, h.z, l.z); splitbf(p.w, h.w, l.w);
        *(ushort4*)&Ph[row*PB + c4] = h;
        *(ushort4*)&Pl[row*PB + c4] = l;
    }
    __syncthreads();

    const float lnsb = lns[b];
    const int lane = t & 63;
    const int w = t >> 6;
    switch (w) {
        case 0:  poly_fused_body<0>(Xh,Xl,Ph,Pl,Out,off,lane,pc,lnsb); break;
        case 1:  poly_fused_body<1>(Xh,Xl,Ph,Pl,Out,off,lane,pc,lnsb); break;
        case 2:  poly_fused_body<2>(Xh,Xl,Ph,Pl,Out,off,lane,pc,lnsb); break;
        default: poly_fused_body<3>(Xh,Xl,Ph,Pl,Out,off,lane,pc,lnsb); break;
    }
}

// ============================================================================
// Fallback (ws too small): round-1 parallel Jacobi
// ============================================================================
#define LDA  129
#define NT   512
#define MAX_SWEEPS 14

__global__ __launch_bounds__(NT, 1)
void logeig_jacobi(const float* __restrict__ in, float* __restrict__ out)
{
    __shared__ float A[NM][LDA];
    __shared__ float V[NM][LDA];
    __shared__ float rc[64], rs[64];
    __shared__ float logd[NM];
    __shared__ float roff[NT/64], rdia[NT/64];
    __shared__ int   s_done;

    const int t = threadIdx.x;
    const long long b = blockIdx.x;
    const float* __restrict__ Ain  = in  + (b << 14);
    float* __restrict__       Aout = out + (b << 14);

    for (int k = 0; k < (NM*NM)/NT; ++k) {
        int idx = t + k*NT;
        int i = idx >> 7, j = idx & 127;
        A[i][j] = Ain[idx];
        V[i][j] = (i == j) ? 1.0f : 0.0f;
    }
    __syncthreads();

    for (int sweep = 0; sweep < MAX_SWEEPS; ++sweep) {
        for (int r = 0; r < NM-1; ++r) {
            if (t < 64) {
                int m = t, p, q;
                if (m == 0) { p = NM-1; q = r; }
                else {
                    p = r + m;            if (p >= NM-1) p -= (NM-1);
                    q = r - m + (NM-1);   if (q >= NM-1) q -= (NM-1);
                }
                float app = A[p][p], aqq = A[q][q], apq = A[p][q];
                float c = 1.0f, s = 0.0f;
                if (fabsf(apq) > 1e-12f*(fabsf(app)+fabsf(aqq)) + 1e-32f) {
                    float tau = (aqq - app) * 0.5f / apq;
                    float tt  = 1.0f / (fabsf(tau) + sqrtf(fmaf(tau,tau,1.0f)));
                    tt = (tau < 0.0f) ? -tt : tt;
                    c = rsqrtf(fmaf(tt,tt,1.0f));
                    s = tt * c;
                }
                rc[m] = c; rs[m] = s;
            }
            __syncthreads();
            for (int k = 0; k < (2*64*NM)/NT; ++k) {
                int task = t + k*NT;
                int i   = task & 127;
                int m   = (task >> 7) & 63;
                int isV = task >> 13;
                int p, q;
                if (m == 0) { p = NM-1; q = r; }
                else {
                    p = r + m;            if (p >= NM-1) p -= (NM-1);
                    q = r - m + (NM-1);   if (q >= NM-1) q -= (NM-1);
                }
                float c = rc[m], s = rs[m];
                if (isV == 0) {
                    float x = A[i][p], y = A[i][q];
                    A[i][p] = c*x - s*y;
                    A[i][q] = s*x + c*y;
                } else {
                    float x = V[i][p], y = V[i][q];
                    V[i][p] = c*x - s*y;
                    V[i][q] = s*x + c*y;
                }
            }
            __syncthreads();
            for (int k = 0; k < (64*NM)/NT; ++k) {
                int task = t + k*NT;
                int j = task & 127;
                int m = task >> 7;
                int p, q;
                if (m == 0) { p = NM-1; q = r; }
                else {
                    p = r + m;            if (p >= NM-1) p -= (NM-1);
                    q = r - m + (NM-1);   if (q >= NM-1) q -= (NM-1);
                }
                float c = rc[m], s = rs[m];
                float x = A[p][j], y = A[q][j];
                A[p][j] = c*x - s*y;
                A[q][j] = s*x + c*y;
            }
            __syncthreads();
        }
        float off2 = 0.0f, dia2 = 0.0f;
        for (int k = 0; k < (NM*NM)/NT; ++k) {
            int idx = t + k*NT;
            int i = idx >> 7, j = idx & 127;
            float v = A[i][j];
            if (i == j) dia2 += v*v; else off2 += v*v;
        }
        #pragma unroll
        for (int o = 32; o > 0; o >>= 1) {
            off2 += __shfl_down(off2, o, 64);
            dia2 += __shfl_down(dia2, o, 64);
        }
        if ((t & 63) == 0) { roff[t >> 6] = off2; rdia[t >> 6] = dia2; }
        __syncthreads();
        if (t == 0) {
            float o2 = 0.0f, d2 = 0.0f;
            for (int w = 0; w < NT/64; ++w) { o2 += roff[w]; d2 += rdia[w]; }
            s_done = (o2 <= 1e-13f * d2) ? 1 : 0;
        }
        __syncthreads();
        if (s_done) break;
    }

    if (t < NM) logd[t] = logf(fmaxf(A[t][t], 1e-12f));
    __syncthreads();
    for (int kk = 0; kk < (NM*NM)/NT; ++kk) {
        int idx = t + kk*NT;
        int i = idx >> 7, k = idx & 127;
        A[i][k] = V[i][k] * logd[k];
    }
    __syncthreads();
    {
        int i  = t >> 2;
        int jb = t & 3;
        float acc[32];
        #pragma unroll
        for (int jj = 0; jj < 32; ++jj) acc[jj] = 0.0f;
        for (int kk = 0; kk < NM; ++kk) {
            int k = (kk + jb) & 127;
            float w = A[i][k];
            #pragma unroll
            for (int jj = 0; jj < 32; ++jj)
                acc[jj] = fmaf(w, V[jb*32 + jj][k], acc[jj]);
        }
        #pragma unroll
        for (int jj = 0; jj < 32; ++jj)
            Aout[i*NM + jb*32 + jj] = acc[jj];
    }
}

// ============================================================================
// Host
// ============================================================================
static void cheb_log_power(double lo, double up, int deg, double* p)
{
    const int NC = deg + 1;
    const int MN = 64;
    double mid = 0.5*(lo+up), hw = 0.5*(up-lo);
    double cc[32];
    for (int j = 0; j < NC; ++j) {
        double s = 0.0;
        for (int m = 0; m < MN; ++m) {
            double th = M_PI*(m+0.5)/MN;
            s += log(mid + hw*cos(th)) * cos(j*th);
        }
        cc[j] = 2.0*s/MN;
    }
    double Tp[32] = {0}, Tc[32] = {0}, Tn[32];
    for (int j = 0; j < NC; ++j) p[j] = 0.0;
    Tp[0] = 1.0;  p[0] += 0.5*cc[0];
    Tc[1] = 1.0;  p[1] += cc[1];
    for (int k = 2; k <= deg; ++k) {
        for (int j = 0; j < NC; ++j) Tn[j] = -Tp[j];
        for (int j = 1; j < NC; ++j) Tn[j] += 2.0*Tc[j-1];
        for (int j = 0; j < NC; ++j) { p[j] += cc[k]*Tn[j]; Tp[j] = Tc[j]; Tc[j] = Tn[j]; }
    }
}

extern "C" void kernel_launch(void* const* d_in, const int* in_sizes, int n_in,
                              void* d_out, int out_size, void* d_ws, size_t ws_size,
                              hipStream_t stream) {
    const float* in = (const float*)d_in[0];
    float* out = (float*)d_out;
    const int batch = in_sizes[0] >> 14;                 // 4096
    const size_t matBytes = (size_t)batch * NM * NM * 4; // 256 MB
    const size_t need = matBytes + (size_t)batch * 4;

    if (ws_size < need) {   // fallback
        logeig_jacobi<<<batch, NT, 0, stream>>>(in, out);
        return;
    }

    float* Mbuf = (float*)d_ws;
    float* lns  = (float*)((char*)d_ws + matBytes);

    // --- scaling: s0 = gersh(A); tighten via sqrt(gersh((A/s0)^2)) ---
    scale_kernel<<<batch, 256, 0, stream>>>(in, out, Mbuf, lns);      // out = X0
    poly_kernel<<<batch, NTG, 0, stream>>>(out, out, Mbuf, 1.f, 0.f, 0.f,
                                           (const float*)nullptr);    // Mbuf = X0^2
    rescale_kernel<<<batch, 256, 0, stream>>>(Mbuf, out, Mbuf, lns);  // out=Mbuf=X

    // --- L1 iters 0-3: f32 (precision-critical; e/mu_min amplification) ---
    for (int j = 0; j < 4; ++j)
        ns_kernel<<<batch, NTG, 0, stream>>>(Mbuf, out, Mbuf, out,
                                             1.5f, sqrtf(1.5f), 1);

    // --- fused MFMA NS segments (schedule {1.5 x(n-3), 1.116, 1, 1}) ---
    ns_fused<<<batch, 256, 0, stream>>>(Mbuf, out, out, 8);  // L1 iters 4..11
    ns_fused<<<batch, 256, 0, stream>>>(out,  out, out, 8);  // L2 (M0=Y0)
    ns_fused<<<batch, 256, 0, stream>>>(out,  out, out, 6);  // L3 (M0=Y0)

    // --- fused Chebyshev-minimax log, deg 10 on [0.25, 1.002] ---
    const double lo = 0.25, up = 1.002;
    const double mid = 0.5*(lo+up), hw = 0.5*(up-lo);
    double p[11];
    cheb_log_power(lo, up, 10, p);

    PolyCoefs pc;
    pc.a  = (float)(p[10]/hw);
    pc.bd = (float)(p[9] - p[10]*mid/hw);
    pc.s1 = (float)(1.0/hw);
    pc.s2 = (float)(mid/hw);
    pc.c0 = (float)p[8]; pc.c1 = (float)p[7]; pc.c2 = (float)p[6];
    pc.c3 = (float)p[5]; pc.c4 = (float)p[4]; pc.c5 = (float)p[3];
    pc.c6 = (float)p[2]; pc.c7 = (float)p[1];
    pc.f1 = (float)(8.0/hw);
    pc.f2 = (float)(8.0*mid/hw);
    pc.f3 = (float)(8.0*p[0]);

    poly_fused<<<batch, 256, 0, stream>>>(out, out, lns, pc);
}

// Round 10
// 7296.386 us; speedup vs baseline: 16.4787x; 1.3112x over previous
//
#include <hip/hip_runtime.h>
#include <hip/hip_bf16.h>
#include <math.h>

#define NM   128
#define PAD  132   // f32 LDS pitch
#define PB   136   // u16 LDS pitch for MFMA splits

typedef __attribute__((ext_vector_type(8))) short bf16x8;
typedef __attribute__((ext_vector_type(4))) float f32x4;

// ============================================================================
// log(A) = ln(s) I + 8 * cheb_log( NS_sqrt^3( A/s ) ).
// Round-10: (1) fused MFMA kernels at 8 waves (parity-split tile partition),
// (2) T kept as bf16 hi/lo split in LDS (no f32 T: kills splitbf-on-read and
// f32-stride bank conflicts), (3) f32 NS iters & X0^2 as lower-triangle +
// mirror-write kernels (0.52x FLOP, outputs exactly symmetric by construction).
// Invariants from rounds 6-8: every matrix written anywhere is EXACTLY
// symmetric (mirror-write + symdiag-on-full-output); M/T/Y/P passthroughs
// read LDS-resident data, never possibly-aliased global buffers.
// ============================================================================

// ---------------------------------------------------------------- f32 kernels
__global__ __launch_bounds__(256,1)
void scale_kernel(const float* __restrict__ A, float* __restrict__ outY,
                  float* __restrict__ outM, float* __restrict__ lns)
{
    __shared__ __align__(16) float L[NM][PAD];
    __shared__ float rs[NM];
    __shared__ float s_inv;
    const int t = threadIdx.x;
    const long long b = blockIdx.x;
    const long long off = b << 14;
    for (int v = 0; v < 16; ++v) {
        int f = t + v*256;
        int row = f >> 5, c4 = (f & 31) << 2;
        *(float4*)&L[row][c4] = ((const float4*)(A + off))[f];
    }
    __syncthreads();
    if (t < NM) {
        float s = 0.f;
        for (int j = 0; j < NM; ++j) s += fabsf(L[t][j]);
        rs[t] = s;
    }
    __syncthreads();
    if (t < 64) {
        float m = fmaxf(rs[t], rs[t+64]);
        #pragma unroll
        for (int o = 32; o > 0; o >>= 1) m = fmaxf(m, __shfl_down(m, o, 64));
        if (t == 0) { s_inv = 1.0f/m; lns[b] = logf(m); }
    }
    __syncthreads();
    const float inv = s_inv;
    for (int v = 0; v < 16; ++v) {
        int f = t + v*256;
        int row = f >> 5, c4 = (f & 31) << 2;
        float4 x = *(const float4*)&L[row][c4];
        x.x *= inv; x.y *= inv; x.z *= inv; x.w *= inv;
        ((float4*)(outY + off))[f] = x;
        ((float4*)(outM + off))[f] = x;
    }
}

__global__ __launch_bounds__(256,1)
void rescale_kernel(const float* __restrict__ Sq, float* __restrict__ X,
                    float* __restrict__ M, float* __restrict__ lns)
{
    __shared__ __align__(16) float L[NM][PAD];
    __shared__ float rs[NM];
    __shared__ float s_g;
    const int t = threadIdx.x;
    const long long b = blockIdx.x;
    const long long off = b << 14;
    for (int v = 0; v < 16; ++v) {
        int f = t + v*256;
        int row = f >> 5, c4 = (f & 31) << 2;
        *(float4*)&L[row][c4] = ((const float4*)(Sq + off))[f];
    }
    __syncthreads();
    if (t < NM) {
        float s = 0.f;
        for (int j = 0; j < NM; ++j) s += fabsf(L[t][j]);
        rs[t] = s;
    }
    __syncthreads();
    if (t < 64) {
        float m = fmaxf(rs[t], rs[t+64]);
        #pragma unroll
        for (int o = 32; o > 0; o >>= 1) m = fmaxf(m, __shfl_down(m, o, 64));
        if (t == 0) { s_g = 1.0f/sqrtf(m); lns[b] = lns[b] + 0.5f*logf(m); }
    }
    __syncthreads();
    const float g = s_g;
    for (int v = 0; v < 16; ++v) {
        int f = t + v*256;
        float4 x = ((const float4*)(X + off))[f];
        x.x *= g; x.y *= g; x.z *= g; x.w *= g;
        ((float4*)(X + off))[f] = x;
        ((float4*)(M + off))[f] = x;
    }
}

// triangular index decode: u -> (bi,bj), bj<=bi
__device__ __forceinline__ void tridec(int u, int &bi, int &bj) {
    int b = (int)(0.5f*(sqrtf(8.0f*(float)u + 1.0f) - 1.0f));
    while ((b+1)*(b+2)/2 <= u) ++b;
    while (b*(b+1)/2 > u) --b;
    bi = b; bj = u - b*(b+1)/2;
}

// Gram: Out = X^T X (= X^2 for symmetric X), lower-triangle + mirror
__global__ __launch_bounds__(512,1)
void gram_tri(const float* __restrict__ X, float* __restrict__ Out)
{
    __shared__ __align__(16) float LX[NM][PAD];
    const int t = threadIdx.x;
    const long long off = (long long)blockIdx.x << 14;
    for (int v = 0; v < 8; ++v) {
        int f = t + v*512;
        int row = f >> 5, c4 = (f & 31) << 2;
        *(float4*)&LX[row][c4] = ((const float4*)(X + off))[f];
    }
    __syncthreads();
    for (int u = t; u < 528; u += 512) {
        int bi, bj; tridec(u, bi, bj);
        const int r4 = bi << 2, c4 = bj << 2;
        float acc[4][4];
        #pragma unroll
        for (int i = 0; i < 4; ++i)
            #pragma unroll
            for (int j = 0; j < 4; ++j) acc[i][j] = 0.f;
        #pragma unroll 4
        for (int k = 0; k < NM; ++k) {
            float av[4], bv[4];
            *(float4*)av = *(const float4*)&LX[k][r4];
            *(float4*)bv = *(const float4*)&LX[k][c4];
            #pragma unroll
            for (int i = 0; i < 4; ++i)
                #pragma unroll
                for (int j = 0; j < 4; ++j) acc[i][j] = fmaf(av[i], bv[j], acc[i][j]);
        }
        #pragma unroll
        for (int i = 0; i < 4; ++i)
            *(float4*)&Out[off + (long long)(r4+i)*NM + c4] =
                make_float4(acc[i][0], acc[i][1], acc[i][2], acc[i][3]);
        if (bi != bj) {
            #pragma unroll
            for (int j = 0; j < 4; ++j)
                *(float4*)&Out[off + (long long)(c4+j)*NM + r4] =
                    make_float4(acc[0][j], acc[1][j], acc[2][j], acc[3][j]);
        }
    }
}

// ---- f32 NS iteration, lower-triangle tiles + mirror-write (0.52x FLOP) ----
__device__ __forceinline__ void ns_tri_p1(const float (*LM)[PAD], const float (*LB)[PAD],
                                          float* __restrict__ outY, long long off,
                                          int bi, int bj, float a15, float a05)
{
    const int r4 = bi << 2, c4 = bj << 2;
    float acc[4][4];
    #pragma unroll
    for (int i = 0; i < 4; ++i)
        #pragma unroll
        for (int j = 0; j < 4; ++j) acc[i][j] = 0.f;
    #pragma unroll 4
    for (int k = 0; k < NM; ++k) {
        float av[4], bv[4];
        *(float4*)av = *(const float4*)&LB[k][r4];
        *(float4*)bv = *(const float4*)&LM[k][c4];
        #pragma unroll
        for (int i = 0; i < 4; ++i)
            #pragma unroll
            for (int j = 0; j < 4; ++j) acc[i][j] = fmaf(av[i], bv[j], acc[i][j]);
    }
    float o[4][4];
    #pragma unroll
    for (int i = 0; i < 4; ++i)
        #pragma unroll
        for (int j = 0; j < 4; ++j)
            o[i][j] = a15*LB[r4+i][c4+j] - a05*acc[i][j];
    if (bi == bj) {
        #pragma unroll
        for (int i = 0; i < 4; ++i)
            #pragma unroll
            for (int j = 0; j < 4; ++j)
                if (j > i) { float s = 0.5f*(o[i][j] + o[j][i]); o[i][j] = s; o[j][i] = s; }
    }
    #pragma unroll
    for (int i = 0; i < 4; ++i)
        *(float4*)&outY[off + (long long)(r4+i)*NM + c4] =
            make_float4(o[i][0], o[i][1], o[i][2], o[i][3]);
    if (bi != bj) {
        #pragma unroll
        for (int j = 0; j < 4; ++j)
            *(float4*)&outY[off + (long long)(c4+j)*NM + r4] =
                make_float4(o[0][j], o[1][j], o[2][j], o[3][j]);
    }
}

__device__ __forceinline__ void ns_tri_p2(const float (*LM)[PAD], float (*LB)[PAD],
                                          int bi, int bj)
{
    const int r4 = bi << 2, c4 = bj << 2;
    float acc[4][4];
    #pragma unroll
    for (int i = 0; i < 4; ++i)
        #pragma unroll
        for (int j = 0; j < 4; ++j) acc[i][j] = 0.f;
    #pragma unroll 4
    for (int k = 0; k < NM; ++k) {
        float av[4], bv[4];
        *(float4*)av = *(const float4*)&LM[k][r4];
        *(float4*)bv = *(const float4*)&LM[k][c4];
        #pragma unroll
        for (int i = 0; i < 4; ++i)
            #pragma unroll
            for (int j = 0; j < 4; ++j) acc[i][j] = fmaf(av[i], bv[j], acc[i][j]);
    }
    // Gram: diag blocks bitwise symmetric (commutative mult, same k-order)
    #pragma unroll
    for (int i = 0; i < 4; ++i)
        *(float4*)&LB[r4+i][c4] = make_float4(acc[i][0], acc[i][1], acc[i][2], acc[i][3]);
    if (bi != bj) {
        #pragma unroll
        for (int j = 0; j < 4; ++j)
            *(float4*)&LB[c4+j][r4] = make_float4(acc[0][j], acc[1][j], acc[2][j], acc[3][j]);
    }
}

__device__ __forceinline__ void ns_tri_p3(const float (*LM)[PAD], const float (*LB)[PAD],
                                          float* __restrict__ outM, long long off,
                                          int bi, int bj, float q)
{
    const int r4 = bi << 2, c4 = bj << 2;
    float acc[4][4];
    #pragma unroll
    for (int i = 0; i < 4; ++i)
        #pragma unroll
        for (int j = 0; j < 4; ++j) acc[i][j] = 0.f;
    #pragma unroll 4
    for (int k = 0; k < NM; ++k) {
        float av[4], bv[4];
        *(float4*)av = *(const float4*)&LM[k][r4];
        *(float4*)bv = *(const float4*)&LB[k][c4];
        #pragma unroll
        for (int i = 0; i < 4; ++i)
            #pragma unroll
            for (int j = 0; j < 4; ++j) acc[i][j] = fmaf(av[i], bv[j], acc[i][j]);
    }
    float o[4][4];
    #pragma unroll
    for (int i = 0; i < 4; ++i)
        #pragma unroll
        for (int j = 0; j < 4; ++j)
            o[i][j] = q*(9.f*LM[r4+i][c4+j] - 6.f*LB[r4+i][c4+j] + acc[i][j]);
    if (bi == bj) {
        #pragma unroll
        for (int i = 0; i < 4; ++i)
            #pragma unroll
            for (int j = 0; j < 4; ++j)
                if (j > i) { float s = 0.5f*(o[i][j] + o[j][i]); o[i][j] = s; o[j][i] = s; }
    }
    #pragma unroll
    for (int i = 0; i < 4; ++i)
        *(float4*)&outM[off + (long long)(r4+i)*NM + c4] =
            make_float4(o[i][0], o[i][1], o[i][2], o[i][3]);
    if (bi != bj) {
        #pragma unroll
        for (int j = 0; j < 4; ++j)
            *(float4*)&outM[off + (long long)(c4+j)*NM + r4] =
                make_float4(o[0][j], o[1][j], o[2][j], o[3][j]);
    }
}

__global__ __launch_bounds__(512,1)
void ns_tri(const float* __restrict__ Mp, const float* __restrict__ Yp,
            float* __restrict__ outM, float* __restrict__ outY,
            float cc, float dd)
{
    __shared__ __align__(16) float LM[NM][PAD];
    __shared__ __align__(16) float LB[NM][PAD];
    const int t = threadIdx.x;
    const long long off = (long long)blockIdx.x << 14;
    for (int v = 0; v < 8; ++v) {
        int f = t + v*512;
        int row = f >> 5, c4 = (f & 31) << 2;
        *(float4*)&LM[row][c4] = ((const float4*)(Mp + off))[f];
        *(float4*)&LB[row][c4] = ((const float4*)(Yp + off))[f];
    }
    __syncthreads();

    const float a15 = 1.5f*dd, a05 = 0.5f*dd, q = 0.25f*cc;
    int bi0, bj0, bi1 = -1, bj1 = 0;
    tridec(t, bi0, bj0);
    if (t < 16) tridec(512 + t, bi1, bj1);

    ns_tri_p1(LM, LB, outY, off, bi0, bj0, a15, a05);
    if (bi1 >= 0) ns_tri_p1(LM, LB, outY, off, bi1, bj1, a15, a05);
    __syncthreads();                       // all LB(Y) reads done
    ns_tri_p2(LM, LB, bi0, bj0);           // LB <- T = M*M
    if (bi1 >= 0) ns_tri_p2(LM, LB, bi1, bj1);
    __syncthreads();
    ns_tri_p3(LM, LB, outM, off, bi0, bj0, q);
    if (bi1 >= 0) ns_tri_p3(LM, LB, outM, off, bi1, bj1, q);
}

// ---------------------------------------------------------------- MFMA common
__device__ __forceinline__ f32x4 mfma16(bf16x8 a, bf16x8 b, f32x4 c) {
    return __builtin_amdgcn_mfma_f32_16x16x32_bf16(a, b, c, 0, 0, 0);
}

__device__ __forceinline__ void splitbf(float x, unsigned short &h, unsigned short &l) {
    __hip_bfloat16 bh = __float2bfloat16(x);
    float r = x - __bfloat162float(bh);
    __hip_bfloat16 bl = __float2bfloat16(r);
    h = *(unsigned short*)&bh;
    l = *(unsigned short*)&bl;
}

__device__ __forceinline__ float ldsM(const unsigned short* __restrict__ H,
                                      const unsigned short* __restrict__ L,
                                      int row, int col) {
    unsigned int uh = ((unsigned int)H[row*PB + col]) << 16;
    unsigned int ul = ((unsigned int)L[row*PB + col]) << 16;
    return __uint_as_float(uh) + __uint_as_float(ul);
}

__device__ __forceinline__ bf16x8 ldfrag(const unsigned short* __restrict__ a,
                                         int rb, int lane, int kc) {
    int row = rb*16 + (lane & 15);
    int col = kc*32 + ((lane >> 4) & 3)*8;
    return *(const bf16x8*)(a + row*PB + col);
}

// Exact symmetrization of a DIAGONAL 16x16 tile (C/D layout: col=lane&15,
// row=(lane>>4)*4+reg; transpose of (row rb+r, col) at lane'=4g+r+16(j>>2)).
__device__ __forceinline__ f32x4 symdiag(f32x4 a, int lane) {
    const int g = (lane >> 4) & 3, j = lane & 15;
    const int rp = j & 3;
    f32x4 out;
    #pragma unroll
    for (int r = 0; r < 4; ++r) {
        int lp = 4*g + r + ((j >> 2) << 4);
        float t0 = __shfl(a[0], lp, 64);
        float t1 = __shfl(a[1], lp, 64);
        float t2 = __shfl(a[2], lp, 64);
        float t3 = __shfl(a[3], lp, 64);
        float tv = (rp == 0) ? t0 : (rp == 1) ? t1 : (rp == 2) ? t2 : t3;
        out[r] = 0.5f*(a[r] + tv);
    }
    return out;
}

// write symmetric tile back to LDS as hi/lo splits (+ mirror)
__device__ __forceinline__ void st_split(unsigned short* __restrict__ H,
                                         unsigned short* __restrict__ L,
                                         int Tr, int Tc, int lane, f32x4 o) {
    int col = Tc*16 + (lane & 15);
    int rb  = Tr*16 + ((lane >> 4) & 3)*4;
    #pragma unroll
    for (int r = 0; r < 4; ++r) {
        unsigned short h, l;
        splitbf(o[r], h, l);
        H[(rb+r)*PB + col] = h;
        L[(rb+r)*PB + col] = l;
        if (Tr != Tc) { H[col*PB + rb + r] = h; L[col*PB + rb + r] = l; }
    }
}

__device__ __forceinline__ void stg_sym(float* __restrict__ out, long long off,
                                        int Tr, int Tc, int lane, f32x4 o) {
    int col = Tc*16 + (lane & 15);
    int rb  = Tr*16 + ((lane >> 4) & 3)*4;
    #pragma unroll
    for (int r = 0; r < 4; ++r)
        out[off + (long long)(rb+r)*NM + col] = o[r];
    if (Tr != Tc)
        *(f32x4*)&out[off + (long long)col*NM + rb] = o;
}

__device__ __forceinline__ f32x4 yepi(const unsigned short* __restrict__ Yh,
                                      const unsigned short* __restrict__ Yl,
                                      int Tr, int Tc, int lane, f32x4 a,
                                      float a15, float a05) {
    int col = Tc*16 + (lane & 15);
    int rb  = Tr*16 + ((lane >> 4) & 3)*4;
    f32x4 o;
    #pragma unroll
    for (int r = 0; r < 4; ++r)
        o[r] = a15*ldsM(Yh, Yl, rb+r, col) - a05*a[r];
    if (Tr == Tc) o = symdiag(o, lane);
    return o;
}

__device__ __forceinline__ f32x4 mepi(const unsigned short* __restrict__ Mh,
                                      const unsigned short* __restrict__ Ml,
                                      const unsigned short* __restrict__ Th,
                                      const unsigned short* __restrict__ Tl,
                                      int Tr, int Tc, int lane, f32x4 a, float q) {
    int col = Tc*16 + (lane & 15);
    int rb  = Tr*16 + ((lane >> 4) & 3)*4;
    f32x4 o;
    #pragma unroll
    for (int r = 0; r < 4; ++r)
        o[r] = q*(9.f*ldsM(Mh, Ml, rb+r, col) - 6.f*ldsM(Th, Tl, rb+r, col) + a[r]);
    if (Tr == Tc) o = symdiag(o, lane);
    return o;
}

__device__ __forceinline__ f32x4 pepi(const unsigned short* __restrict__ Ph,
                                      const unsigned short* __restrict__ Pl,
                                      int Tr, int Tc, int lane, f32x4 a,
                                      float s1, float s2, float dadd) {
    int col = Tc*16 + (lane & 15);
    int rb  = Tr*16 + ((lane >> 4) & 3)*4;
    f32x4 o;
    #pragma unroll
    for (int r = 0; r < 4; ++r)
        o[r] = s1*a[r] - s2*ldsM(Ph, Pl, rb+r, col) + ((rb+r) == col ? dadd : 0.f);
    if (Tr == Tc) o = symdiag(o, lane);
    return o;
}

// ---- 8-wave tile partition: pair p = W&3 -> rows (p, 7-p); 9 tiles split by
// parity between halves h = W>>2 (5 tiles for h=0, 4 for h=1). Union over the
// 8 waves = all 36 lower-triangle tiles, each exactly once.
template<int W>
struct TileSet {
    static constexpr int P  = W & 3;
    static constexpr int R0 = P;
    static constexpr int R1 = 7 - P;
    static constexpr int H  = W >> 2;
    static constexpr int N  = (10 - H) / 2;   // 5 or 4
    static constexpr int tr(int i) { int g = 2*i + H; return g <= R0 ? R0 : R1; }
    static constexpr int tc(int i) { int g = 2*i + H; return g <= R0 ? g : g - R0 - 1; }
};

template<int W>
__device__ __forceinline__ void tri8_gemm(const unsigned short* __restrict__ Ah,
                                          const unsigned short* __restrict__ Al,
                                          const unsigned short* __restrict__ Bh,
                                          const unsigned short* __restrict__ Bl,
                                          int lane, f32x4* acc) {
    using TS = TileSet<W>;
    #pragma unroll
    for (int kc = 0; kc < 4; ++kc) {
        bf16x8 a0h = ldfrag(Ah, TS::R0, lane, kc), a0l = ldfrag(Al, TS::R0, lane, kc);
        bf16x8 a1h = ldfrag(Ah, TS::R1, lane, kc), a1l = ldfrag(Al, TS::R1, lane, kc);
        #pragma unroll
        for (int i = 0; i < TS::N; ++i) {
            const int r = TS::tr(i), c = TS::tc(i);
            bf16x8 bh = ldfrag(Bh, c, lane, kc), bl = ldfrag(Bl, c, lane, kc);
            bf16x8 ah = (r == TS::R0) ? a0h : a1h;
            bf16x8 al = (r == TS::R0) ? a0l : a1l;
            acc[i] = mfma16(ah, bh, acc[i]);
            acc[i] = mfma16(ah, bl, acc[i]);
            acc[i] = mfma16(al, bh, acc[i]);
        }
    }
}

// ---------------------------------------------------------------- fused NS
template<int W>
__device__ __forceinline__ void ns_fused_body8(
    unsigned short* Mh, unsigned short* Ml,
    unsigned short* Yh, unsigned short* Yl,    // Yh/Yl double as Th/Tl
    float* outY, long long off, int lane, int niter)
{
    using TS = TileSet<W>;
    constexpr int NT_ = TS::N;
    const f32x4 z = {0.f, 0.f, 0.f, 0.f};
    f32x4 acc[NT_], yv[NT_];

    for (int j = 0; j < niter; ++j) {
        const int last = (j == niter-1);
        // schedule: 1.5 x(niter-3), 1.116, 1, 1 (certified c<=1.5 cap)
        const float cc = (j < niter-3) ? 1.5f : ((j == niter-3) ? 1.116f : 1.0f);
        const float dd = sqrtf(cc);
        const float a15 = 1.5f*dd, a05 = 0.5f*dd;

        // ---- phase 1: Y' = a15*Y - a05*(Y*M) -> regs ----
        #pragma unroll
        for (int i = 0; i < NT_; ++i) acc[i] = z;
        tri8_gemm<W>(Yh, Yl, Mh, Ml, lane, acc);
        #pragma unroll
        for (int i = 0; i < NT_; ++i)
            yv[i] = yepi(Yh, Yl, TS::tr(i), TS::tc(i), lane, acc[i], a15, a05);

        if (last) {
            #pragma unroll
            for (int i = 0; i < NT_; ++i)
                stg_sym(outY, off, TS::tr(i), TS::tc(i), lane, yv[i]);
            return;
        }
        __syncthreads();   // all Yh/Yl reads done; T overlays

        // ---- phase 2: T = M*M (split bf16 into Yh/Yl region) ----
        #pragma unroll
        for (int i = 0; i < NT_; ++i) acc[i] = z;
        tri8_gemm<W>(Mh, Ml, Mh, Ml, lane, acc);
        #pragma unroll
        for (int i = 0; i < NT_; ++i)
            st_split(Yh, Yl, TS::tr(i), TS::tc(i), lane, acc[i]);
        __syncthreads();

        // ---- phase 3: M' = q*(9M - 6T + M*T) ----
        #pragma unroll
        for (int i = 0; i < NT_; ++i) acc[i] = z;
        tri8_gemm<W>(Mh, Ml, Yh, Yl, lane, acc);
        const float q = 0.25f*cc;
        #pragma unroll
        for (int i = 0; i < NT_; ++i)
            acc[i] = mepi(Mh, Ml, Yh, Yl, TS::tr(i), TS::tc(i), lane, acc[i], q);
        __syncthreads();   // all Mh/Ml/T reads done

        // ---- writeback M', Y' splits ----
        #pragma unroll
        for (int i = 0; i < NT_; ++i)
            st_split(Mh, Ml, TS::tr(i), TS::tc(i), lane, acc[i]);
        #pragma unroll
        for (int i = 0; i < NT_; ++i)
            st_split(Yh, Yl, TS::tr(i), TS::tc(i), lane, yv[i]);
        __syncthreads();
    }
}

__global__ __launch_bounds__(512,1)
void ns_fused(const float* __restrict__ Mp, const float* __restrict__ Yp,
              float* __restrict__ outY, int niter)
{
    __shared__ __align__(16) unsigned short pool[4*NM*PB];
    unsigned short* Mh = pool;
    unsigned short* Ml = pool + NM*PB;
    unsigned short* Yh = pool + 2*NM*PB;
    unsigned short* Yl = pool + 3*NM*PB;

    const int t = threadIdx.x;
    const long long off = (long long)blockIdx.x << 14;
    for (int v = 0; v < 8; ++v) {
        int f = t + v*512;
        int row = f >> 5, c4 = (f & 31) << 2;
        float4 x = ((const float4*)(Mp + off))[f];
        ushort4 h, l;
        splitbf(x.x, h.x, l.x); splitbf(x.y, h.y, l.y);
        splitbf(x.z, h.z, l.z); splitbf(x.w, h.w, l.w);
        *(ushort4*)&Mh[row*PB + c4] = h;
        *(ushort4*)&Ml[row*PB + c4] = l;
        x = ((const float4*)(Yp + off))[f];
        splitbf(x.x, h.x, l.x); splitbf(x.y, h.y, l.y);
        splitbf(x.z, h.z, l.z); splitbf(x.w, h.w, l.w);
        *(ushort4*)&Yh[row*PB + c4] = h;
        *(ushort4*)&Yl[row*PB + c4] = l;
    }
    __syncthreads();

    const int lane = t & 63;
    const int w = t >> 6;
    switch (w) {
        case 0:  ns_fused_body8<0>(Mh,Ml,Yh,Yl,outY,off,lane,niter); break;
        case 1:  ns_fused_body8<1>(Mh,Ml,Yh,Yl,outY,off,lane,niter); break;
        case 2:  ns_fused_body8<2>(Mh,Ml,Yh,Yl,outY,off,lane,niter); break;
        case 3:  ns_fused_body8<3>(Mh,Ml,Yh,Yl,outY,off,lane,niter); break;
        case 4:  ns_fused_body8<4>(Mh,Ml,Yh,Yl,outY,off,lane,niter); break;
        case 5:  ns_fused_body8<5>(Mh,Ml,Yh,Yl,outY,off,lane,niter); break;
        case 6:  ns_fused_body8<6>(Mh,Ml,Yh,Yl,outY,off,lane,niter); break;
        default: ns_fused_body8<7>(Mh,Ml,Yh,Yl,outY,off,lane,niter); break;
    }
}

// ---------------------------------------------------------------- fused poly
struct PolyCoefs {
    float a, bd;                          // P0 = a*X + bd*I
    float s1, s2;                         // inner: P = s1*(X*P) - s2*P + c*I
    float c0,c1,c2,c3,c4,c5,c6,c7;        // 8 inner coefficients
    float f1, f2, f3;                     // final: out = f1*(X*P) - f2*P + (f3+lns)*I
};

template<int W>
__device__ __forceinline__ void poly_fused_body8(
    const unsigned short* Xh, const unsigned short* Xl,
    unsigned short* Ph, unsigned short* Pl,
    float* Out, long long off, int lane, PolyCoefs pc, float lnsb)
{
    using TS = TileSet<W>;
    constexpr int NT_ = TS::N;
    const f32x4 z = {0.f, 0.f, 0.f, 0.f};
    f32x4 acc[NT_];

    for (int step = 0; step < 8; ++step) {
        #pragma unroll
        for (int i = 0; i < NT_; ++i) acc[i] = z;
        tri8_gemm<W>(Xh, Xl, Ph, Pl, lane, acc);
        float s3v;
        switch (step) {
            case 0: s3v = pc.c0; break;  case 1: s3v = pc.c1; break;
            case 2: s3v = pc.c2; break;  case 3: s3v = pc.c3; break;
            case 4: s3v = pc.c4; break;  case 5: s3v = pc.c5; break;
            case 6: s3v = pc.c6; break;  default: s3v = pc.c7; break;
        }
        #pragma unroll
        for (int i = 0; i < NT_; ++i)
            acc[i] = pepi(Ph, Pl, TS::tr(i), TS::tc(i), lane, acc[i], pc.s1, pc.s2, s3v);
        __syncthreads();   // all Ph/Pl reads done
        #pragma unroll
        for (int i = 0; i < NT_; ++i)
            st_split(Ph, Pl, TS::tr(i), TS::tc(i), lane, acc[i]);
        __syncthreads();
    }
    // final combine -> global
    #pragma unroll
    for (int i = 0; i < NT_; ++i) acc[i] = z;
    tri8_gemm<W>(Xh, Xl, Ph, Pl, lane, acc);
    const float dadd = pc.f3 + lnsb;
    #pragma unroll
    for (int i = 0; i < NT_; ++i) {
        f32x4 o = pepi(Ph, Pl, TS::tr(i), TS::tc(i), lane, acc[i], pc.f1, pc.f2, dadd);
        stg_sym(Out, off, TS::tr(i), TS::tc(i), lane, o);
    }
}

__global__ __launch_bounds__(512,1)
void poly_fused(const float* __restrict__ Xp, float* __restrict__ Out,
                const float* __restrict__ lns, PolyCoefs pc)
{
    __shared__ __align__(16) unsigned short pool[4*NM*PB];
    unsigned short* Xh = pool;
    unsigned short* Xl = pool + NM*PB;
    unsigned short* Ph = pool + 2*NM*PB;
    unsigned short* Pl = pool + 3*NM*PB;

    const int t = threadIdx.x;
    const long long b = blockIdx.x;
    const long long off = b << 14;
    for (int v = 0; v < 8; ++v) {
        int f = t + v*512;
        int row = f >> 5, c4 = (f & 31) << 2;
        float4 x = ((const float4*)(Xp + off))[f];
        float4 p;
        p.x = pc.a*x.x + ((c4+0)==row ? pc.bd : 0.f);
        p.y = pc.a*x.y + ((c4+1)==row ? pc.bd : 0.f);
        p.z = pc.a*x.z + ((c4+2)==row ? pc.bd : 0.f);
        p.w = pc.a*x.w + ((c4+3)==row ? pc.bd : 0.f);
        ushort4 h, l;
        splitbf(x.x, h.x, l.x); splitbf(x.y, h.y, l.y);
        splitbf(x.z, h.z, l.z); splitbf(x.w, h.w, l.w);
        *(ushort4*)&Xh[row*PB + c4] = h;
        *(ushort4*)&Xl[row*PB + c4] = l;
        splitbf(p.x, h.x, l.x); splitbf(p.y, h.y, l.y);
        splitbf(p.z, h.z, l.z); splitbf(p.w, h.w, l.w);
        *(ushort4*)&Ph[row*PB + c4] = h;
        *(ushort4*)&Pl[row*PB + c4] = l;
    }
    __syncthreads();

    const float lnsb = lns[b];
    const int lane = t & 63;
    const int w = t >> 6;
    switch (w) {
        case 0:  poly_fused_body8<0>(Xh,Xl,Ph,Pl,Out,off,lane,pc,lnsb); break;
        case 1:  poly_fused_body8<1>(Xh,Xl,Ph,Pl,Out,off,lane,pc,lnsb); break;
        case 2:  poly_fused_body8<2>(Xh,Xl,Ph,Pl,Out,off,lane,pc,lnsb); break;
        case 3:  poly_fused_body8<3>(Xh,Xl,Ph,Pl,Out,off,lane,pc,lnsb); break;
        case 4:  poly_fused_body8<4>(Xh,Xl,Ph,Pl,Out,off,lane,pc,lnsb); break;
        case 5:  poly_fused_body8<5>(Xh,Xl,Ph,Pl,Out,off,lane,pc,lnsb); break;
        case 6:  poly_fused_body8<6>(Xh,Xl,Ph,Pl,Out,off,lane,pc,lnsb); break;
        default: poly_fused_body8<7>(Xh,Xl,Ph,Pl,Out,off,lane,pc,lnsb); break;
    }
}

// ============================================================================
// Fallback (ws too small): round-1 parallel Jacobi
// ============================================================================
#define LDA  129
#define NT   512
#define MAX_SWEEPS 14

__global__ __launch_bounds__(NT, 1)
void logeig_jacobi(const float* __restrict__ in, float* __restrict__ out)
{
    __shared__ float A[NM][LDA];
    __shared__ float V[NM][LDA];
    __shared__ float rc[64], rs[64];
    __shared__ float logd[NM];
    __shared__ float roff[NT/64], rdia[NT/64];
    __shared__ int   s_done;

    const int t = threadIdx.x;
    const long long b = blockIdx.x;
    const float* __restrict__ Ain  = in  + (b << 14);
    float* __restrict__       Aout = out + (b << 14);

    for (int k = 0; k < (NM*NM)/NT; ++k) {
        int idx = t + k*NT;
        int i = idx >> 7, j = idx & 127;
        A[i][j] = Ain[idx];
        V[i][j] = (i == j) ? 1.0f : 0.0f;
    }
    __syncthreads();

    for (int sweep = 0; sweep < MAX_SWEEPS; ++sweep) {
        for (int r = 0; r < NM-1; ++r) {
            if (t < 64) {
                int m = t, p, q;
                if (m == 0) { p = NM-1; q = r; }
                else {
                    p = r + m;            if (p >= NM-1) p -= (NM-1);
                    q = r - m + (NM-1);   if (q >= NM-1) q -= (NM-1);
                }
                float app = A[p][p], aqq = A[q][q], apq = A[p][q];
                float c = 1.0f, s = 0.0f;
                if (fabsf(apq) > 1e-12f*(fabsf(app)+fabsf(aqq)) + 1e-32f) {
                    float tau = (aqq - app) * 0.5f / apq;
                    float tt  = 1.0f / (fabsf(tau) + sqrtf(fmaf(tau,tau,1.0f)));
                    tt = (tau < 0.0f) ? -tt : tt;
                    c = rsqrtf(fmaf(tt,tt,1.0f));
                    s = tt * c;
                }
                rc[m] = c; rs[m] = s;
            }
            __syncthreads();
            for (int k = 0; k < (2*64*NM)/NT; ++k) {
                int task = t + k*NT;
                int i   = task & 127;
                int m   = (task >> 7) & 63;
                int isV = task >> 13;
                int p, q;
                if (m == 0) { p = NM-1; q = r; }
                else {
                    p = r + m;            if (p >= NM-1) p -= (NM-1);
                    q = r - m + (NM-1);   if (q >= NM-1) q -= (NM-1);
                }
                float c = rc[m], s = rs[m];
                if (isV == 0) {
                    float x = A[i][p], y = A[i][q];
                    A[i][p] = c*x - s*y;
                    A[i][q] = s*x + c*y;
                } else {
                    float x = V[i][p], y = V[i][q];
                    V[i][p] = c*x - s*y;
                    V[i][q] = s*x + c*y;
                }
            }
            __syncthreads();
            for (int k = 0; k < (64*NM)/NT; ++k) {
                int task = t + k*NT;
                int j = task & 127;
                int m = task >> 7;
                int p, q;
                if (m == 0) { p = NM-1; q = r; }
                else {
                    p = r + m;            if (p >= NM-1) p -= (NM-1);
                    q = r - m + (NM-1);   if (q >= NM-1) q -= (NM-1);
                }
                float c = rc[m], s = rs[m];
                float x = A[p][j], y = A[q][j];
                A[p][j] = c*x - s*y;
                A[q][j] = s*x + c*y;
            }
            __syncthreads();
        }
        float off2 = 0.0f, dia2 = 0.0f;
        for (int k = 0; k < (NM*NM)/NT; ++k) {
            int idx = t + k*NT;
            int i = idx >> 7, j = idx & 127;
            float v = A[i][j];
            if (i == j) dia2 += v*v; else off2 += v*v;
        }
        #pragma unroll
        for (int o = 32; o > 0; o >>= 1) {
            off2 += __shfl_down(off2, o, 64);
            dia2 += __shfl_down(dia2, o, 64);
        }
        if ((t & 63) == 0) { roff[t >> 6] = off2; rdia[t >> 6] = dia2; }
        __syncthreads();
        if (t == 0) {
            float o2 = 0.0f, d2 = 0.0f;
            for (int w = 0; w < NT/64; ++w) { o2 += roff[w]; d2 += rdia[w]; }
            s_done = (o2 <= 1e-13f * d2) ? 1 : 0;
        }
        __syncthreads();
        if (s_done) break;
    }

    if (t < NM) logd[t] = logf(fmaxf(A[t][t], 1e-12f));
    __syncthreads();
    for (int kk = 0; kk < (NM*NM)/NT; ++kk) {
        int idx = t + kk*NT;
        int i = idx >> 7, k = idx & 127;
        A[i][k] = V[i][k] * logd[k];
    }
    __syncthreads();
    {
        int i  = t >> 2;
        int jb = t & 3;
        float acc[32];
        #pragma unroll
        for (int jj = 0; jj < 32; ++jj) acc[jj] = 0.0f;
        for (int kk = 0; kk < NM; ++kk) {
            int k = (kk + jb) & 127;
            float w = A[i][k];
            #pragma unroll
            for (int jj = 0; jj < 32; ++jj)
                acc[jj] = fmaf(w, V[jb*32 + jj][k], acc[jj]);
        }
        #pragma unroll
        for (int jj = 0; jj < 32; ++jj)
            Aout[i*NM + jb*32 + jj] = acc[jj];
    }
}

// ============================================================================
// Host
// ============================================================================
static void cheb_log_power(double lo, double up, int deg, double* p)
{
    const int NC = deg + 1;
    const int MN = 64;
    double mid = 0.5*(lo+up), hw = 0.5*(up-lo);
    double cc[32];
    for (int j = 0; j < NC; ++j) {
        double s = 0.0;
        for (int m = 0; m < MN; ++m) {
            double th = M_PI*(m+0.5)/MN;
            s += log(mid + hw*cos(th)) * cos(j*th);
        }
        cc[j] = 2.0*s/MN;
    }
    double Tp[32] = {0}, Tc[32] = {0}, Tn[32];
    for (int j = 0; j < NC; ++j) p[j] = 0.0;
    Tp[0] = 1.0;  p[0] += 0.5*cc[0];
    Tc[1] = 1.0;  p[1] += cc[1];
    for (int k = 2; k <= deg; ++k) {
        for (int j = 0; j < NC; ++j) Tn[j] = -Tp[j];
        for (int j = 1; j < NC; ++j) Tn[j] += 2.0*Tc[j-1];
        for (int j = 0; j < NC; ++j) { p[j] += cc[k]*Tn[j]; Tp[j] = Tc[j]; Tc[j] = Tn[j]; }
    }
}

extern "C" void kernel_launch(void* const* d_in, const int* in_sizes, int n_in,
                              void* d_out, int out_size, void* d_ws, size_t ws_size,
                              hipStream_t stream) {
    const float* in = (const float*)d_in[0];
    float* out = (float*)d_out;
    const int batch = in_sizes[0] >> 14;                 // 4096
    const size_t matBytes = (size_t)batch * NM * NM * 4; // 256 MB
    const size_t need = matBytes + (size_t)batch * 4;

    if (ws_size < need) {   // fallback
        logeig_jacobi<<<batch, NT, 0, stream>>>(in, out);
        return;
    }

    float* Mbuf = (float*)d_ws;
    float* lns  = (float*)((char*)d_ws + matBytes);

    // --- scaling: s0 = gersh(A); tighten via sqrt(gersh((A/s0)^2)) ---
    scale_kernel<<<batch, 256, 0, stream>>>(in, out, Mbuf, lns);      // out = X0
    gram_tri<<<batch, 512, 0, stream>>>(out, Mbuf);                   // Mbuf = X0^2
    rescale_kernel<<<batch, 256, 0, stream>>>(Mbuf, out, Mbuf, lns);  // out=Mbuf=X

    // --- L1 iters 0-3: f32 lower-triangle (precision-critical) ---
    for (int j = 0; j < 4; ++j)
        ns_tri<<<batch, 512, 0, stream>>>(Mbuf, out, Mbuf, out,
                                          1.5f, sqrtf(1.5f));

    // --- fused MFMA NS segments (schedule {1.5 x(n-3), 1.116, 1, 1}) ---
    ns_fused<<<batch, 512, 0, stream>>>(Mbuf, out, out, 8);  // L1 iters 4..11
    ns_fused<<<batch, 512, 0, stream>>>(out,  out, out, 8);  // L2 (M0=Y0)
    ns_fused<<<batch, 512, 0, stream>>>(out,  out, out, 6);  // L3 (M0=Y0)

    // --- fused Chebyshev-minimax log, deg 10 on [0.25, 1.002] ---
    const double lo = 0.25, up = 1.002;
    const double mid = 0.5*(lo+up), hw = 0.5*(up-lo);
    double p[11];
    cheb_log_power(lo, up, 10, p);

    PolyCoefs pc;
    pc.a  = (float)(p[10]/hw);
    pc.bd = (float)(p[9] - p[10]*mid/hw);
    pc.s1 = (float)(1.0/hw);
    pc.s2 = (float)(mid/hw);
    pc.c0 = (float)p[8]; pc.c1 = (float)p[7]; pc.c2 = (float)p[6];
    pc.c3 = (float)p[5]; pc.c4 = (float)p[4]; pc.c5 = (float)p[3];
    pc.c6 = (float)p[2]; pc.c7 = (float)p[1];
    pc.f1 = (float)(8.0/hw);
    pc.f2 = (float)(8.0*mid/hw);
    pc.f3 = (float)(8.0*p[0]);

    poly_fused<<<batch, 512, 0, stream>>>(out, out, lns, pc);
}

// Round 11
// 7207.464 us; speedup vs baseline: 16.6820x; 1.0123x over previous
//
#include <hip/hip_runtime.h>
#include <hip/hip_bf16.h>
#include <math.h>

#define NM   128
#define PAD  132   // f32 LDS pitch
#define PB   136   // u16 LDS pitch for MFMA splits

typedef __attribute__((ext_vector_type(8))) short bf16x8;
typedef __attribute__((ext_vector_type(4))) float f32x4;

// ============================================================================
// log(A) = ln(s) I + 8 * cheb_log( NS_sqrt^3( A/s ) ).
// Round-11: (1) ns_fused/poly_fused at 16 waves (quarter-split tile partition;
// 4 waves/SIMD for latency hiding), (2) ns_tri4 = all 4 f32 iterations fused,
// Y' held in registers while T overlays Y's LDS, (3) Chebyshev deg 8.
// Invariants (rounds 6-8): every matrix written is EXACTLY symmetric
// (mirror-write + symdiag-on-full-output); passthrough terms read LDS-resident
// data only, never possibly-aliased global buffers.
// ============================================================================

// ---------------------------------------------------------------- f32 kernels
__global__ __launch_bounds__(256,1)
void scale_kernel(const float* __restrict__ A, float* __restrict__ outY,
                  float* __restrict__ outM, float* __restrict__ lns)
{
    __shared__ __align__(16) float L[NM][PAD];
    __shared__ float rs[NM];
    __shared__ float s_inv;
    const int t = threadIdx.x;
    const long long b = blockIdx.x;
    const long long off = b << 14;
    for (int v = 0; v < 16; ++v) {
        int f = t + v*256;
        int row = f >> 5, c4 = (f & 31) << 2;
        *(float4*)&L[row][c4] = ((const float4*)(A + off))[f];
    }
    __syncthreads();
    if (t < NM) {
        float s = 0.f;
        for (int j = 0; j < NM; ++j) s += fabsf(L[t][j]);
        rs[t] = s;
    }
    __syncthreads();
    if (t < 64) {
        float m = fmaxf(rs[t], rs[t+64]);
        #pragma unroll
        for (int o = 32; o > 0; o >>= 1) m = fmaxf(m, __shfl_down(m, o, 64));
        if (t == 0) { s_inv = 1.0f/m; lns[b] = logf(m); }
    }
    __syncthreads();
    const float inv = s_inv;
    for (int v = 0; v < 16; ++v) {
        int f = t + v*256;
        int row = f >> 5, c4 = (f & 31) << 2;
        float4 x = *(const float4*)&L[row][c4];
        x.x *= inv; x.y *= inv; x.z *= inv; x.w *= inv;
        ((float4*)(outY + off))[f] = x;
        ((float4*)(outM + off))[f] = x;
    }
}

__global__ __launch_bounds__(256,1)
void rescale_kernel(const float* __restrict__ Sq, float* __restrict__ X,
                    float* __restrict__ M, float* __restrict__ lns)
{
    __shared__ __align__(16) float L[NM][PAD];
    __shared__ float rs[NM];
    __shared__ float s_g;
    const int t = threadIdx.x;
    const long long b = blockIdx.x;
    const long long off = b << 14;
    for (int v = 0; v < 16; ++v) {
        int f = t + v*256;
        int row = f >> 5, c4 = (f & 31) << 2;
        *(float4*)&L[row][c4] = ((const float4*)(Sq + off))[f];
    }
    __syncthreads();
    if (t < NM) {
        float s = 0.f;
        for (int j = 0; j < NM; ++j) s += fabsf(L[t][j]);
        rs[t] = s;
    }
    __syncthreads();
    if (t < 64) {
        float m = fmaxf(rs[t], rs[t+64]);
        #pragma unroll
        for (int o = 32; o > 0; o >>= 1) m = fmaxf(m, __shfl_down(m, o, 64));
        if (t == 0) { s_g = 1.0f/sqrtf(m); lns[b] = lns[b] + 0.5f*logf(m); }
    }
    __syncthreads();
    const float g = s_g;
    for (int v = 0; v < 16; ++v) {
        int f = t + v*256;
        float4 x = ((const float4*)(X + off))[f];
        x.x *= g; x.y *= g; x.z *= g; x.w *= g;
        ((float4*)(X + off))[f] = x;
        ((float4*)(M + off))[f] = x;
    }
}

// triangular index decode: u -> (bi,bj), bj<=bi
__device__ __forceinline__ void tridec(int u, int &bi, int &bj) {
    int b = (int)(0.5f*(sqrtf(8.0f*(float)u + 1.0f) - 1.0f));
    while ((b+1)*(b+2)/2 <= u) ++b;
    while (b*(b+1)/2 > u) --b;
    bi = b; bj = u - b*(b+1)/2;
}

// Gram: Out = X^T X (= X^2 for symmetric X), lower-triangle + mirror
__global__ __launch_bounds__(512,1)
void gram_tri(const float* __restrict__ X, float* __restrict__ Out)
{
    __shared__ __align__(16) float LX[NM][PAD];
    const int t = threadIdx.x;
    const long long off = (long long)blockIdx.x << 14;
    for (int v = 0; v < 8; ++v) {
        int f = t + v*512;
        int row = f >> 5, c4 = (f & 31) << 2;
        *(float4*)&LX[row][c4] = ((const float4*)(X + off))[f];
    }
    __syncthreads();
    for (int u = t; u < 528; u += 512) {
        int bi, bj; tridec(u, bi, bj);
        const int r4 = bi << 2, c4 = bj << 2;
        float acc[4][4];
        #pragma unroll
        for (int i = 0; i < 4; ++i)
            #pragma unroll
            for (int j = 0; j < 4; ++j) acc[i][j] = 0.f;
        #pragma unroll 4
        for (int k = 0; k < NM; ++k) {
            float av[4], bv[4];
            *(float4*)av = *(const float4*)&LX[k][r4];
            *(float4*)bv = *(const float4*)&LX[k][c4];
            #pragma unroll
            for (int i = 0; i < 4; ++i)
                #pragma unroll
                for (int j = 0; j < 4; ++j) acc[i][j] = fmaf(av[i], bv[j], acc[i][j]);
        }
        #pragma unroll
        for (int i = 0; i < 4; ++i)
            *(float4*)&Out[off + (long long)(r4+i)*NM + c4] =
                make_float4(acc[i][0], acc[i][1], acc[i][2], acc[i][3]);
        if (bi != bj) {
            #pragma unroll
            for (int j = 0; j < 4; ++j)
                *(float4*)&Out[off + (long long)(c4+j)*NM + r4] =
                    make_float4(acc[0][j], acc[1][j], acc[2][j], acc[3][j]);
        }
    }
}

// ---- fused 4-iteration f32 NS (lower-triangle tiles, Y' in regs over T) ----
__device__ __forceinline__ void tri_p1_reg(const float (*LM)[PAD], const float (*LY)[PAD],
                                           int bi, int bj, float a15, float a05,
                                           float o[4][4])
{
    const int r4 = bi << 2, c4 = bj << 2;
    float acc[4][4];
    #pragma unroll
    for (int i = 0; i < 4; ++i)
        #pragma unroll
        for (int j = 0; j < 4; ++j) acc[i][j] = 0.f;
    #pragma unroll 4
    for (int k = 0; k < NM; ++k) {
        float av[4], bv[4];
        *(float4*)av = *(const float4*)&LY[k][r4];
        *(float4*)bv = *(const float4*)&LM[k][c4];
        #pragma unroll
        for (int i = 0; i < 4; ++i)
            #pragma unroll
            for (int j = 0; j < 4; ++j) acc[i][j] = fmaf(av[i], bv[j], acc[i][j]);
    }
    #pragma unroll
    for (int i = 0; i < 4; ++i)
        #pragma unroll
        for (int j = 0; j < 4; ++j)
            o[i][j] = a15*LY[r4+i][c4+j] - a05*acc[i][j];
    if (bi == bj) {
        #pragma unroll
        for (int i = 0; i < 4; ++i)
            #pragma unroll
            for (int j = 0; j < 4; ++j)
                if (j > i) { float s = 0.5f*(o[i][j] + o[j][i]); o[i][j] = s; o[j][i] = s; }
    }
}

__device__ __forceinline__ void tri_p2_lds(const float (*LM)[PAD], float (*LY)[PAD],
                                           int bi, int bj)
{
    const int r4 = bi << 2, c4 = bj << 2;
    float acc[4][4];
    #pragma unroll
    for (int i = 0; i < 4; ++i)
        #pragma unroll
        for (int j = 0; j < 4; ++j) acc[i][j] = 0.f;
    #pragma unroll 4
    for (int k = 0; k < NM; ++k) {
        float av[4], bv[4];
        *(float4*)av = *(const float4*)&LM[k][r4];
        *(float4*)bv = *(const float4*)&LM[k][c4];
        #pragma unroll
        for (int i = 0; i < 4; ++i)
            #pragma unroll
            for (int j = 0; j < 4; ++j) acc[i][j] = fmaf(av[i], bv[j], acc[i][j]);
    }
    #pragma unroll
    for (int i = 0; i < 4; ++i)
        *(float4*)&LY[r4+i][c4] = make_float4(acc[i][0], acc[i][1], acc[i][2], acc[i][3]);
    if (bi != bj) {
        #pragma unroll
        for (int j = 0; j < 4; ++j)
            *(float4*)&LY[c4+j][r4] = make_float4(acc[0][j], acc[1][j], acc[2][j], acc[3][j]);
    }
}

__device__ __forceinline__ void tri_p3_reg(const float (*LM)[PAD], const float (*LY)[PAD],
                                           int bi, int bj, float q, float o[4][4])
{
    const int r4 = bi << 2, c4 = bj << 2;
    float acc[4][4];
    #pragma unroll
    for (int i = 0; i < 4; ++i)
        #pragma unroll
        for (int j = 0; j < 4; ++j) acc[i][j] = 0.f;
    #pragma unroll 4
    for (int k = 0; k < NM; ++k) {
        float av[4], bv[4];
        *(float4*)av = *(const float4*)&LM[k][r4];
        *(float4*)bv = *(const float4*)&LY[k][c4];
        #pragma unroll
        for (int i = 0; i < 4; ++i)
            #pragma unroll
            for (int j = 0; j < 4; ++j) acc[i][j] = fmaf(av[i], bv[j], acc[i][j]);
    }
    #pragma unroll
    for (int i = 0; i < 4; ++i)
        #pragma unroll
        for (int j = 0; j < 4; ++j)
            o[i][j] = q*(9.f*LM[r4+i][c4+j] - 6.f*LY[r4+i][c4+j] + acc[i][j]);
    if (bi == bj) {
        #pragma unroll
        for (int i = 0; i < 4; ++i)
            #pragma unroll
            for (int j = 0; j < 4; ++j)
                if (j > i) { float s = 0.5f*(o[i][j] + o[j][i]); o[i][j] = s; o[j][i] = s; }
    }
}

__device__ __forceinline__ void tri_wb(float (*L)[PAD], int bi, int bj, const float o[4][4])
{
    const int r4 = bi << 2, c4 = bj << 2;
    #pragma unroll
    for (int i = 0; i < 4; ++i)
        *(float4*)&L[r4+i][c4] = make_float4(o[i][0], o[i][1], o[i][2], o[i][3]);
    if (bi != bj) {
        #pragma unroll
        for (int j = 0; j < 4; ++j)
            *(float4*)&L[c4+j][r4] = make_float4(o[0][j], o[1][j], o[2][j], o[3][j]);
    }
}

__global__ __launch_bounds__(512,1)
void ns_tri4(const float* __restrict__ Mp, const float* __restrict__ Yp,
             float* __restrict__ outM, float* __restrict__ outY, int niter)
{
    __shared__ __align__(16) float LM[NM][PAD];
    __shared__ __align__(16) float LY[NM][PAD];   // holds Y, then T, then Y'
    const int t = threadIdx.x;
    const long long off = (long long)blockIdx.x << 14;
    for (int v = 0; v < 8; ++v) {
        int f = t + v*512;
        int row = f >> 5, c4 = (f & 31) << 2;
        *(float4*)&LM[row][c4] = ((const float4*)(Mp + off))[f];
        *(float4*)&LY[row][c4] = ((const float4*)(Yp + off))[f];
    }
    __syncthreads();

    int b0i, b0j, b1i = -1, b1j = 0;
    tridec(t, b0i, b0j);
    if (t < 16) tridec(512 + t, b1i, b1j);

    const float cc = 1.5f, dd = sqrtf(1.5f);
    const float a15 = 1.5f*dd, a05 = 0.5f*dd, q = 0.25f*cc;
    float y0[4][4], y1[4][4], m0[4][4], m1[4][4];

    for (int it = 0; it < niter; ++it) {
        tri_p1_reg(LM, LY, b0i, b0j, a15, a05, y0);
        if (b1i >= 0) tri_p1_reg(LM, LY, b1i, b1j, a15, a05, y1);
        __syncthreads();                    // all Y reads done
        tri_p2_lds(LM, LY, b0i, b0j);       // LY <- T = M*M
        if (b1i >= 0) tri_p2_lds(LM, LY, b1i, b1j);
        __syncthreads();
        tri_p3_reg(LM, LY, b0i, b0j, q, m0);
        if (b1i >= 0) tri_p3_reg(LM, LY, b1i, b1j, q, m1);
        __syncthreads();                    // all M/T reads done
        tri_wb(LM, b0i, b0j, m0);
        tri_wb(LY, b0i, b0j, y0);
        if (b1i >= 0) { tri_wb(LM, b1i, b1j, m1); tri_wb(LY, b1i, b1j, y1); }
        __syncthreads();
    }

    for (int v = 0; v < 8; ++v) {
        int f = t + v*512;
        int row = f >> 5, c4 = (f & 31) << 2;
        ((float4*)(outM + off))[f] = *(const float4*)&LM[row][c4];
        ((float4*)(outY + off))[f] = *(const float4*)&LY[row][c4];
    }
}

// ---------------------------------------------------------------- MFMA common
__device__ __forceinline__ f32x4 mfma16(bf16x8 a, bf16x8 b, f32x4 c) {
    return __builtin_amdgcn_mfma_f32_16x16x32_bf16(a, b, c, 0, 0, 0);
}

__device__ __forceinline__ void splitbf(float x, unsigned short &h, unsigned short &l) {
    __hip_bfloat16 bh = __float2bfloat16(x);
    float r = x - __bfloat162float(bh);
    __hip_bfloat16 bl = __float2bfloat16(r);
    h = *(unsigned short*)&bh;
    l = *(unsigned short*)&bl;
}

__device__ __forceinline__ float ldsM(const unsigned short* __restrict__ H,
                                      const unsigned short* __restrict__ L,
                                      int row, int col) {
    unsigned int uh = ((unsigned int)H[row*PB + col]) << 16;
    unsigned int ul = ((unsigned int)L[row*PB + col]) << 16;
    return __uint_as_float(uh) + __uint_as_float(ul);
}

__device__ __forceinline__ bf16x8 ldfrag(const unsigned short* __restrict__ a,
                                         int rb, int lane, int kc) {
    int row = rb*16 + (lane & 15);
    int col = kc*32 + ((lane >> 4) & 3)*8;
    return *(const bf16x8*)(a + row*PB + col);
}

// Exact symmetrization of a DIAGONAL 16x16 tile (C/D layout: col=lane&15,
// row=(lane>>4)*4+reg; transpose of (row rb+r, col) at lane'=4g+r+16(j>>2)).
__device__ __forceinline__ f32x4 symdiag(f32x4 a, int lane) {
    const int g = (lane >> 4) & 3, j = lane & 15;
    const int rp = j & 3;
    f32x4 out;
    #pragma unroll
    for (int r = 0; r < 4; ++r) {
        int lp = 4*g + r + ((j >> 2) << 4);
        float t0 = __shfl(a[0], lp, 64);
        float t1 = __shfl(a[1], lp, 64);
        float t2 = __shfl(a[2], lp, 64);
        float t3 = __shfl(a[3], lp, 64);
        float tv = (rp == 0) ? t0 : (rp == 1) ? t1 : (rp == 2) ? t2 : t3;
        out[r] = 0.5f*(a[r] + tv);
    }
    return out;
}

// write symmetric tile back to LDS as hi/lo splits (+ mirror)
__device__ __forceinline__ void st_split(unsigned short* __restrict__ H,
                                         unsigned short* __restrict__ L,
                                         int Tr, int Tc, int lane, f32x4 o) {
    int col = Tc*16 + (lane & 15);
    int rb  = Tr*16 + ((lane >> 4) & 3)*4;
    #pragma unroll
    for (int r = 0; r < 4; ++r) {
        unsigned short h, l;
        splitbf(o[r], h, l);
        H[(rb+r)*PB + col] = h;
        L[(rb+r)*PB + col] = l;
        if (Tr != Tc) { H[col*PB + rb + r] = h; L[col*PB + rb + r] = l; }
    }
}

__device__ __forceinline__ void stg_sym(float* __restrict__ out, long long off,
                                        int Tr, int Tc, int lane, f32x4 o) {
    int col = Tc*16 + (lane & 15);
    int rb  = Tr*16 + ((lane >> 4) & 3)*4;
    #pragma unroll
    for (int r = 0; r < 4; ++r)
        out[off + (long long)(rb+r)*NM + col] = o[r];
    if (Tr != Tc)
        *(f32x4*)&out[off + (long long)col*NM + rb] = o;
}

__device__ __forceinline__ f32x4 yepi(const unsigned short* __restrict__ Yh,
                                      const unsigned short* __restrict__ Yl,
                                      int Tr, int Tc, int lane, f32x4 a,
                                      float a15, float a05) {
    int col = Tc*16 + (lane & 15);
    int rb  = Tr*16 + ((lane >> 4) & 3)*4;
    f32x4 o;
    #pragma unroll
    for (int r = 0; r < 4; ++r)
        o[r] = a15*ldsM(Yh, Yl, rb+r, col) - a05*a[r];
    if (Tr == Tc) o = symdiag(o, lane);
    return o;
}

__device__ __forceinline__ f32x4 mepi(const unsigned short* __restrict__ Mh,
                                      const unsigned short* __restrict__ Ml,
                                      const unsigned short* __restrict__ Th,
                                      const unsigned short* __restrict__ Tl,
                                      int Tr, int Tc, int lane, f32x4 a, float q) {
    int col = Tc*16 + (lane & 15);
    int rb  = Tr*16 + ((lane >> 4) & 3)*4;
    f32x4 o;
    #pragma unroll
    for (int r = 0; r < 4; ++r)
        o[r] = q*(9.f*ldsM(Mh, Ml, rb+r, col) - 6.f*ldsM(Th, Tl, rb+r, col) + a[r]);
    if (Tr == Tc) o = symdiag(o, lane);
    return o;
}

__device__ __forceinline__ f32x4 pepi(const unsigned short* __restrict__ Ph,
                                      const unsigned short* __restrict__ Pl,
                                      int Tr, int Tc, int lane, f32x4 a,
                                      float s1, float s2, float dadd) {
    int col = Tc*16 + (lane & 15);
    int rb  = Tr*16 + ((lane >> 4) & 3)*4;
    f32x4 o;
    #pragma unroll
    for (int r = 0; r < 4; ++r)
        o[r] = s1*a[r] - s2*ldsM(Ph, Pl, rb+r, col) + ((rb+r) == col ? dadd : 0.f);
    if (Tr == Tc) o = symdiag(o, lane);
    return o;
}

// ---- 16-wave tile partition: P = W>>2 -> rows (P, 7-P) = 9 tiles g=0..8,
// quarter Q = W&3 takes g in {Q, Q+4, Q+8} (3 or 2 tiles). Union over the
// 16 waves = all 36 lower-triangle tiles, each exactly once.
template<int W>
struct TS16 {
    static constexpr int P  = W >> 2;
    static constexpr int Q  = W & 3;
    static constexpr int R0 = P;
    static constexpr int R1 = 7 - P;
    static constexpr int N  = (Q == 0) ? 3 : 2;
    static constexpr int g(int i)  { return 4*i + Q; }
    static constexpr int tr(int i) { return g(i) <= R0 ? R0 : R1; }
    static constexpr int tc(int i) { return g(i) <= R0 ? g(i) : g(i) - R0 - 1; }
};

template<int W>
__device__ __forceinline__ void tri16_gemm(const unsigned short* __restrict__ Ah,
                                           const unsigned short* __restrict__ Al,
                                           const unsigned short* __restrict__ Bh,
                                           const unsigned short* __restrict__ Bl,
                                           int lane, f32x4* acc) {
    using TS = TS16<W>;
    #pragma unroll
    for (int kc = 0; kc < 4; ++kc) {
        bf16x8 a0h = ldfrag(Ah, TS::R0, lane, kc), a0l = ldfrag(Al, TS::R0, lane, kc);
        bf16x8 a1h = ldfrag(Ah, TS::R1, lane, kc), a1l = ldfrag(Al, TS::R1, lane, kc);
        #pragma unroll
        for (int i = 0; i < TS::N; ++i) {
            const int r = TS::tr(i), c = TS::tc(i);
            bf16x8 bh = ldfrag(Bh, c, lane, kc), bl = ldfrag(Bl, c, lane, kc);
            bf16x8 ah = (r == TS::R0) ? a0h : a1h;
            bf16x8 al = (r == TS::R0) ? a0l : a1l;
            acc[i] = mfma16(ah, bh, acc[i]);
            acc[i] = mfma16(ah, bl, acc[i]);
            acc[i] = mfma16(al, bh, acc[i]);
        }
    }
}

// ---------------------------------------------------------------- fused NS
template<int W>
__device__ __forceinline__ void ns_fused_body16(
    unsigned short* Mh, unsigned short* Ml,
    unsigned short* Yh, unsigned short* Yl,    // Yh/Yl double as Th/Tl
    float* outY, long long off, int lane, int niter)
{
    using TS = TS16<W>;
    constexpr int NT_ = TS::N;
    const f32x4 z = {0.f, 0.f, 0.f, 0.f};
    f32x4 acc[NT_], yv[NT_];

    for (int j = 0; j < niter; ++j) {
        const int last = (j == niter-1);
        // schedule: 1.5 x(niter-3), 1.116, 1, 1 (certified c<=1.5 cap)
        const float cc = (j < niter-3) ? 1.5f : ((j == niter-3) ? 1.116f : 1.0f);
        const float dd = sqrtf(cc);
        const float a15 = 1.5f*dd, a05 = 0.5f*dd;

        // ---- phase 1: Y' = a15*Y - a05*(Y*M) -> regs ----
        #pragma unroll
        for (int i = 0; i < NT_; ++i) acc[i] = z;
        tri16_gemm<W>(Yh, Yl, Mh, Ml, lane, acc);
        #pragma unroll
        for (int i = 0; i < NT_; ++i)
            yv[i] = yepi(Yh, Yl, TS::tr(i), TS::tc(i), lane, acc[i], a15, a05);

        if (last) {
            #pragma unroll
            for (int i = 0; i < NT_; ++i)
                stg_sym(outY, off, TS::tr(i), TS::tc(i), lane, yv[i]);
            return;
        }
        __syncthreads();   // all Yh/Yl reads done; T overlays

        // ---- phase 2: T = M*M (split bf16 into Yh/Yl region) ----
        #pragma unroll
        for (int i = 0; i < NT_; ++i) acc[i] = z;
        tri16_gemm<W>(Mh, Ml, Mh, Ml, lane, acc);
        #pragma unroll
        for (int i = 0; i < NT_; ++i)
            st_split(Yh, Yl, TS::tr(i), TS::tc(i), lane, acc[i]);
        __syncthreads();

        // ---- phase 3: M' = q*(9M - 6T + M*T) ----
        #pragma unroll
        for (int i = 0; i < NT_; ++i) acc[i] = z;
        tri16_gemm<W>(Mh, Ml, Yh, Yl, lane, acc);
        const float q = 0.25f*cc;
        #pragma unroll
        for (int i = 0; i < NT_; ++i)
            acc[i] = mepi(Mh, Ml, Yh, Yl, TS::tr(i), TS::tc(i), lane, acc[i], q);
        __syncthreads();   // all Mh/Ml/T reads done

        // ---- writeback M', Y' splits ----
        #pragma unroll
        for (int i = 0; i < NT_; ++i)
            st_split(Mh, Ml, TS::tr(i), TS::tc(i), lane, acc[i]);
        #pragma unroll
        for (int i = 0; i < NT_; ++i)
            st_split(Yh, Yl, TS::tr(i), TS::tc(i), lane, yv[i]);
        __syncthreads();
    }
}

__global__ __launch_bounds__(1024,1)
void ns_fused(const float* __restrict__ Mp, const float* __restrict__ Yp,
              float* __restrict__ outY, int niter)
{
    __shared__ __align__(16) unsigned short pool[4*NM*PB];
    unsigned short* Mh = pool;
    unsigned short* Ml = pool + NM*PB;
    unsigned short* Yh = pool + 2*NM*PB;
    unsigned short* Yl = pool + 3*NM*PB;

    const int t = threadIdx.x;
    const long long off = (long long)blockIdx.x << 14;
    for (int v = 0; v < 4; ++v) {
        int f = t + v*1024;
        int row = f >> 5, c4 = (f & 31) << 2;
        float4 x = ((const float4*)(Mp + off))[f];
        ushort4 h, l;
        splitbf(x.x, h.x, l.x); splitbf(x.y, h.y, l.y);
        splitbf(x.z, h.z, l.z); splitbf(x.w, h.w, l.w);
        *(ushort4*)&Mh[row*PB + c4] = h;
        *(ushort4*)&Ml[row*PB + c4] = l;
        x = ((const float4*)(Yp + off))[f];
        splitbf(x.x, h.x, l.x); splitbf(x.y, h.y, l.y);
        splitbf(x.z, h.z, l.z); splitbf(x.w, h.w, l.w);
        *(ushort4*)&Yh[row*PB + c4] = h;
        *(ushort4*)&Yl[row*PB + c4] = l;
    }
    __syncthreads();

    const int lane = t & 63;
    const int w = t >> 6;
    switch (w) {
        case 0:  ns_fused_body16<0>(Mh,Ml,Yh,Yl,outY,off,lane,niter); break;
        case 1:  ns_fused_body16<1>(Mh,Ml,Yh,Yl,outY,off,lane,niter); break;
        case 2:  ns_fused_body16<2>(Mh,Ml,Yh,Yl,outY,off,lane,niter); break;
        case 3:  ns_fused_body16<3>(Mh,Ml,Yh,Yl,outY,off,lane,niter); break;
        case 4:  ns_fused_body16<4>(Mh,Ml,Yh,Yl,outY,off,lane,niter); break;
        case 5:  ns_fused_body16<5>(Mh,Ml,Yh,Yl,outY,off,lane,niter); break;
        case 6:  ns_fused_body16<6>(Mh,Ml,Yh,Yl,outY,off,lane,niter); break;
        case 7:  ns_fused_body16<7>(Mh,Ml,Yh,Yl,outY,off,lane,niter); break;
        case 8:  ns_fused_body16<8>(Mh,Ml,Yh,Yl,outY,off,lane,niter); break;
        case 9:  ns_fused_body16<9>(Mh,Ml,Yh,Yl,outY,off,lane,niter); break;
        case 10: ns_fused_body16<10>(Mh,Ml,Yh,Yl,outY,off,lane,niter); break;
        case 11: ns_fused_body16<11>(Mh,Ml,Yh,Yl,outY,off,lane,niter); break;
        case 12: ns_fused_body16<12>(Mh,Ml,Yh,Yl,outY,off,lane,niter); break;
        case 13: ns_fused_body16<13>(Mh,Ml,Yh,Yl,outY,off,lane,niter); break;
        case 14: ns_fused_body16<14>(Mh,Ml,Yh,Yl,outY,off,lane,niter); break;
        default: ns_fused_body16<15>(Mh,Ml,Yh,Yl,outY,off,lane,niter); break;
    }
}

// ---------------------------------------------------------------- fused poly
struct PolyCoefs {
    float a, bd;                          // P0 = a*X + bd*I
    float s1, s2;                         // inner: P = s1*(X*P) - s2*P + c*I
    float c0,c1,c2,c3,c4,c5;              // 6 inner coefficients (deg 8)
    float f1, f2, f3;                     // final: out = f1*(X*P) - f2*P + (f3+lns)*I
};

template<int W>
__device__ __forceinline__ void poly_fused_body16(
    const unsigned short* Xh, const unsigned short* Xl,
    unsigned short* Ph, unsigned short* Pl,
    float* Out, long long off, int lane, PolyCoefs pc, float lnsb)
{
    using TS = TS16<W>;
    constexpr int NT_ = TS::N;
    const f32x4 z = {0.f, 0.f, 0.f, 0.f};
    f32x4 acc[NT_];

    for (int step = 0; step < 6; ++step) {
        #pragma unroll
        for (int i = 0; i < NT_; ++i) acc[i] = z;
        tri16_gemm<W>(Xh, Xl, Ph, Pl, lane, acc);
        float s3v;
        switch (step) {
            case 0: s3v = pc.c0; break;  case 1: s3v = pc.c1; break;
            case 2: s3v = pc.c2; break;  case 3: s3v = pc.c3; break;
            case 4: s3v = pc.c4; break;  default: s3v = pc.c5; break;
        }
        #pragma unroll
        for (int i = 0; i < NT_; ++i)
            acc[i] = pepi(Ph, Pl, TS::tr(i), TS::tc(i), lane, acc[i], pc.s1, pc.s2, s3v);
        __syncthreads();   // all Ph/Pl reads done
        #pragma unroll
        for (int i = 0; i < NT_; ++i)
            st_split(Ph, Pl, TS::tr(i), TS::tc(i), lane, acc[i]);
        __syncthreads();
    }
    // final combine -> global
    #pragma unroll
    for (int i = 0; i < NT_; ++i) acc[i] = z;
    tri16_gemm<W>(Xh, Xl, Ph, Pl, lane, acc);
    const float dadd = pc.f3 + lnsb;
    #pragma unroll
    for (int i = 0; i < NT_; ++i) {
        f32x4 o = pepi(Ph, Pl, TS::tr(i), TS::tc(i), lane, acc[i], pc.f1, pc.f2, dadd);
        stg_sym(Out, off, TS::tr(i), TS::tc(i), lane, o);
    }
}

__global__ __launch_bounds__(1024,1)
void poly_fused(const float* __restrict__ Xp, float* __restrict__ Out,
                const float* __restrict__ lns, PolyCoefs pc)
{
    __shared__ __align__(16) unsigned short pool[4*NM*PB];
    unsigned short* Xh = pool;
    unsigned short* Xl = pool + NM*PB;
    unsigned short* Ph = pool + 2*NM*PB;
    unsigned short* Pl = pool + 3*NM*PB;

    const int t = threadIdx.x;
    const long long b = blockIdx.x;
    const long long off = b << 14;
    for (int v = 0; v < 4; ++v) {
        int f = t + v*1024;
        int row = f >> 5, c4 = (f & 31) << 2;
        float4 x = ((const float4*)(Xp + off))[f];
        float4 p;
        p.x = pc.a*x.x + ((c4+0)==row ? pc.bd : 0.f);
        p.y = pc.a*x.y + ((c4+1)==row ? pc.bd : 0.f);
        p.z = pc.a*x.z + ((c4+2)==row ? pc.bd : 0.f);
        p.w = pc.a*x.w + ((c4+3)==row ? pc.bd : 0.f);
        ushort4 h, l;
        splitbf(x.x, h.x, l.x); splitbf(x.y, h.y, l.y);
        splitbf(x.z, h.z, l.z); splitbf(x.w, h.w, l.w);
        *(ushort4*)&Xh[row*PB + c4] = h;
        *(ushort4*)&Xl[row*PB + c4] = l;
        splitbf(p.x, h.x, l.x); splitbf(p.y, h.y, l.y);
        splitbf(p.z, h.z, l.z); splitbf(p.w, h.w, l.w);
        *(ushort4*)&Ph[row*PB + c4] = h;
        *(ushort4*)&Pl[row*PB + c4] = l;
    }
    __syncthreads();

    const float lnsb = lns[b];
    const int lane = t & 63;
    const int w = t >> 6;
    switch (w) {
        case 0:  poly_fused_body16<0>(Xh,Xl,Ph,Pl,Out,off,lane,pc,lnsb); break;
        case 1:  poly_fused_body16<1>(Xh,Xl,Ph,Pl,Out,off,lane,pc,lnsb); break;
        case 2:  poly_fused_body16<2>(Xh,Xl,Ph,Pl,Out,off,lane,pc,lnsb); break;
        case 3:  poly_fused_body16<3>(Xh,Xl,Ph,Pl,Out,off,lane,pc,lnsb); break;
        case 4:  poly_fused_body16<4>(Xh,Xl,Ph,Pl,Out,off,lane,pc,lnsb); break;
        case 5:  poly_fused_body16<5>(Xh,Xl,Ph,Pl,Out,off,lane,pc,lnsb); break;
        case 6:  poly_fused_body16<6>(Xh,Xl,Ph,Pl,Out,off,lane,pc,lnsb); break;
        case 7:  poly_fused_body16<7>(Xh,Xl,Ph,Pl,Out,off,lane,pc,lnsb); break;
        case 8:  poly_fused_body16<8>(Xh,Xl,Ph,Pl,Out,off,lane,pc,lnsb); break;
        case 9:  poly_fused_body16<9>(Xh,Xl,Ph,Pl,Out,off,lane,pc,lnsb); break;
        case 10: poly_fused_body16<10>(Xh,Xl,Ph,Pl,Out,off,lane,pc,lnsb); break;
        case 11: poly_fused_body16<11>(Xh,Xl,Ph,Pl,Out,off,lane,pc,lnsb); break;
        case 12: poly_fused_body16<12>(Xh,Xl,Ph,Pl,Out,off,lane,pc,lnsb); break;
        case 13: poly_fused_body16<13>(Xh,Xl,Ph,Pl,Out,off,lane,pc,lnsb); break;
        case 14: poly_fused_body16<14>(Xh,Xl,Ph,Pl,Out,off,lane,pc,lnsb); break;
        default: poly_fused_body16<15>(Xh,Xl,Ph,Pl,Out,off,lane,pc,lnsb); break;
    }
}

// ============================================================================
// Fallback (ws too small): round-1 parallel Jacobi
// ============================================================================
#define LDA  129
#define NT   512
#define MAX_SWEEPS 14

__global__ __launch_bounds__(NT, 1)
void logeig_jacobi(const float* __restrict__ in, float* __restrict__ out)
{
    __shared__ float A[NM][LDA];
    __shared__ float V[NM][LDA];
    __shared__ float rc[64], rs[64];
    __shared__ float logd[NM];
    __shared__ float roff[NT/64], rdia[NT/64];
    __shared__ int   s_done;

    const int t = threadIdx.x;
    const long long b = blockIdx.x;
    const float* __restrict__ Ain  = in  + (b << 14);
    float* __restrict__       Aout = out + (b << 14);

    for (int k = 0; k < (NM*NM)/NT; ++k) {
        int idx = t + k*NT;
        int i = idx >> 7, j = idx & 127;
        A[i][j] = Ain[idx];
        V[i][j] = (i == j) ? 1.0f : 0.0f;
    }
    __syncthreads();

    for (int sweep = 0; sweep < MAX_SWEEPS; ++sweep) {
        for (int r = 0; r < NM-1; ++r) {
            if (t < 64) {
                int m = t, p, q;
                if (m == 0) { p = NM-1; q = r; }
                else {
                    p = r + m;            if (p >= NM-1) p -= (NM-1);
                    q = r - m + (NM-1);   if (q >= NM-1) q -= (NM-1);
                }
                float app = A[p][p], aqq = A[q][q], apq = A[p][q];
                float c = 1.0f, s = 0.0f;
                if (fabsf(apq) > 1e-12f*(fabsf(app)+fabsf(aqq)) + 1e-32f) {
                    float tau = (aqq - app) * 0.5f / apq;
                    float tt  = 1.0f / (fabsf(tau) + sqrtf(fmaf(tau,tau,1.0f)));
                    tt = (tau < 0.0f) ? -tt : tt;
                    c = rsqrtf(fmaf(tt,tt,1.0f));
                    s = tt * c;
                }
                rc[m] = c; rs[m] = s;
            }
            __syncthreads();
            for (int k = 0; k < (2*64*NM)/NT; ++k) {
                int task = t + k*NT;
                int i   = task & 127;
                int m   = (task >> 7) & 63;
                int isV = task >> 13;
                int p, q;
                if (m == 0) { p = NM-1; q = r; }
                else {
                    p = r + m;            if (p >= NM-1) p -= (NM-1);
                    q = r - m + (NM-1);   if (q >= NM-1) q -= (NM-1);
                }
                float c = rc[m], s = rs[m];
                if (isV == 0) {
                    float x = A[i][p], y = A[i][q];
                    A[i][p] = c*x - s*y;
                    A[i][q] = s*x + c*y;
                } else {
                    float x = V[i][p], y = V[i][q];
                    V[i][p] = c*x - s*y;
                    V[i][q] = s*x + c*y;
                }
            }
            __syncthreads();
            for (int k = 0; k < (64*NM)/NT; ++k) {
                int task = t + k*NT;
                int j = task & 127;
                int m = task >> 7;
                int p, q;
                if (m == 0) { p = NM-1; q = r; }
                else {
                    p = r + m;            if (p >= NM-1) p -= (NM-1);
                    q = r - m + (NM-1);   if (q >= NM-1) q -= (NM-1);
                }
                float c = rc[m], s = rs[m];
                float x = A[p][j], y = A[q][j];
                A[p][j] = c*x - s*y;
                A[q][j] = s*x + c*y;
            }
            __syncthreads();
        }
        float off2 = 0.0f, dia2 = 0.0f;
        for (int k = 0; k < (NM*NM)/NT; ++k) {
            int idx = t + k*NT;
            int i = idx >> 7, j = idx & 127;
            float v = A[i][j];
            if (i == j) dia2 += v*v; else off2 += v*v;
        }
        #pragma unroll
        for (int o = 32; o > 0; o >>= 1) {
            off2 += __shfl_down(off2, o, 64);
            dia2 += __shfl_down(dia2, o, 64);
        }
        if ((t & 63) == 0) { roff[t >> 6] = off2; rdia[t >> 6] = dia2; }
        __syncthreads();
        if (t == 0) {
            float o2 = 0.0f, d2 = 0.0f;
            for (int w = 0; w < NT/64; ++w) { o2 += roff[w]; d2 += rdia[w]; }
            s_done = (o2 <= 1e-13f * d2) ? 1 : 0;
        }
        __syncthreads();
        if (s_done) break;
    }

    if (t < NM) logd[t] = logf(fmaxf(A[t][t], 1e-12f));
    __syncthreads();
    for (int kk = 0; kk < (NM*NM)/NT; ++kk) {
        int idx = t + kk*NT;
        int i = idx >> 7, k = idx & 127;
        A[i][k] = V[i][k] * logd[k];
    }
    __syncthreads();
    {
        int i  = t >> 2;
        int jb = t & 3;
        float acc[32];
        #pragma unroll
        for (int jj = 0; jj < 32; ++jj) acc[jj] = 0.0f;
        for (int kk = 0; kk < NM; ++kk) {
            int k = (kk + jb) & 127;
            float w = A[i][k];
            #pragma unroll
            for (int jj = 0; jj < 32; ++jj)
                acc[jj] = fmaf(w, V[jb*32 + jj][k], acc[jj]);
        }
        #pragma unroll
        for (int jj = 0; jj < 32; ++jj)
            Aout[i*NM + jb*32 + jj] = acc[jj];
    }
}

// ============================================================================
// Host
// ============================================================================
static void cheb_log_power(double lo, double up, int deg, double* p)
{
    const int NC = deg + 1;
    const int MN = 64;
    double mid = 0.5*(lo+up), hw = 0.5*(up-lo);
    double cc[32];
    for (int j = 0; j < NC; ++j) {
        double s = 0.0;
        for (int m = 0; m < MN; ++m) {
            double th = M_PI*(m+0.5)/MN;
            s += log(mid + hw*cos(th)) * cos(j*th);
        }
        cc[j] = 2.0*s/MN;
    }
    double Tp[32] = {0}, Tc[32] = {0}, Tn[32];
    for (int j = 0; j < NC; ++j) p[j] = 0.0;
    Tp[0] = 1.0;  p[0] += 0.5*cc[0];
    Tc[1] = 1.0;  p[1] += cc[1];
    for (int k = 2; k <= deg; ++k) {
        for (int j = 0; j < NC; ++j) Tn[j] = -Tp[j];
        for (int j = 1; j < NC; ++j) Tn[j] += 2.0*Tc[j-1];
        for (int j = 0; j < NC; ++j) { p[j] += cc[k]*Tn[j]; Tp[j] = Tc[j]; Tc[j] = Tn[j]; }
    }
}

extern "C" void kernel_launch(void* const* d_in, const int* in_sizes, int n_in,
                              void* d_out, int out_size, void* d_ws, size_t ws_size,
                              hipStream_t stream) {
    const float* in = (const float*)d_in[0];
    float* out = (float*)d_out;
    const int batch = in_sizes[0] >> 14;                 // 4096
    const size_t matBytes = (size_t)batch * NM * NM * 4; // 256 MB
    const size_t need = matBytes + (size_t)batch * 4;

    if (ws_size < need) {   // fallback
        logeig_jacobi<<<batch, NT, 0, stream>>>(in, out);
        return;
    }

    float* Mbuf = (float*)d_ws;
    float* lns  = (float*)((char*)d_ws + matBytes);

    // --- scaling: s0 = gersh(A); tighten via sqrt(gersh((A/s0)^2)) ---
    scale_kernel<<<batch, 256, 0, stream>>>(in, out, Mbuf, lns);      // out = X0
    gram_tri<<<batch, 512, 0, stream>>>(out, Mbuf);                   // Mbuf = X0^2
    rescale_kernel<<<batch, 256, 0, stream>>>(Mbuf, out, Mbuf, lns);  // out=Mbuf=X

    // --- L1 iters 0-3: fused f32 lower-triangle (precision-critical) ---
    ns_tri4<<<batch, 512, 0, stream>>>(Mbuf, out, Mbuf, out, 4);

    // --- fused MFMA NS segments (schedule {1.5 x(n-3), 1.116, 1, 1}) ---
    ns_fused<<<batch, 1024, 0, stream>>>(Mbuf, out, out, 8);  // L1 iters 4..11
    ns_fused<<<batch, 1024, 0, stream>>>(out,  out, out, 8);  // L2 (M0=Y0)
    ns_fused<<<batch, 1024, 0, stream>>>(out,  out, out, 6);  // L3 (M0=Y0)

    // --- fused Chebyshev-minimax log, deg 8 on [0.25, 1.002] ---
    const double lo = 0.25, up = 1.002;
    const double mid = 0.5*(lo+up), hw = 0.5*(up-lo);
    double p[9];
    cheb_log_power(lo, up, 8, p);

    PolyCoefs pc;
    pc.a  = (float)(p[8]/hw);
    pc.bd = (float)(p[7] - p[8]*mid/hw);
    pc.s1 = (float)(1.0/hw);
    pc.s2 = (float)(mid/hw);
    pc.c0 = (float)p[6]; pc.c1 = (float)p[5]; pc.c2 = (float)p[4];
    pc.c3 = (float)p[3]; pc.c4 = (float)p[2]; pc.c5 = (float)p[1];
    pc.f1 = (float)(8.0/hw);
    pc.f2 = (float)(8.0*mid/hw);
    pc.f3 = (float)(8.0*p[0]);

    poly_fused<<<batch, 1024, 0, stream>>>(out, out, lns, pc);
}

// Round 12
// 7206.889 us; speedup vs baseline: 16.6833x; 1.0001x over previous
//
#include <hip/hip_runtime.h>
#include <hip/hip_bf16.h>
#include <math.h>

#define NM   128
#define PAD  132   // f32 LDS pitch
#define PB   136   // u16 LDS pitch for MFMA bf16 splits
#define PBI  144   // i8 plane pitch (bytes); 144%16==0 for b128 frags, 36 dw/row -> 2-way banks

typedef __attribute__((ext_vector_type(8))) short bf16x8;
typedef __attribute__((ext_vector_type(4))) float f32x4;
typedef __attribute__((ext_vector_type(4))) int   i32x4;

#if defined(__has_builtin)
#if __has_builtin(__builtin_amdgcn_mfma_i32_16x16x64_i8)
#define HAVE_I8MFMA 1
#endif
#endif

// ============================================================================
// log(A) = ln(s) I + 8 * cheb_log( NS_sqrt^3( A/s ) ).
// Round-12: the 4 precision-critical early NS iterations move from f32-VALU
// (LDS-bound, 3.1ms) to EXACT 24-bit fixed-point i8-MFMA: quantize x->round
// (x*2^21), split into 3 signed-i8 planes, 8 MFMA products in 4 weight groups
// with exact i32 accumulation (no rounding; only quantization 2^-22 abs +
// dropped ll term <=4.7e-7 abs). Guarded by __has_builtin -> ns_tri4 fallback.
// Invariants: every matrix written is EXACTLY symmetric (mirror-write +
// symdiag-on-full-output); passthroughs read LDS-resident data only.
// ============================================================================

// ---------------------------------------------------------------- f32 kernels
__global__ __launch_bounds__(256,1)
void scale_kernel(const float* __restrict__ A, float* __restrict__ outY,
                  float* __restrict__ outM, float* __restrict__ lns)
{
    __shared__ __align__(16) float L[NM][PAD];
    __shared__ float rs[NM];
    __shared__ float s_inv;
    const int t = threadIdx.x;
    const long long b = blockIdx.x;
    const long long off = b << 14;
    for (int v = 0; v < 16; ++v) {
        int f = t + v*256;
        int row = f >> 5, c4 = (f & 31) << 2;
        *(float4*)&L[row][c4] = ((const float4*)(A + off))[f];
    }
    __syncthreads();
    if (t < NM) {
        float s = 0.f;
        for (int j = 0; j < NM; ++j) s += fabsf(L[t][j]);
        rs[t] = s;
    }
    __syncthreads();
    if (t < 64) {
        float m = fmaxf(rs[t], rs[t+64]);
        #pragma unroll
        for (int o = 32; o > 0; o >>= 1) m = fmaxf(m, __shfl_down(m, o, 64));
        if (t == 0) { s_inv = 1.0f/m; lns[b] = logf(m); }
    }
    __syncthreads();
    const float inv = s_inv;
    for (int v = 0; v < 16; ++v) {
        int f = t + v*256;
        int row = f >> 5, c4 = (f & 31) << 2;
        float4 x = *(const float4*)&L[row][c4];
        x.x *= inv; x.y *= inv; x.z *= inv; x.w *= inv;
        ((float4*)(outY + off))[f] = x;
        ((float4*)(outM + off))[f] = x;
    }
}

__global__ __launch_bounds__(256,1)
void rescale_kernel(const float* __restrict__ Sq, float* __restrict__ X,
                    float* __restrict__ M, float* __restrict__ lns)
{
    __shared__ __align__(16) float L[NM][PAD];
    __shared__ float rs[NM];
    __shared__ float s_g;
    const int t = threadIdx.x;
    const long long b = blockIdx.x;
    const long long off = b << 14;
    for (int v = 0; v < 16; ++v) {
        int f = t + v*256;
        int row = f >> 5, c4 = (f & 31) << 2;
        *(float4*)&L[row][c4] = ((const float4*)(Sq + off))[f];
    }
    __syncthreads();
    if (t < NM) {
        float s = 0.f;
        for (int j = 0; j < NM; ++j) s += fabsf(L[t][j]);
        rs[t] = s;
    }
    __syncthreads();
    if (t < 64) {
        float m = fmaxf(rs[t], rs[t+64]);
        #pragma unroll
        for (int o = 32; o > 0; o >>= 1) m = fmaxf(m, __shfl_down(m, o, 64));
        if (t == 0) { s_g = 1.0f/sqrtf(m); lns[b] = lns[b] + 0.5f*logf(m); }
    }
    __syncthreads();
    const float g = s_g;
    for (int v = 0; v < 16; ++v) {
        int f = t + v*256;
        float4 x = ((const float4*)(X + off))[f];
        x.x *= g; x.y *= g; x.z *= g; x.w *= g;
        ((float4*)(X + off))[f] = x;
        ((float4*)(M + off))[f] = x;
    }
}

// triangular index decode: u -> (bi,bj), bj<=bi
__device__ __forceinline__ void tridec(int u, int &bi, int &bj) {
    int b = (int)(0.5f*(sqrtf(8.0f*(float)u + 1.0f) - 1.0f));
    while ((b+1)*(b+2)/2 <= u) ++b;
    while (b*(b+1)/2 > u) --b;
    bi = b; bj = u - b*(b+1)/2;
}

// Gram: Out = X^T X (= X^2 for symmetric X), lower-triangle + mirror
__global__ __launch_bounds__(512,1)
void gram_tri(const float* __restrict__ X, float* __restrict__ Out)
{
    __shared__ __align__(16) float LX[NM][PAD];
    const int t = threadIdx.x;
    const long long off = (long long)blockIdx.x << 14;
    for (int v = 0; v < 8; ++v) {
        int f = t + v*512;
        int row = f >> 5, c4 = (f & 31) << 2;
        *(float4*)&LX[row][c4] = ((const float4*)(X + off))[f];
    }
    __syncthreads();
    for (int u = t; u < 528; u += 512) {
        int bi, bj; tridec(u, bi, bj);
        const int r4 = bi << 2, c4 = bj << 2;
        float acc[4][4];
        #pragma unroll
        for (int i = 0; i < 4; ++i)
            #pragma unroll
            for (int j = 0; j < 4; ++j) acc[i][j] = 0.f;
        #pragma unroll 4
        for (int k = 0; k < NM; ++k) {
            float av[4], bv[4];
            *(float4*)av = *(const float4*)&LX[k][r4];
            *(float4*)bv = *(const float4*)&LX[k][c4];
            #pragma unroll
            for (int i = 0; i < 4; ++i)
                #pragma unroll
                for (int j = 0; j < 4; ++j) acc[i][j] = fmaf(av[i], bv[j], acc[i][j]);
        }
        #pragma unroll
        for (int i = 0; i < 4; ++i)
            *(float4*)&Out[off + (long long)(r4+i)*NM + c4] =
                make_float4(acc[i][0], acc[i][1], acc[i][2], acc[i][3]);
        if (bi != bj) {
            #pragma unroll
            for (int j = 0; j < 4; ++j)
                *(float4*)&Out[off + (long long)(c4+j)*NM + r4] =
                    make_float4(acc[0][j], acc[1][j], acc[2][j], acc[3][j]);
        }
    }
}

// ---- fused 4-iteration f32 NS (fallback when i8 MFMA unavailable) ----
__device__ __forceinline__ void tri_p1_reg(const float (*LM)[PAD], const float (*LY)[PAD],
                                           int bi, int bj, float a15, float a05,
                                           float o[4][4])
{
    const int r4 = bi << 2, c4 = bj << 2;
    float acc[4][4];
    #pragma unroll
    for (int i = 0; i < 4; ++i)
        #pragma unroll
        for (int j = 0; j < 4; ++j) acc[i][j] = 0.f;
    #pragma unroll 4
    for (int k = 0; k < NM; ++k) {
        float av[4], bv[4];
        *(float4*)av = *(const float4*)&LY[k][r4];
        *(float4*)bv = *(const float4*)&LM[k][c4];
        #pragma unroll
        for (int i = 0; i < 4; ++i)
            #pragma unroll
            for (int j = 0; j < 4; ++j) acc[i][j] = fmaf(av[i], bv[j], acc[i][j]);
    }
    #pragma unroll
    for (int i = 0; i < 4; ++i)
        #pragma unroll
        for (int j = 0; j < 4; ++j)
            o[i][j] = a15*LY[r4+i][c4+j] - a05*acc[i][j];
    if (bi == bj) {
        #pragma unroll
        for (int i = 0; i < 4; ++i)
            #pragma unroll
            for (int j = 0; j < 4; ++j)
                if (j > i) { float s = 0.5f*(o[i][j] + o[j][i]); o[i][j] = s; o[j][i] = s; }
    }
}

__device__ __forceinline__ void tri_p2_lds(const float (*LM)[PAD], float (*LY)[PAD],
                                           int bi, int bj)
{
    const int r4 = bi << 2, c4 = bj << 2;
    float acc[4][4];
    #pragma unroll
    for (int i = 0; i < 4; ++i)
        #pragma unroll
        for (int j = 0; j < 4; ++j) acc[i][j] = 0.f;
    #pragma unroll 4
    for (int k = 0; k < NM; ++k) {
        float av[4], bv[4];
        *(float4*)av = *(const float4*)&LM[k][r4];
        *(float4*)bv = *(const float4*)&LM[k][c4];
        #pragma unroll
        for (int i = 0; i < 4; ++i)
            #pragma unroll
            for (int j = 0; j < 4; ++j) acc[i][j] = fmaf(av[i], bv[j], acc[i][j]);
    }
    #pragma unroll
    for (int i = 0; i < 4; ++i)
        *(float4*)&LY[r4+i][c4] = make_float4(acc[i][0], acc[i][1], acc[i][2], acc[i][3]);
    if (bi != bj) {
        #pragma unroll
        for (int j = 0; j < 4; ++j)
            *(float4*)&LY[c4+j][r4] = make_float4(acc[0][j], acc[1][j], acc[2][j], acc[3][j]);
    }
}

__device__ __forceinline__ void tri_p3_reg(const float (*LM)[PAD], const float (*LY)[PAD],
                                           int bi, int bj, float q, float o[4][4])
{
    const int r4 = bi << 2, c4 = bj << 2;
    float acc[4][4];
    #pragma unroll
    for (int i = 0; i < 4; ++i)
        #pragma unroll
        for (int j = 0; j < 4; ++j) acc[i][j] = 0.f;
    #pragma unroll 4
    for (int k = 0; k < NM; ++k) {
        float av[4], bv[4];
        *(float4*)av = *(const float4*)&LM[k][r4];
        *(float4*)bv = *(const float4*)&LY[k][c4];
        #pragma unroll
        for (int i = 0; i < 4; ++i)
            #pragma unroll
            for (int j = 0; j < 4; ++j) acc[i][j] = fmaf(av[i], bv[j], acc[i][j]);
    }
    #pragma unroll
    for (int i = 0; i < 4; ++i)
        #pragma unroll
        for (int j = 0; j < 4; ++j)
            o[i][j] = q*(9.f*LM[r4+i][c4+j] - 6.f*LY[r4+i][c4+j] + acc[i][j]);
    if (bi == bj) {
        #pragma unroll
        for (int i = 0; i < 4; ++i)
            #pragma unroll
            for (int j = 0; j < 4; ++j)
                if (j > i) { float s = 0.5f*(o[i][j] + o[j][i]); o[i][j] = s; o[j][i] = s; }
    }
}

__device__ __forceinline__ void tri_wb(float (*L)[PAD], int bi, int bj, const float o[4][4])
{
    const int r4 = bi << 2, c4 = bj << 2;
    #pragma unroll
    for (int i = 0; i < 4; ++i)
        *(float4*)&L[r4+i][c4] = make_float4(o[i][0], o[i][1], o[i][2], o[i][3]);
    if (bi != bj) {
        #pragma unroll
        for (int j = 0; j < 4; ++j)
            *(float4*)&L[c4+j][r4] = make_float4(o[0][j], o[1][j], o[2][j], o[3][j]);
    }
}

__global__ __launch_bounds__(512,1)
void ns_tri4(const float* __restrict__ Mp, const float* __restrict__ Yp,
             float* __restrict__ outM, float* __restrict__ outY, int niter)
{
    __shared__ __align__(16) float LM[NM][PAD];
    __shared__ __align__(16) float LY[NM][PAD];
    const int t = threadIdx.x;
    const long long off = (long long)blockIdx.x << 14;
    for (int v = 0; v < 8; ++v) {
        int f = t + v*512;
        int row = f >> 5, c4 = (f & 31) << 2;
        *(float4*)&LM[row][c4] = ((const float4*)(Mp + off))[f];
        *(float4*)&LY[row][c4] = ((const float4*)(Yp + off))[f];
    }
    __syncthreads();

    int b0i, b0j, b1i = -1, b1j = 0;
    tridec(t, b0i, b0j);
    if (t < 16) tridec(512 + t, b1i, b1j);

    const float cc = 1.5f, dd = sqrtf(1.5f);
    const float a15 = 1.5f*dd, a05 = 0.5f*dd, q = 0.25f*cc;
    float y0[4][4], y1[4][4], m0[4][4], m1[4][4];

    for (int it = 0; it < niter; ++it) {
        tri_p1_reg(LM, LY, b0i, b0j, a15, a05, y0);
        if (b1i >= 0) tri_p1_reg(LM, LY, b1i, b1j, a15, a05, y1);
        __syncthreads();
        tri_p2_lds(LM, LY, b0i, b0j);
        if (b1i >= 0) tri_p2_lds(LM, LY, b1i, b1j);
        __syncthreads();
        tri_p3_reg(LM, LY, b0i, b0j, q, m0);
        if (b1i >= 0) tri_p3_reg(LM, LY, b1i, b1j, q, m1);
        __syncthreads();
        tri_wb(LM, b0i, b0j, m0);
        tri_wb(LY, b0i, b0j, y0);
        if (b1i >= 0) { tri_wb(LM, b1i, b1j, m1); tri_wb(LY, b1i, b1j, y1); }
        __syncthreads();
    }

    for (int v = 0; v < 8; ++v) {
        int f = t + v*512;
        int row = f >> 5, c4 = (f & 31) << 2;
        ((float4*)(outM + off))[f] = *(const float4*)&LM[row][c4];
        ((float4*)(outY + off))[f] = *(const float4*)&LY[row][c4];
    }
}

// ---------------------------------------------------------------- MFMA common
__device__ __forceinline__ f32x4 mfma16(bf16x8 a, bf16x8 b, f32x4 c) {
    return __builtin_amdgcn_mfma_f32_16x16x32_bf16(a, b, c, 0, 0, 0);
}

__device__ __forceinline__ void splitbf(float x, unsigned short &h, unsigned short &l) {
    __hip_bfloat16 bh = __float2bfloat16(x);
    float r = x - __bfloat162float(bh);
    __hip_bfloat16 bl = __float2bfloat16(r);
    h = *(unsigned short*)&bh;
    l = *(unsigned short*)&bl;
}

__device__ __forceinline__ float ldsM(const unsigned short* __restrict__ H,
                                      const unsigned short* __restrict__ L,
                                      int row, int col) {
    unsigned int uh = ((unsigned int)H[row*PB + col]) << 16;
    unsigned int ul = ((unsigned int)L[row*PB + col]) << 16;
    return __uint_as_float(uh) + __uint_as_float(ul);
}

__device__ __forceinline__ bf16x8 ldfrag(const unsigned short* __restrict__ a,
                                         int rb, int lane, int kc) {
    int row = rb*16 + (lane & 15);
    int col = kc*32 + ((lane >> 4) & 3)*8;
    return *(const bf16x8*)(a + row*PB + col);
}

// Exact symmetrization of a DIAGONAL 16x16 tile (C/D layout: col=lane&15,
// row=(lane>>4)*4+reg; transpose of (row rb+r, col) at lane'=4g+r+16(j>>2)).
__device__ __forceinline__ f32x4 symdiag(f32x4 a, int lane) {
    const int g = (lane >> 4) & 3, j = lane & 15;
    const int rp = j & 3;
    f32x4 out;
    #pragma unroll
    for (int r = 0; r < 4; ++r) {
        int lp = 4*g + r + ((j >> 2) << 4);
        float t0 = __shfl(a[0], lp, 64);
        float t1 = __shfl(a[1], lp, 64);
        float t2 = __shfl(a[2], lp, 64);
        float t3 = __shfl(a[3], lp, 64);
        float tv = (rp == 0) ? t0 : (rp == 1) ? t1 : (rp == 2) ? t2 : t3;
        out[r] = 0.5f*(a[r] + tv);
    }
    return out;
}

// write symmetric tile back to LDS as hi/lo splits (+ mirror)
__device__ __forceinline__ void st_split(unsigned short* __restrict__ H,
                                         unsigned short* __restrict__ L,
                                         int Tr, int Tc, int lane, f32x4 o) {
    int col = Tc*16 + (lane & 15);
    int rb  = Tr*16 + ((lane >> 4) & 3)*4;
    #pragma unroll
    for (int r = 0; r < 4; ++r) {
        unsigned short h, l;
        splitbf(o[r], h, l);
        H[(rb+r)*PB + col] = h;
        L[(rb+r)*PB + col] = l;
        if (Tr != Tc) { H[col*PB + rb + r] = h; L[col*PB + rb + r] = l; }
    }
}

__device__ __forceinline__ void stg_sym(float* __restrict__ out, long long off,
                                        int Tr, int Tc, int lane, f32x4 o) {
    int col = Tc*16 + (lane & 15);
    int rb  = Tr*16 + ((lane >> 4) & 3)*4;
    #pragma unroll
    for (int r = 0; r < 4; ++r)
        out[off + (long long)(rb+r)*NM + col] = o[r];
    if (Tr != Tc)
        *(f32x4*)&out[off + (long long)col*NM + rb] = o;
}

__device__ __forceinline__ f32x4 yepi(const unsigned short* __restrict__ Yh,
                                      const unsigned short* __restrict__ Yl,
                                      int Tr, int Tc, int lane, f32x4 a,
                                      float a15, float a05) {
    int col = Tc*16 + (lane & 15);
    int rb  = Tr*16 + ((lane >> 4) & 3)*4;
    f32x4 o;
    #pragma unroll
    for (int r = 0; r < 4; ++r)
        o[r] = a15*ldsM(Yh, Yl, rb+r, col) - a05*a[r];
    if (Tr == Tc) o = symdiag(o, lane);
    return o;
}

__device__ __forceinline__ f32x4 mepi(const unsigned short* __restrict__ Mh,
                                      const unsigned short* __restrict__ Ml,
                                      const unsigned short* __restrict__ Th,
                                      const unsigned short* __restrict__ Tl,
                                      int Tr, int Tc, int lane, f32x4 a, float q) {
    int col = Tc*16 + (lane & 15);
    int rb  = Tr*16 + ((lane >> 4) & 3)*4;
    f32x4 o;
    #pragma unroll
    for (int r = 0; r < 4; ++r)
        o[r] = q*(9.f*ldsM(Mh, Ml, rb+r, col) - 6.f*ldsM(Th, Tl, rb+r, col) + a[r]);
    if (Tr == Tc) o = symdiag(o, lane);
    return o;
}

__device__ __forceinline__ f32x4 pepi(const unsigned short* __restrict__ Ph,
                                      const unsigned short* __restrict__ Pl,
                                      int Tr, int Tc, int lane, f32x4 a,
                                      float s1, float s2, float dadd) {
    int col = Tc*16 + (lane & 15);
    int rb  = Tr*16 + ((lane >> 4) & 3)*4;
    f32x4 o;
    #pragma unroll
    for (int r = 0; r < 4; ++r)
        o[r] = s1*a[r] - s2*ldsM(Ph, Pl, rb+r, col) + ((rb+r) == col ? dadd : 0.f);
    if (Tr == Tc) o = symdiag(o, lane);
    return o;
}

// ---- 16-wave tile partition ----
template<int W>
struct TS16 {
    static constexpr int P  = W >> 2;
    static constexpr int Q  = W & 3;
    static constexpr int R0 = P;
    static constexpr int R1 = 7 - P;
    static constexpr int N  = (Q == 0) ? 3 : 2;
    static constexpr int g(int i)  { return 4*i + Q; }
    static constexpr int tr(int i) { return g(i) <= R0 ? R0 : R1; }
    static constexpr int tc(int i) { return g(i) <= R0 ? g(i) : g(i) - R0 - 1; }
};

template<int W>
__device__ __forceinline__ void tri16_gemm(const unsigned short* __restrict__ Ah,
                                           const unsigned short* __restrict__ Al,
                                           const unsigned short* __restrict__ Bh,
                                           const unsigned short* __restrict__ Bl,
                                           int lane, f32x4* acc) {
    using TS = TS16<W>;
    #pragma unroll
    for (int kc = 0; kc < 4; ++kc) {
        bf16x8 a0h = ldfrag(Ah, TS::R0, lane, kc), a0l = ldfrag(Al, TS::R0, lane, kc);
        bf16x8 a1h = ldfrag(Ah, TS::R1, lane, kc), a1l = ldfrag(Al, TS::R1, lane, kc);
        #pragma unroll
        for (int i = 0; i < TS::N; ++i) {
            const int r = TS::tr(i), c = TS::tc(i);
            bf16x8 bh = ldfrag(Bh, c, lane, kc), bl = ldfrag(Bl, c, lane, kc);
            bf16x8 ah = (r == TS::R0) ? a0h : a1h;
            bf16x8 al = (r == TS::R0) ? a0l : a1l;
            acc[i] = mfma16(ah, bh, acc[i]);
            acc[i] = mfma16(ah, bl, acc[i]);
            acc[i] = mfma16(al, bh, acc[i]);
        }
    }
}

// ---------------------------------------------------------------- fused NS
template<int W>
__device__ __forceinline__ void ns_fused_body16(
    unsigned short* Mh, unsigned short* Ml,
    unsigned short* Yh, unsigned short* Yl,
    float* outY, long long off, int lane, int niter)
{
    using TS = TS16<W>;
    constexpr int NT_ = TS::N;
    const f32x4 z = {0.f, 0.f, 0.f, 0.f};
    f32x4 acc[NT_], yv[NT_];

    for (int j = 0; j < niter; ++j) {
        const int last = (j == niter-1);
        const float cc = (j < niter-3) ? 1.5f : ((j == niter-3) ? 1.116f : 1.0f);
        const float dd = sqrtf(cc);
        const float a15 = 1.5f*dd, a05 = 0.5f*dd;

        #pragma unroll
        for (int i = 0; i < NT_; ++i) acc[i] = z;
        tri16_gemm<W>(Yh, Yl, Mh, Ml, lane, acc);
        #pragma unroll
        for (int i = 0; i < NT_; ++i)
            yv[i] = yepi(Yh, Yl, TS::tr(i), TS::tc(i), lane, acc[i], a15, a05);

        if (last) {
            #pragma unroll
            for (int i = 0; i < NT_; ++i)
                stg_sym(outY, off, TS::tr(i), TS::tc(i), lane, yv[i]);
            return;
        }
        __syncthreads();

        #pragma unroll
        for (int i = 0; i < NT_; ++i) acc[i] = z;
        tri16_gemm<W>(Mh, Ml, Mh, Ml, lane, acc);
        #pragma unroll
        for (int i = 0; i < NT_; ++i)
            st_split(Yh, Yl, TS::tr(i), TS::tc(i), lane, acc[i]);
        __syncthreads();

        #pragma unroll
        for (int i = 0; i < NT_; ++i) acc[i] = z;
        tri16_gemm<W>(Mh, Ml, Yh, Yl, lane, acc);
        const float q = 0.25f*cc;
        #pragma unroll
        for (int i = 0; i < NT_; ++i)
            acc[i] = mepi(Mh, Ml, Yh, Yl, TS::tr(i), TS::tc(i), lane, acc[i], q);
        __syncthreads();

        #pragma unroll
        for (int i = 0; i < NT_; ++i)
            st_split(Mh, Ml, TS::tr(i), TS::tc(i), lane, acc[i]);
        #pragma unroll
        for (int i = 0; i < NT_; ++i)
            st_split(Yh, Yl, TS::tr(i), TS::tc(i), lane, yv[i]);
        __syncthreads();
    }
}

__global__ __launch_bounds__(1024,1)
void ns_fused(const float* __restrict__ Mp, const float* __restrict__ Yp,
              float* __restrict__ outY, int niter)
{
    __shared__ __align__(16) unsigned short pool[4*NM*PB];
    unsigned short* Mh = pool;
    unsigned short* Ml = pool + NM*PB;
    unsigned short* Yh = pool + 2*NM*PB;
    unsigned short* Yl = pool + 3*NM*PB;

    const int t = threadIdx.x;
    const long long off = (long long)blockIdx.x << 14;
    for (int v = 0; v < 4; ++v) {
        int f = t + v*1024;
        int row = f >> 5, c4 = (f & 31) << 2;
        float4 x = ((const float4*)(Mp + off))[f];
        ushort4 h, l;
        splitbf(x.x, h.x, l.x); splitbf(x.y, h.y, l.y);
        splitbf(x.z, h.z, l.z); splitbf(x.w, h.w, l.w);
        *(ushort4*)&Mh[row*PB + c4] = h;
        *(ushort4*)&Ml[row*PB + c4] = l;
        x = ((const float4*)(Yp + off))[f];
        splitbf(x.x, h.x, l.x); splitbf(x.y, h.y, l.y);
        splitbf(x.z, h.z, l.z); splitbf(x.w, h.w, l.w);
        *(ushort4*)&Yh[row*PB + c4] = h;
        *(ushort4*)&Yl[row*PB + c4] = l;
    }
    __syncthreads();

    const int lane = t & 63;
    const int w = t >> 6;
    switch (w) {
        case 0:  ns_fused_body16<0>(Mh,Ml,Yh,Yl,outY,off,lane,niter); break;
        case 1:  ns_fused_body16<1>(Mh,Ml,Yh,Yl,outY,off,lane,niter); break;
        case 2:  ns_fused_body16<2>(Mh,Ml,Yh,Yl,outY,off,lane,niter); break;
        case 3:  ns_fused_body16<3>(Mh,Ml,Yh,Yl,outY,off,lane,niter); break;
        case 4:  ns_fused_body16<4>(Mh,Ml,Yh,Yl,outY,off,lane,niter); break;
        case 5:  ns_fused_body16<5>(Mh,Ml,Yh,Yl,outY,off,lane,niter); break;
        case 6:  ns_fused_body16<6>(Mh,Ml,Yh,Yl,outY,off,lane,niter); break;
        case 7:  ns_fused_body16<7>(Mh,Ml,Yh,Yl,outY,off,lane,niter); break;
        case 8:  ns_fused_body16<8>(Mh,Ml,Yh,Yl,outY,off,lane,niter); break;
        case 9:  ns_fused_body16<9>(Mh,Ml,Yh,Yl,outY,off,lane,niter); break;
        case 10: ns_fused_body16<10>(Mh,Ml,Yh,Yl,outY,off,lane,niter); break;
        case 11: ns_fused_body16<11>(Mh,Ml,Yh,Yl,outY,off,lane,niter); break;
        case 12: ns_fused_body16<12>(Mh,Ml,Yh,Yl,outY,off,lane,niter); break;
        case 13: ns_fused_body16<13>(Mh,Ml,Yh,Yl,outY,off,lane,niter); break;
        case 14: ns_fused_body16<14>(Mh,Ml,Yh,Yl,outY,off,lane,niter); break;
        default: ns_fused_body16<15>(Mh,Ml,Yh,Yl,outY,off,lane,niter); break;
    }
}

// ---------------------------------------------------------------- fused poly
struct PolyCoefs {
    float a, bd;
    float s1, s2;
    float c0,c1,c2,c3,c4,c5;
    float f1, f2, f3;
};

template<int W>
__device__ __forceinline__ void poly_fused_body16(
    const unsigned short* Xh, const unsigned short* Xl,
    unsigned short* Ph, unsigned short* Pl,
    float* Out, long long off, int lane, PolyCoefs pc, float lnsb)
{
    using TS = TS16<W>;
    constexpr int NT_ = TS::N;
    const f32x4 z = {0.f, 0.f, 0.f, 0.f};
    f32x4 acc[NT_];

    for (int step = 0; step < 6; ++step) {
        #pragma unroll
        for (int i = 0; i < NT_; ++i) acc[i] = z;
        tri16_gemm<W>(Xh, Xl, Ph, Pl, lane, acc);
        float s3v;
        switch (step) {
            case 0: s3v = pc.c0; break;  case 1: s3v = pc.c1; break;
            case 2: s3v = pc.c2; break;  case 3: s3v = pc.c3; break;
            case 4: s3v = pc.c4; break;  default: s3v = pc.c5; break;
        }
        #pragma unroll
        for (int i = 0; i < NT_; ++i)
            acc[i] = pepi(Ph, Pl, TS::tr(i), TS::tc(i), lane, acc[i], pc.s1, pc.s2, s3v);
        __syncthreads();
        #pragma unroll
        for (int i = 0; i < NT_; ++i)
            st_split(Ph, Pl, TS::tr(i), TS::tc(i), lane, acc[i]);
        __syncthreads();
    }
    #pragma unroll
    for (int i = 0; i < NT_; ++i) acc[i] = z;
    tri16_gemm<W>(Xh, Xl, Ph, Pl, lane, acc);
    const float dadd = pc.f3 + lnsb;
    #pragma unroll
    for (int i = 0; i < NT_; ++i) {
        f32x4 o = pepi(Ph, Pl, TS::tr(i), TS::tc(i), lane, acc[i], pc.f1, pc.f2, dadd);
        stg_sym(Out, off, TS::tr(i), TS::tc(i), lane, o);
    }
}

__global__ __launch_bounds__(1024,1)
void poly_fused(const float* __restrict__ Xp, float* __restrict__ Out,
                const float* __restrict__ lns, PolyCoefs pc)
{
    __shared__ __align__(16) unsigned short pool[4*NM*PB];
    unsigned short* Xh = pool;
    unsigned short* Xl = pool + NM*PB;
    unsigned short* Ph = pool + 2*NM*PB;
    unsigned short* Pl = pool + 3*NM*PB;

    const int t = threadIdx.x;
    const long long b = blockIdx.x;
    const long long off = b << 14;
    for (int v = 0; v < 4; ++v) {
        int f = t + v*1024;
        int row = f >> 5, c4 = (f & 31) << 2;
        float4 x = ((const float4*)(Xp + off))[f];
        float4 p;
        p.x = pc.a*x.x + ((c4+0)==row ? pc.bd : 0.f);
        p.y = pc.a*x.y + ((c4+1)==row ? pc.bd : 0.f);
        p.z = pc.a*x.z + ((c4+2)==row ? pc.bd : 0.f);
        p.w = pc.a*x.w + ((c4+3)==row ? pc.bd : 0.f);
        ushort4 h, l;
        splitbf(x.x, h.x, l.x); splitbf(x.y, h.y, l.y);
        splitbf(x.z, h.z, l.z); splitbf(x.w, h.w, l.w);
        *(ushort4*)&Xh[row*PB + c4] = h;
        *(ushort4*)&Xl[row*PB + c4] = l;
        splitbf(p.x, h.x, l.x); splitbf(p.y, h.y, l.y);
        splitbf(p.z, h.z, l.z); splitbf(p.w, h.w, l.w);
        *(ushort4*)&Ph[row*PB + c4] = h;
        *(ushort4*)&Pl[row*PB + c4] = l;
    }
    __syncthreads();

    const float lnsb = lns[b];
    const int lane = t & 63;
    const int w = t >> 6;
    switch (w) {
        case 0:  poly_fused_body16<0>(Xh,Xl,Ph,Pl,Out,off,lane,pc,lnsb); break;
        case 1:  poly_fused_body16<1>(Xh,Xl,Ph,Pl,Out,off,lane,pc,lnsb); break;
        case 2:  poly_fused_body16<2>(Xh,Xl,Ph,Pl,Out,off,lane,pc,lnsb); break;
        case 3:  poly_fused_body16<3>(Xh,Xl,Ph,Pl,Out,off,lane,pc,lnsb); break;
        case 4:  poly_fused_body16<4>(Xh,Xl,Ph,Pl,Out,off,lane,pc,lnsb); break;
        case 5:  poly_fused_body16<5>(Xh,Xl,Ph,Pl,Out,off,lane,pc,lnsb); break;
        case 6:  poly_fused_body16<6>(Xh,Xl,Ph,Pl,Out,off,lane,pc,lnsb); break;
        case 7:  poly_fused_body16<7>(Xh,Xl,Ph,Pl,Out,off,lane,pc,lnsb); break;
        case 8:  poly_fused_body16<8>(Xh,Xl,Ph,Pl,Out,off,lane,pc,lnsb); break;
        case 9:  poly_fused_body16<9>(Xh,Xl,Ph,Pl,Out,off,lane,pc,lnsb); break;
        case 10: poly_fused_body16<10>(Xh,Xl,Ph,Pl,Out,off,lane,pc,lnsb); break;
        case 11: poly_fused_body16<11>(Xh,Xl,Ph,Pl,Out,off,lane,pc,lnsb); break;
        case 12: poly_fused_body16<12>(Xh,Xl,Ph,Pl,Out,off,lane,pc,lnsb); break;
        case 13: poly_fused_body16<13>(Xh,Xl,Ph,Pl,Out,off,lane,pc,lnsb); break;
        case 14: poly_fused_body16<14>(Xh,Xl,Ph,Pl,Out,off,lane,pc,lnsb); break;
        default: poly_fused_body16<15>(Xh,Xl,Ph,Pl,Out,off,lane,pc,lnsb); break;
    }
}

// ============================================================================
// i8-MFMA exact 24-bit fixed-point NS (first 4 iterations)
// ============================================================================
#if HAVE_I8MFMA

__device__ __forceinline__ i32x4 mfma8(i32x4 a, i32x4 b, i32x4 c) {
    return __builtin_amdgcn_mfma_i32_16x16x64_i8(a, b, c, 0, 0, 0);
}

// exact 3-piece i8 split of round(x * 2^21): x = h*2^16 + m*2^8 + l
__device__ __forceinline__ void spliti(float x, int &h, int &m, int &l) {
    int xi = __float2int_rn(x * 2097152.0f);
    l = (int)(signed char)(xi & 255);
    int r1 = (xi - l) >> 8;
    m = (int)(signed char)(r1 & 255);
    h = (r1 - m) >> 8;
}

__device__ __forceinline__ void pack4i(float4 x, unsigned &uh, unsigned &um, unsigned &ul) {
    float v[4] = {x.x, x.y, x.z, x.w};
    uh = um = ul = 0;
    #pragma unroll
    for (int i = 0; i < 4; ++i) {
        int h, m, l;
        spliti(v[i], h, m, l);
        uh |= ((unsigned)(h & 255)) << (8*i);
        um |= ((unsigned)(m & 255)) << (8*i);
        ul |= ((unsigned)(l & 255)) << (8*i);
    }
}

__device__ __forceinline__ float recLDS(const signed char* __restrict__ H,
                                        const signed char* __restrict__ Md,
                                        const signed char* __restrict__ L,
                                        int row, int col) {
    int v = ((int)H[row*PBI + col] << 16) + ((int)Md[row*PBI + col] << 8)
          + (int)L[row*PBI + col];
    return (float)v * 4.76837158203125e-7f;   // 2^-21
}

// recombine 4 weight-grouped i32 accumulators: x*y = g0*2^-10 + g1*2^-18 + g2*2^-26 + g3*2^-34
__device__ __forceinline__ f32x4 rec4(i32x4 g0, i32x4 g1, i32x4 g2, i32x4 g3) {
    f32x4 r;
    #pragma unroll
    for (int i = 0; i < 4; ++i)
        r[i] = (float)g0[i]*9.765625e-4f
             + (float)g1[i]*3.814697265625e-6f
             + (float)g2[i]*1.4901161193847656e-8f
             + (float)g3[i]*5.8207660913467407e-11f;
    return r;
}

__device__ __forceinline__ i32x4 ldfrag8(const signed char* __restrict__ p,
                                         int rb, int lane, int kc) {
    int row = rb*16 + (lane & 15);
    int col = kc*64 + ((lane >> 4) & 3)*16;
    return *(const i32x4*)(p + row*PBI + col);
}

__device__ __forceinline__ void st_spliti(signed char* __restrict__ H,
                                          signed char* __restrict__ Md,
                                          signed char* __restrict__ L,
                                          int Tr, int Tc, int lane, f32x4 o) {
    int col = Tc*16 + (lane & 15);
    int rb  = Tr*16 + ((lane >> 4) & 3)*4;
    #pragma unroll
    for (int r = 0; r < 4; ++r) {
        int h, m, l;
        spliti(o[r], h, m, l);
        H[(rb+r)*PBI + col] = (signed char)h;
        Md[(rb+r)*PBI + col] = (signed char)m;
        L[(rb+r)*PBI + col] = (signed char)l;
        if (Tr != Tc) {
            H[col*PBI + rb + r] = (signed char)h;
            Md[col*PBI + rb + r] = (signed char)m;
            L[col*PBI + rb + r] = (signed char)l;
        }
    }
}

// 8-wave tile partition (5/4 tiles per wave, union = 36 lower tiles)
template<int W>
struct TS8 {
    static constexpr int P  = W & 3;
    static constexpr int R0 = P;
    static constexpr int R1 = 7 - P;
    static constexpr int H  = W >> 2;
    static constexpr int N  = (10 - H) / 2;
    static constexpr int tr(int i) { int g = 2*i + H; return g <= R0 ? R0 : R1; }
    static constexpr int tc(int i) { int g = 2*i + H; return g <= R0 ? g : g - R0 - 1; }
};

template<int W>
__device__ __forceinline__ void tri8_gemm_i8(
    const signed char* __restrict__ Ah, const signed char* __restrict__ Am,
    const signed char* __restrict__ Al,
    const signed char* __restrict__ Bh, const signed char* __restrict__ Bm,
    const signed char* __restrict__ Bl,
    int lane, i32x4* g0, i32x4* g1, i32x4* g2, i32x4* g3)
{
    using TS = TS8<W>;
    #pragma unroll
    for (int kc = 0; kc < 2; ++kc) {
        i32x4 a0h = ldfrag8(Ah, TS::R0, lane, kc);
        i32x4 a0m = ldfrag8(Am, TS::R0, lane, kc);
        i32x4 a0l = ldfrag8(Al, TS::R0, lane, kc);
        i32x4 a1h = ldfrag8(Ah, TS::R1, lane, kc);
        i32x4 a1m = ldfrag8(Am, TS::R1, lane, kc);
        i32x4 a1l = ldfrag8(Al, TS::R1, lane, kc);
        #pragma unroll
        for (int i = 0; i < TS::N; ++i) {
            const int r = TS::tr(i), c = TS::tc(i);
            i32x4 bh = ldfrag8(Bh, c, lane, kc);
            i32x4 bm = ldfrag8(Bm, c, lane, kc);
            i32x4 bl = ldfrag8(Bl, c, lane, kc);
            i32x4 ah = (r == TS::R0) ? a0h : a1h;
            i32x4 am = (r == TS::R0) ? a0m : a1m;
            i32x4 al = (r == TS::R0) ? a0l : a1l;
            g0[i] = mfma8(ah, bh, g0[i]);
            g1[i] = mfma8(ah, bm, g1[i]);
            g1[i] = mfma8(am, bh, g1[i]);
            g2[i] = mfma8(ah, bl, g2[i]);
            g2[i] = mfma8(am, bm, g2[i]);
            g2[i] = mfma8(al, bh, g2[i]);
            g3[i] = mfma8(am, bl, g3[i]);
            g3[i] = mfma8(al, bm, g3[i]);
        }
    }
}

template<int W>
__device__ __forceinline__ void ns_i8_body(
    signed char* Mh, signed char* Mm, signed char* Ml,
    signed char* Yh, signed char* Ym, signed char* Yl,   // double as T planes
    float* outM, float* outY, long long off, int lane, int niter)
{
    using TS = TS8<W>;
    constexpr int NT_ = TS::N;
    const i32x4 zi = {0, 0, 0, 0};
    i32x4 g0[NT_], g1[NT_], g2[NT_], g3[NT_];
    f32x4 yv[NT_], mv[NT_];
    const float cc = 1.5f, dd = sqrtf(1.5f);
    const float a15 = 1.5f*dd, a05 = 0.5f*dd, q = 0.25f*cc;

    for (int j = 0; j < niter; ++j) {
        const int last = (j == niter-1);

        // ---- phase 1: Y' = a15*Y - a05*(Y*M) -> regs ----
        #pragma unroll
        for (int i = 0; i < NT_; ++i) { g0[i]=zi; g1[i]=zi; g2[i]=zi; g3[i]=zi; }
        tri8_gemm_i8<W>(Yh,Ym,Yl, Mh,Mm,Ml, lane, g0,g1,g2,g3);
        #pragma unroll
        for (int i = 0; i < NT_; ++i) {
            f32x4 a = rec4(g0[i], g1[i], g2[i], g3[i]);
            int Tr = TS::tr(i), Tc = TS::tc(i);
            int col = Tc*16 + (lane & 15);
            int rb  = Tr*16 + ((lane >> 4) & 3)*4;
            f32x4 o;
            #pragma unroll
            for (int r = 0; r < 4; ++r)
                o[r] = a15*recLDS(Yh, Ym, Yl, rb+r, col) - a05*a[r];
            if (Tr == Tc) o = symdiag(o, lane);
            yv[i] = o;
        }
        __syncthreads();   // all Y-plane reads done; T overlays

        // ---- phase 2: T = M*M (Gram: diag tiles exactly symmetric, int-exact) ----
        #pragma unroll
        for (int i = 0; i < NT_; ++i) { g0[i]=zi; g1[i]=zi; g2[i]=zi; g3[i]=zi; }
        tri8_gemm_i8<W>(Mh,Mm,Ml, Mh,Mm,Ml, lane, g0,g1,g2,g3);
        #pragma unroll
        for (int i = 0; i < NT_; ++i) {
            f32x4 tv = rec4(g0[i], g1[i], g2[i], g3[i]);
            st_spliti(Yh, Ym, Yl, TS::tr(i), TS::tc(i), lane, tv);
        }
        __syncthreads();

        // ---- phase 3: M' = q*(9M - 6T + M*T) -> regs ----
        #pragma unroll
        for (int i = 0; i < NT_; ++i) { g0[i]=zi; g1[i]=zi; g2[i]=zi; g3[i]=zi; }
        tri8_gemm_i8<W>(Mh,Mm,Ml, Yh,Ym,Yl, lane, g0,g1,g2,g3);
        #pragma unroll
        for (int i = 0; i < NT_; ++i) {
            f32x4 a = rec4(g0[i], g1[i], g2[i], g3[i]);
            int Tr = TS::tr(i), Tc = TS::tc(i);
            int col = Tc*16 + (lane & 15);
            int rb  = Tr*16 + ((lane >> 4) & 3)*4;
            f32x4 o;
            #pragma unroll
            for (int r = 0; r < 4; ++r)
                o[r] = q*(9.f*recLDS(Mh, Mm, Ml, rb+r, col)
                        - 6.f*recLDS(Yh, Ym, Yl, rb+r, col) + a[r]);
            if (Tr == Tc) o = symdiag(o, lane);
            mv[i] = o;
        }
        __syncthreads();   // all M/T-plane reads done

        if (last) {
            #pragma unroll
            for (int i = 0; i < NT_; ++i)
                stg_sym(outY, off, TS::tr(i), TS::tc(i), lane, yv[i]);
            #pragma unroll
            for (int i = 0; i < NT_; ++i)
                stg_sym(outM, off, TS::tr(i), TS::tc(i), lane, mv[i]);
        } else {
            #pragma unroll
            for (int i = 0; i < NT_; ++i)
                st_spliti(Mh, Mm, Ml, TS::tr(i), TS::tc(i), lane, mv[i]);
            #pragma unroll
            for (int i = 0; i < NT_; ++i)
                st_spliti(Yh, Ym, Yl, TS::tr(i), TS::tc(i), lane, yv[i]);
            __syncthreads();
        }
    }
}

__global__ __launch_bounds__(512,1)
void ns_i8(const float* __restrict__ Mp, const float* __restrict__ Yp,
           float* __restrict__ outM, float* __restrict__ outY, int niter)
{
    __shared__ __align__(16) signed char pool8[6*NM*PBI];   // 110.6 KB
    signed char* Mh = pool8;
    signed char* Mm = pool8 + 1*NM*PBI;
    signed char* Ml = pool8 + 2*NM*PBI;
    signed char* Yh = pool8 + 3*NM*PBI;
    signed char* Ym = pool8 + 4*NM*PBI;
    signed char* Yl = pool8 + 5*NM*PBI;

    const int t = threadIdx.x;
    const long long off = (long long)blockIdx.x << 14;
    for (int v = 0; v < 8; ++v) {
        int f = t + v*512;
        int row = f >> 5, c4 = (f & 31) << 2;
        unsigned uh, um, ul;
        float4 x = ((const float4*)(Mp + off))[f];
        pack4i(x, uh, um, ul);
        *(unsigned*)&Mh[row*PBI + c4] = uh;
        *(unsigned*)&Mm[row*PBI + c4] = um;
        *(unsigned*)&Ml[row*PBI + c4] = ul;
        x = ((const float4*)(Yp + off))[f];
        pack4i(x, uh, um, ul);
        *(unsigned*)&Yh[row*PBI + c4] = uh;
        *(unsigned*)&Ym[row*PBI + c4] = um;
        *(unsigned*)&Yl[row*PBI + c4] = ul;
    }
    __syncthreads();

    const int lane = t & 63;
    const int w = t >> 6;
    switch (w) {
        case 0:  ns_i8_body<0>(Mh,Mm,Ml,Yh,Ym,Yl,outM,outY,off,lane,niter); break;
        case 1:  ns_i8_body<1>(Mh,Mm,Ml,Yh,Ym,Yl,outM,outY,off,lane,niter); break;
        case 2:  ns_i8_body<2>(Mh,Mm,Ml,Yh,Ym,Yl,outM,outY,off,lane,niter); break;
        case 3:  ns_i8_body<3>(Mh,Mm,Ml,Yh,Ym,Yl,outM,outY,off,lane,niter); break;
        case 4:  ns_i8_body<4>(Mh,Mm,Ml,Yh,Ym,Yl,outM,outY,off,lane,niter); break;
        case 5:  ns_i8_body<5>(Mh,Mm,Ml,Yh,Ym,Yl,outM,outY,off,lane,niter); break;
        case 6:  ns_i8_body<6>(Mh,Mm,Ml,Yh,Ym,Yl,outM,outY,off,lane,niter); break;
        default: ns_i8_body<7>(Mh,Mm,Ml,Yh,Ym,Yl,outM,outY,off,lane,niter); break;
    }
}
#endif  // HAVE_I8MFMA

// ============================================================================
// Fallback (ws too small): round-1 parallel Jacobi
// ============================================================================
#define LDA  129
#define NT   512
#define MAX_SWEEPS 14

__global__ __launch_bounds__(NT, 1)
void logeig_jacobi(const float* __restrict__ in, float* __restrict__ out)
{
    __shared__ float A[NM][LDA];
    __shared__ float V[NM][LDA];
    __shared__ float rc[64], rs[64];
    __shared__ float logd[NM];
    __shared__ float roff[NT/64], rdia[NT/64];
    __shared__ int   s_done;

    const int t = threadIdx.x;
    const long long b = blockIdx.x;
    const float* __restrict__ Ain  = in  + (b << 14);
    float* __restrict__       Aout = out + (b << 14);

    for (int k = 0; k < (NM*NM)/NT; ++k) {
        int idx = t + k*NT;
        int i = idx >> 7, j = idx & 127;
        A[i][j] = Ain[idx];
        V[i][j] = (i == j) ? 1.0f : 0.0f;
    }
    __syncthreads();

    for (int sweep = 0; sweep < MAX_SWEEPS; ++sweep) {
        for (int r = 0; r < NM-1; ++r) {
            if (t < 64) {
                int m = t, p, q;
                if (m == 0) { p = NM-1; q = r; }
                else {
                    p = r + m;            if (p >= NM-1) p -= (NM-1);
                    q = r - m + (NM-1);   if (q >= NM-1) q -= (NM-1);
                }
                float app = A[p][p], aqq = A[q][q], apq = A[p][q];
                float c = 1.0f, s = 0.0f;
                if (fabsf(apq) > 1e-12f*(fabsf(app)+fabsf(aqq)) + 1e-32f) {
                    float tau = (aqq - app) * 0.5f / apq;
                    float tt  = 1.0f / (fabsf(tau) + sqrtf(fmaf(tau,tau,1.0f)));
                    tt = (tau < 0.0f) ? -tt : tt;
                    c = rsqrtf(fmaf(tt,tt,1.0f));
                    s = tt * c;
                }
                rc[m] = c; rs[m] = s;
            }
            __syncthreads();
            for (int k = 0; k < (2*64*NM)/NT; ++k) {
                int task = t + k*NT;
                int i   = task & 127;
                int m   = (task >> 7) & 63;
                int isV = task >> 13;
                int p, q;
                if (m == 0) { p = NM-1; q = r; }
                else {
                    p = r + m;            if (p >= NM-1) p -= (NM-1);
                    q = r - m + (NM-1);   if (q >= NM-1) q -= (NM-1);
                }
                float c = rc[m], s = rs[m];
                if (isV == 0) {
                    float x = A[i][p], y = A[i][q];
                    A[i][p] = c*x - s*y;
                    A[i][q] = s*x + c*y;
                } else {
                    float x = V[i][p], y = V[i][q];
                    V[i][p] = c*x - s*y;
                    V[i][q] = s*x + c*y;
                }
            }
            __syncthreads();
            for (int k = 0; k < (64*NM)/NT; ++k) {
                int task = t + k*NT;
                int j = task & 127;
                int m = task >> 7;
                int p, q;
                if (m == 0) { p = NM-1; q = r; }
                else {
                    p = r + m;            if (p >= NM-1) p -= (NM-1);
                    q = r - m + (NM-1);   if (q >= NM-1) q -= (NM-1);
                }
                float c = rc[m], s = rs[m];
                float x = A[p][j], y = A[q][j];
                A[p][j] = c*x - s*y;
                A[q][j] = s*x + c*y;
            }
            __syncthreads();
        }
        float off2 = 0.0f, dia2 = 0.0f;
        for (int k = 0; k < (NM*NM)/NT; ++k) {
            int idx = t + k*NT;
            int i = idx >> 7, j = idx & 127;
            float v = A[i][j];
            if (i == j) dia2 += v*v; else off2 += v*v;
        }
        #pragma unroll
        for (int o = 32; o > 0; o >>= 1) {
            off2 += __shfl_down(off2, o, 64);
            dia2 += __shfl_down(dia2, o, 64);
        }
        if ((t & 63) == 0) { roff[t >> 6] = off2; rdia[t >> 6] = dia2; }
        __syncthreads();
        if (t == 0) {
            float o2 = 0.0f, d2 = 0.0f;
            for (int w = 0; w < NT/64; ++w) { o2 += roff[w]; d2 += rdia[w]; }
            s_done = (o2 <= 1e-13f * d2) ? 1 : 0;
        }
        __syncthreads();
        if (s_done) break;
    }

    if (t < NM) logd[t] = logf(fmaxf(A[t][t], 1e-12f));
    __syncthreads();
    for (int kk = 0; kk < (NM*NM)/NT; ++kk) {
        int idx = t + kk*NT;
        int i = idx >> 7, k = idx & 127;
        A[i][k] = V[i][k] * logd[k];
    }
    __syncthreads();
    {
        int i  = t >> 2;
        int jb = t & 3;
        float acc[32];
        #pragma unroll
        for (int jj = 0; jj < 32; ++jj) acc[jj] = 0.0f;
        for (int kk = 0; kk < NM; ++kk) {
            int k = (kk + jb) & 127;
            float w = A[i][k];
            #pragma unroll
            for (int jj = 0; jj < 32; ++jj)
                acc[jj] = fmaf(w, V[jb*32 + jj][k], acc[jj]);
        }
        #pragma unroll
        for (int jj = 0; jj < 32; ++jj)
            Aout[i*NM + jb*32 + jj] = acc[jj];
    }
}

// ============================================================================
// Host
// ============================================================================
static void cheb_log_power(double lo, double up, int deg, double* p)
{
    const int NC = deg + 1;
    const int MN = 64;
    double mid = 0.5*(lo+up), hw = 0.5*(up-lo);
    double cc[32];
    for (int j = 0; j < NC; ++j) {
        double s = 0.0;
        for (int m = 0; m < MN; ++m) {
            double th = M_PI*(m+0.5)/MN;
            s += log(mid + hw*cos(th)) * cos(j*th);
        }
        cc[j] = 2.0*s/MN;
    }
    double Tp[32] = {0}, Tc[32] = {0}, Tn[32];
    for (int j = 0; j < NC; ++j) p[j] = 0.0;
    Tp[0] = 1.0;  p[0] += 0.5*cc[0];
    Tc[1] = 1.0;  p[1] += cc[1];
    for (int k = 2; k <= deg; ++k) {
        for (int j = 0; j < NC; ++j) Tn[j] = -Tp[j];
        for (int j = 1; j < NC; ++j) Tn[j] += 2.0*Tc[j-1];
        for (int j = 0; j < NC; ++j) { p[j] += cc[k]*Tn[j]; Tp[j] = Tc[j]; Tc[j] = Tn[j]; }
    }
}

extern "C" void kernel_launch(void* const* d_in, const int* in_sizes, int n_in,
                              void* d_out, int out_size, void* d_ws, size_t ws_size,
                              hipStream_t stream) {
    const float* in = (const float*)d_in[0];
    float* out = (float*)d_out;
    const int batch = in_sizes[0] >> 14;                 // 4096
    const size_t matBytes = (size_t)batch * NM * NM * 4; // 256 MB
    const size_t need = matBytes + (size_t)batch * 4;

    if (ws_size < need) {   // fallback
        logeig_jacobi<<<batch, NT, 0, stream>>>(in, out);
        return;
    }

    float* Mbuf = (float*)d_ws;
    float* lns  = (float*)((char*)d_ws + matBytes);

    // --- scaling: s0 = gersh(A); tighten via sqrt(gersh((A/s0)^2)) ---
    scale_kernel<<<batch, 256, 0, stream>>>(in, out, Mbuf, lns);      // out = X0
    gram_tri<<<batch, 512, 0, stream>>>(out, Mbuf);                   // Mbuf = X0^2
    rescale_kernel<<<batch, 256, 0, stream>>>(Mbuf, out, Mbuf, lns);  // out=Mbuf=X

    // --- L1 iters 0-3 (precision-critical): exact 24-bit i8-MFMA or f32 ---
#if HAVE_I8MFMA
    ns_i8<<<batch, 512, 0, stream>>>(Mbuf, out, Mbuf, out, 4);
#else
    ns_tri4<<<batch, 512, 0, stream>>>(Mbuf, out, Mbuf, out, 4);
#endif

    // --- fused MFMA NS segments (schedule {1.5 x(n-3), 1.116, 1, 1}) ---
    ns_fused<<<batch, 1024, 0, stream>>>(Mbuf, out, out, 8);  // L1 iters 4..11
    ns_fused<<<batch, 1024, 0, stream>>>(out,  out, out, 8);  // L2 (M0=Y0)
    ns_fused<<<batch, 1024, 0, stream>>>(out,  out, out, 6);  // L3 (M0=Y0)

    // --- fused Chebyshev-minimax log, deg 8 on [0.25, 1.002] ---
    const double lo = 0.25, up = 1.002;
    const double mid = 0.5*(lo+up), hw = 0.5*(up-lo);
    double p[9];
    cheb_log_power(lo, up, 8, p);

    PolyCoefs pc;
    pc.a  = (float)(p[8]/hw);
    pc.bd = (float)(p[7] - p[8]*mid/hw);
    pc.s1 = (float)(1.0/hw);
    pc.s2 = (float)(mid/hw);
    pc.c0 = (float)p[6]; pc.c1 = (float)p[5]; pc.c2 = (float)p[4];
    pc.c3 = (float)p[3]; pc.c4 = (float)p[2]; pc.c5 = (float)p[1];
    pc.f1 = (float)(8.0/hw);
    pc.f2 = (float)(8.0*mid/hw);
    pc.f3 = (float)(8.0*p[0]);

    poly_fused<<<batch, 1024, 0, stream>>>(out, out, lns, pc);
}